// Round 10
// baseline (1447.341 us; speedup 1.0000x reference)
//
#include <hip/hip_runtime.h>
#include <cstdint>
#include <cstddef>

#define B_ 2
#define S_ 2048
#define HID_ 2048
#define HK_ 16
#define HV_ 32
#define DK_ 128
#define DV_ 128
#define KEY_DIM_ 2048
#define VAL_DIM_ 4096
#define QKVZ_DIM_ 12288
#define BA_DIM_ 64
#define CONV_DIM_ 8192
#define EPS_ 1e-6f

typedef unsigned short bf16;
typedef __attribute__((ext_vector_type(8))) short bf16x8;
typedef __attribute__((ext_vector_type(4))) float f32x4;
typedef __attribute__((ext_vector_type(2))) float f32x2;

__device__ __forceinline__ float silu_f(float x) { return x / (1.f + expf(-x)); }

__device__ __forceinline__ bf16 f2bf(float x) {
    unsigned int u = __float_as_uint(x);
    u += 0x7FFF + ((u >> 16) & 1);   // round-to-nearest-even
    return (bf16)(u >> 16);
}
__device__ __forceinline__ float bf2f(bf16 x) {
    return __uint_as_float((unsigned)x << 16);
}
#define BF2F_LO(u) __uint_as_float((unsigned)(u) << 16)
#define BF2F_HI(u) __uint_as_float((unsigned)(u) & 0xFFFF0000u)

typedef const __attribute__((address_space(1))) unsigned int cgu32;
typedef __attribute__((address_space(3))) unsigned int lsu32;
__device__ __forceinline__ void gld16(const void* g, void* l) {
    __builtin_amdgcn_global_load_lds((cgu32*)g, (lsu32*)l, 16, 0, 0);
}

// ---- packed fp32 math (VOP3P, gfx90a+) ------------------------------------
__device__ __forceinline__ f32x2 pk_mul(f32x2 a, f32x2 b) {
    f32x2 d;
    asm("v_pk_mul_f32 %0, %1, %2" : "=v"(d) : "v"(a), "v"(b));
    return d;
}
__device__ __forceinline__ f32x2 pk_fma(f32x2 a, f32x2 b, f32x2 c) {
    f32x2 d;
    asm("v_pk_fma_f32 %0, %1, %2, %3" : "=v"(d) : "v"(a), "v"(b), "v"(c));
    return d;
}
__device__ __forceinline__ f32x2 pk_add(f32x2 a, f32x2 b) {
    f32x2 d;
    asm("v_pk_add_f32 %0, %1, %2" : "=v"(d) : "v"(a), "v"(b));
    return d;
}

// DPP rotate-add: sum over each 16-lane row (pure VALU, stays off LDS pipe).
template <int CTRL>
__device__ __forceinline__ float dpp_ror_add(float x) {
    const int t =
        __builtin_amdgcn_update_dpp(0, __float_as_int(x), CTRL, 0xF, 0xF, false);
    return x + __int_as_float(t);
}
__device__ __forceinline__ float row16_sum(float x) {
    x = dpp_ror_add<0x128>(x);
    x = dpp_ror_add<0x124>(x);
    x = dpp_ror_add<0x122>(x);
    x = dpp_ror_add<0x121>(x);
    return x;
}

// ---------------------------------------------------------------------------
// fp32 -> bf16 conversion, 4 elems/thread
// ---------------------------------------------------------------------------
__global__ __launch_bounds__(256) void f2bf_kernel(const float* __restrict__ in,
                                                   bf16* __restrict__ out) {
    const int64_t i = (int64_t)blockIdx.x * 256 + threadIdx.x;
    const float4 v = ((const float4*)in)[i];
    ushort4 o;
    o.x = f2bf(v.x); o.y = f2bf(v.y); o.z = f2bf(v.z); o.w = f2bf(v.w);
    ((ushort4*)out)[i] = o;
}

// ---------------------------------------------------------------------------
// bf16 MFMA GEMM NT (m97 structure, unchanged)
// ---------------------------------------------------------------------------
template <int OUTBF16>
__global__ __launch_bounds__(256) void gemm_mfma_nt(const bf16* __restrict__ A,
                                                    const bf16* __restrict__ Bm,
                                                    void* __restrict__ Cv,
                                                    int M, int N, int K) {
    __shared__ bf16 As[128 * 32];
    __shared__ bf16 Bs[128 * 32];
    const int tid = threadIdx.x;
    const int w = tid >> 6;
    const int l = tid & 63;
    const int bm = blockIdx.y, bn = blockIdx.x;

    const int srow = l >> 2;
    const int scol = (l & 3) << 3;
    const bf16* Ag = A + (size_t)(bm * 128 + w * 16 + srow) * K + scol;
    const bf16* Bg = Bm + (size_t)(bn * 128 + w * 16 + srow) * K + scol;
    bf16* Al = As + w * 16 * 32;
    bf16* Bl = Bs + w * 16 * 32;
    const size_t rstep = (size_t)64 * K;

    const int wr = (w >> 1) * 64;
    const int wc = (w & 1) * 64;
    const int fl = l & 15;
    const int fk = (l >> 4) * 8;

    f32x4 acc[4][4];
#pragma unroll
    for (int m = 0; m < 4; ++m)
#pragma unroll
        for (int n = 0; n < 4; ++n) acc[m][n] = (f32x4){0.f, 0.f, 0.f, 0.f};

    for (int k0 = 0; k0 < K; k0 += 32) {
        gld16(Ag + k0, Al);
        gld16(Ag + k0 + rstep, Al + 64 * 32);
        gld16(Bg + k0, Bl);
        gld16(Bg + k0 + rstep, Bl + 64 * 32);
        __syncthreads();

        bf16x8 af[4], bb[4];
#pragma unroll
        for (int m = 0; m < 4; ++m)
            af[m] = *(const bf16x8*)(As + (wr + m * 16 + fl) * 32 + fk);
#pragma unroll
        for (int n = 0; n < 4; ++n)
            bb[n] = *(const bf16x8*)(Bs + (wc + n * 16 + fl) * 32 + fk);
#pragma unroll
        for (int m = 0; m < 4; ++m)
#pragma unroll
            for (int n = 0; n < 4; ++n)
                acc[m][n] = __builtin_amdgcn_mfma_f32_16x16x32_bf16(
                    af[m], bb[n], acc[m][n], 0, 0, 0);
        __syncthreads();
    }

    if (OUTBF16) {
        bf16* C = (bf16*)Cv;
#pragma unroll
        for (int m = 0; m < 4; ++m)
#pragma unroll
            for (int n = 0; n < 4; ++n)
#pragma unroll
                for (int r = 0; r < 4; ++r) {
                    const int row = bm * 128 + wr + m * 16 + (l >> 4) * 4 + r;
                    const int col = bn * 128 + wc + n * 16 + fl;
                    C[(size_t)row * N + col] = f2bf(acc[m][n][r]);
                }
    } else {
        float* C = (float*)Cv;
#pragma unroll
        for (int m = 0; m < 4; ++m)
#pragma unroll
            for (int n = 0; n < 4; ++n)
#pragma unroll
                for (int r = 0; r < 4; ++r) {
                    const int row = bm * 128 + wr + m * 16 + (l >> 4) * 4 + r;
                    const int col = bn * 128 + wc + n * 16 + fl;
                    C[(size_t)row * N + col] = acc[m][n][r];
                }
    }
}

// ---------------------------------------------------------------------------
// fp32 vector GEMM (tiny ba projection)
// ---------------------------------------------------------------------------
#define BM 64
#define BN 64
#define BKK 32

__global__ __launch_bounds__(256) void gemm_nt_f32(const float* __restrict__ A,
                                                   const float* __restrict__ Bm,
                                                   float* __restrict__ C,
                                                   int M, int N, int K) {
    __shared__ float As[BKK][BM + 4];
    __shared__ float Bs[BKK][BN + 4];
    const int tid = threadIdx.x;
    const int tx = tid & 15;
    const int ty = tid >> 4;
    const int bm = blockIdx.y, bn = blockIdx.x;
    const float* Ab = A + (size_t)bm * BM * K;
    const float* Bb = Bm + (size_t)bn * BN * K;
    const int lr = tid >> 2;
    const int lc = (tid & 3) << 3;

    float c[4][4] = {{0.f, 0.f, 0.f, 0.f}, {0.f, 0.f, 0.f, 0.f},
                     {0.f, 0.f, 0.f, 0.f}, {0.f, 0.f, 0.f, 0.f}};

    for (int k0 = 0; k0 < K; k0 += BKK) {
        const float4 a0 = *(const float4*)(Ab + (size_t)lr * K + k0 + lc);
        const float4 a1 = *(const float4*)(Ab + (size_t)lr * K + k0 + lc + 4);
        const float4 b0 = *(const float4*)(Bb + (size_t)lr * K + k0 + lc);
        const float4 b1 = *(const float4*)(Bb + (size_t)lr * K + k0 + lc + 4);
        __syncthreads();
        As[lc + 0][lr] = a0.x; As[lc + 1][lr] = a0.y;
        As[lc + 2][lr] = a0.z; As[lc + 3][lr] = a0.w;
        As[lc + 4][lr] = a1.x; As[lc + 5][lr] = a1.y;
        As[lc + 6][lr] = a1.z; As[lc + 7][lr] = a1.w;
        Bs[lc + 0][lr] = b0.x; Bs[lc + 1][lr] = b0.y;
        Bs[lc + 2][lr] = b0.z; Bs[lc + 3][lr] = b0.w;
        Bs[lc + 4][lr] = b1.x; Bs[lc + 5][lr] = b1.y;
        Bs[lc + 6][lr] = b1.z; Bs[lc + 7][lr] = b1.w;
        __syncthreads();
#pragma unroll
        for (int kk = 0; kk < BKK; ++kk) {
            const float4 Av = *(const float4*)&As[kk][ty << 2];
            const float4 Bv = *(const float4*)&Bs[kk][tx << 2];
            const float aa[4] = {Av.x, Av.y, Av.z, Av.w};
            const float bb[4] = {Bv.x, Bv.y, Bv.z, Bv.w};
#pragma unroll
            for (int i = 0; i < 4; ++i)
#pragma unroll
                for (int j = 0; j < 4; ++j)
                    c[i][j] = fmaf(aa[i], bb[j], c[i][j]);
        }
    }
    float* Cp = C + (size_t)(bm * BM + (ty << 2)) * N + bn * BN + (tx << 2);
#pragma unroll
    for (int i = 0; i < 4; ++i)
        *(float4*)(Cp + (size_t)i * N) =
            make_float4(c[i][0], c[i][1], c[i][2], c[i][3]);
}

// ---------------------------------------------------------------------------
// Causal depthwise conv (K=4) + SiLU.
// q -> qf (fp32), k -> kf (fp32), v -> vbuf (bf16).
// ---------------------------------------------------------------------------
__global__ __launch_bounds__(256) void conv_silu_kernel(
    const bf16* __restrict__ qkvz, const float* __restrict__ cw,
    float* __restrict__ qf, float* __restrict__ kf, bf16* __restrict__ vbuf) {
    const int64_t idx = (int64_t)blockIdx.x * 256 + threadIdx.x;
    const int c = (int)(idx & (CONV_DIM_ - 1));
    const int64_t bs = idx >> 13;
    const int s = (int)(bs & (S_ - 1));

    int col;
    if (c < KEY_DIM_) {
        col = ((c >> 7) * 768) + (c & 127);                       // q
    } else if (c < 2 * KEY_DIM_) {
        const int c2 = c - KEY_DIM_;
        col = ((c2 >> 7) * 768) + 128 + (c2 & 127);               // k
    } else {
        const int c3 = c - 2 * KEY_DIM_;
        col = ((c3 >> 8) * 768) + 256 + (c3 & 255);               // v
    }
    const float w0 = cw[c * 4 + 0], w1 = cw[c * 4 + 1];
    const float w2 = cw[c * 4 + 2], w3 = cw[c * 4 + 3];
    const bf16* xp = qkvz + bs * (int64_t)QKVZ_DIM_ + col;
    float acc = w3 * bf2f(xp[0]);
    if (s >= 1) acc = fmaf(w2, bf2f(xp[-QKVZ_DIM_]), acc);
    if (s >= 2) acc = fmaf(w1, bf2f(xp[-2 * QKVZ_DIM_]), acc);
    if (s >= 3) acc = fmaf(w0, bf2f(xp[-3 * QKVZ_DIM_]), acc);
    const float y = silu_f(acc);
    if (c < KEY_DIM_) {
        qf[bs * KEY_DIM_ + c] = y;
    } else if (c < 2 * KEY_DIM_) {
        kf[bs * KEY_DIM_ + (c - KEY_DIM_)] = y;
    } else {
        vbuf[bs * VAL_DIM_ + (c - 2 * KEY_DIM_)] = f2bf(y);
    }
}

// ---------------------------------------------------------------------------
// Pre-normalize q/k (fp32, in place): q *= DK^-0.5/||q||, k *= 1/||k||.
// ---------------------------------------------------------------------------
__global__ __launch_bounds__(256) void normalize_qk_kernel(
    float* __restrict__ qf, float* __restrict__ kf) {
    const int wid = (blockIdx.x * 256 + threadIdx.x) >> 6;  // B*S*HK
    const int lane = threadIdx.x & 63;
    const int hk = wid & (HK_ - 1);
    const int64_t bs = wid >> 4;
    float* qp = qf + bs * KEY_DIM_ + hk * DK_ + lane * 2;
    float* kp = kf + bs * KEY_DIM_ + hk * DK_ + lane * 2;
    const f32x2 q = *(const f32x2*)qp;
    const f32x2 k = *(const f32x2*)kp;
    float qs = fmaf(q.x, q.x, q.y * q.y);
    float ks = fmaf(k.x, k.x, k.y * k.y);
#pragma unroll
    for (int m = 1; m < 64; m <<= 1) {
        qs += __shfl_xor(qs, m);
        ks += __shfl_xor(ks, m);
    }
    const float qsc = rsqrtf(qs + EPS_) * 0.08838834764831845f;  // DK^-0.5
    const float ksc = rsqrtf(ks + EPS_);
    *(f32x2*)qp = (f32x2){q.x * qsc, q.y * qsc};
    *(f32x2*)kp = (f32x2){k.x * ksc, k.y * ksc};
}

// ---------------------------------------------------------------------------
// Gate precompute: egbuf = exp(g), betabuf = sigmoid(b)
// ---------------------------------------------------------------------------
__global__ __launch_bounds__(256) void gate_kernel(
    const float* __restrict__ ba, const float* __restrict__ A_log,
    const float* __restrict__ dt_bias, float* __restrict__ egbuf,
    float* __restrict__ betabuf) {
    const int idx = blockIdx.x * 256 + threadIdx.x;   // B*S*HV
    const int hv = idx & (HV_ - 1);
    const int bs = idx >> 5;
    const int hk = hv >> 1, j = hv & 1;
    const float* p = ba + (size_t)bs * BA_DIM_ + hk * 4;
    const float bval = p[j];
    const float aval = p[2 + j];
    const float x = aval + dt_bias[hv];
    const float sp = (x > 20.f) ? x : log1pf(expf(x));
    egbuf[idx] = expf(-expf(A_log[hv]) * sp);
    betabuf[idx] = 1.f / (1.f + expf(-bval));
}

// ---------------------------------------------------------------------------
// Gated delta rule scan, short-chain edition.
// __launch_bounds__(256,2): VGPR cap 256 so A/B prefetch sets stay RESIDENT
// (R6-R9 were allocated 28-40 VGPRs -> prefetch collapsed to load-near-use).
// Chain re-association: three INDEPENDENT reduces (k.st, q.st, q.k), then
//   p = eg*(k.st); delta = (v-p)*beta; o = eg*(q.st)+delta*(q.k);
//   st = eg*st + delta*k.
// Loop-carried chain = st -> k.st reduce -> delta -> st only.
// XCD swizzle (R9) kept: FETCH 57MB proven.
// ---------------------------------------------------------------------------
__global__ __launch_bounds__(256, 2) void delta_scan_kernel(
    const float* __restrict__ qf, const float* __restrict__ kf,
    const bf16* __restrict__ vbuf, const float* __restrict__ egbuf,
    const float* __restrict__ betabuf, bf16* __restrict__ core) {
    const int w = threadIdx.x >> 6;         // wave in block 0..3
    const int lane = threadIdx.x & 63;
    // --- XCD swizzle (as R9) ---
    const int xcd = blockIdx.x & 7;
    const int slot = blockIdx.x >> 3;       // 0..63
    const int i = ((slot >> 4) << 3) | xcd; // bhk 0..31
    const int b = i >> 4;
    const int hk = i & 15;
    const int within = slot & 15;           // 0..15
    const int hv = hk * 2 + (within >> 3);
    const int dvb = (within & 7) * 4 + w;   // 0..31
    // --- lane split ---
    const int g = lane & 15;
    const int dvi = lane >> 4;
    const int dv = (dvb << 2) + dvi;

    const float* qbase = qf + (size_t)b * S_ * KEY_DIM_ + hk * DK_ + g * 8;
    const float* kbase = kf + (size_t)b * S_ * KEY_DIM_ + hk * DK_ + g * 8;
    const bf16* vbase = vbuf + (size_t)b * S_ * VAL_DIM_ + hv * DV_ + dv;
    const float* egp = egbuf + (size_t)b * S_ * HV_ + hv;
    const float* bp = betabuf + (size_t)b * S_ * HV_ + hv;
    bf16* op = core + (size_t)b * S_ * VAL_DIM_ + hv * DV_ + dv;

    f32x2 st0 = {0.f, 0.f}, st1 = {0.f, 0.f};
    f32x2 st2 = {0.f, 0.f}, st3 = {0.f, 0.f};

    f32x4 qA[2], kA[2], qB[2], kB[2];
    float vvA, egA, btA, vvB, egB, btB;

#define LOADSET(Qv, Kv, VV, EG, BT, sidx)                                      \
    do {                                                                       \
        const size_t _ro = (size_t)(sidx)*KEY_DIM_;                            \
        Qv[0] = *(const f32x4*)(qbase + _ro);                                  \
        Qv[1] = *(const f32x4*)(qbase + _ro + 4);                              \
        Kv[0] = *(const f32x4*)(kbase + _ro);                                  \
        Kv[1] = *(const f32x4*)(kbase + _ro + 4);                              \
        VV = bf2f(vbase[(size_t)(sidx)*VAL_DIM_]);                             \
        EG = egp[(size_t)(sidx)*HV_];                                          \
        BT = bp[(size_t)(sidx)*HV_];                                           \
    } while (0)

#define STEP(Qv, Kv, VV, EG, BT, sidx)                                         \
    do {                                                                       \
        const f32x2 k0 = __builtin_shufflevector(Kv[0], Kv[0], 0, 1);          \
        const f32x2 k1 = __builtin_shufflevector(Kv[0], Kv[0], 2, 3);          \
        const f32x2 k2 = __builtin_shufflevector(Kv[1], Kv[1], 0, 1);          \
        const f32x2 k3 = __builtin_shufflevector(Kv[1], Kv[1], 2, 3);          \
        const f32x2 q0 = __builtin_shufflevector(Qv[0], Qv[0], 0, 1);          \
        const f32x2 q1 = __builtin_shufflevector(Qv[0], Qv[0], 2, 3);          \
        const f32x2 q2 = __builtin_shufflevector(Qv[1], Qv[1], 0, 1);          \
        const f32x2 q3 = __builtin_shufflevector(Qv[1], Qv[1], 2, 3);          \
        /* three independent reduces: k.st (carried), q.st, q.k */             \
        f32x2 pa = pk_mul(k0, st0);                                            \
        pa = pk_fma(k1, st1, pa);                                              \
        f32x2 pb = pk_mul(k2, st2);                                            \
        pb = pk_fma(k3, st3, pb);                                              \
        pa = pk_add(pa, pb);                                                   \
        f32x2 oa = pk_mul(q0, st0);                                            \
        oa = pk_fma(q1, st1, oa);                                              \
        f32x2 ob = pk_mul(q2, st2);                                            \
        ob = pk_fma(q3, st3, ob);                                              \
        oa = pk_add(oa, ob);                                                   \
        f32x2 ca = pk_mul(q0, k0);                                             \
        ca = pk_fma(q1, k1, ca);                                               \
        f32x2 cb = pk_mul(q2, k2);                                             \
        cb = pk_fma(q3, k3, cb);                                               \
        ca = pk_add(ca, cb);                                                   \
        float pr = pa.x + pa.y;                                                \
        float qs = oa.x + oa.y;                                                \
        float qk = ca.x + ca.y;                                                \
        pr = row16_sum(pr);                                                    \
        qs = row16_sum(qs);                                                    \
        qk = row16_sum(qk);                                                    \
        const float p = EG * pr;                                               \
        const float delta = (VV - p) * BT;                                     \
        const float o = fmaf(EG, qs, delta * qk);                              \
        const f32x2 d2 = {delta, delta};                                       \
        const f32x2 eg2 = {EG, EG};                                            \
        st0 = pk_fma(st0, eg2, pk_mul(k0, d2));                                \
        st1 = pk_fma(st1, eg2, pk_mul(k1, d2));                                \
        st2 = pk_fma(st2, eg2, pk_mul(k2, d2));                                \
        st3 = pk_fma(st3, eg2, pk_mul(k3, d2));                                \
        if (g == 0) op[(size_t)(sidx)*VAL_DIM_] = f2bf(o);                     \
    } while (0)

    LOADSET(qA, kA, vvA, egA, btA, 0);
    LOADSET(qB, kB, vvB, egB, btB, 1);

    for (int s = 0; s < S_; s += 2) {
        // issue next A-set loads BEFORE consuming current (keeps them a full
        // iteration ahead; VGPR budget now allows residency)
        STEP(qA, kA, vvA, egA, btA, s);
        LOADSET(qA, kA, vvA, egA, btA, s + 2);
        STEP(qB, kB, vvB, egB, btB, s + 1);
        LOADSET(qB, kB, vvB, egB, btB, s + 3);
    }
#undef LOADSET
#undef STEP
}

// ---------------------------------------------------------------------------
// Gated RMSNorm in-place on bf16 core; z from bf16 qkvz.
// ---------------------------------------------------------------------------
__global__ __launch_bounds__(256) void rmsnorm_gate_kernel(
    bf16* __restrict__ core, const bf16* __restrict__ qkvz,
    const float* __restrict__ nw) {
    const int wid = (blockIdx.x * 256 + threadIdx.x) >> 6;
    const int lane = threadIdx.x & 63;
    const int hv = wid & (HV_ - 1);
    const int64_t bs = wid >> 5;
    bf16* x = core + (size_t)bs * VAL_DIM_ + hv * DV_;
    const float x0 = bf2f(x[lane]);
    const float x1 = bf2f(x[lane + 64]);
    float ss = fmaf(x0, x0, x1 * x1);
#pragma unroll
    for (int m = 1; m < 64; m <<= 1) ss += __shfl_xor(ss, m);
    const float inv = rsqrtf(ss * (1.f / 128.f) + EPS_);
    const bf16* z =
        qkvz + (size_t)bs * QKVZ_DIM_ + (hv >> 1) * 768 + 512 + (hv & 1) * 128;
    x[lane] = f2bf(x0 * inv * nw[lane] * silu_f(bf2f(z[lane])));
    x[lane + 64] =
        f2bf(x1 * inv * nw[lane + 64] * silu_f(bf2f(z[lane + 64])));
}

// ---------------------------------------------------------------------------
extern "C" void kernel_launch(void* const* d_in, const int* in_sizes, int n_in,
                              void* d_out, int out_size, void* d_ws,
                              size_t ws_size, hipStream_t stream) {
    const float* hidden  = (const float*)d_in[0];
    const float* W_qkvz  = (const float*)d_in[1];
    const float* W_ba    = (const float*)d_in[2];
    const float* conv_w  = (const float*)d_in[3];
    const float* dt_bias = (const float*)d_in[4];
    const float* A_log   = (const float*)d_in[5];
    const float* norm_w  = (const float*)d_in[6];
    const float* W_out   = (const float*)d_in[7];
    float* out = (float*)d_out;

    // workspace: ~321.1 MB (< run-proven 337.5 MB)
    bf16* hidden_bf = (bf16*)d_ws;                        //  8,388,608 e
    bf16* Wq_bf  = hidden_bf + (size_t)8388608;           // 25,165,824 e
    bf16* Wo_bf  = Wq_bf + (size_t)25165824;              //  8,388,608 e
    bf16* qkvz   = Wo_bf + (size_t)8388608;               // 50,331,648 e
    float* qf    = (float*)(qkvz + (size_t)50331648);     //  8,388,608 f
    float* kf    = qf + (size_t)8388608;                  //  8,388,608 f
    bf16* vbuf   = (bf16*)(kf + (size_t)8388608);         // 16,777,216 e
    bf16* core   = vbuf + (size_t)16777216;               // 16,777,216 e
    float* ba      = (float*)(core + (size_t)16777216);   //    262,144 f
    float* egbuf   = ba + 262144;                         //    131,072 f
    float* betabuf = egbuf + 131072;                      //    131,072 f

    const int MBS = B_ * S_;  // 4096

    // 0. fp32 -> bf16 operand conversion
    f2bf_kernel<<<8388608 / 1024, 256, 0, stream>>>(hidden, hidden_bf);
    f2bf_kernel<<<25165824 / 1024, 256, 0, stream>>>(W_qkvz, Wq_bf);
    f2bf_kernel<<<8388608 / 1024, 256, 0, stream>>>(W_out, Wo_bf);

    // 1. qkvz = hidden @ W_qkvz^T (bf16 MFMA)
    gemm_mfma_nt<1><<<dim3(QKVZ_DIM_ / 128, MBS / 128), 256, 0, stream>>>(
        hidden_bf, Wq_bf, (void*)qkvz, MBS, QKVZ_DIM_, HID_);
    // 2. ba = hidden @ W_ba^T (fp32 vector)
    gemm_nt_f32<<<dim3(BA_DIM_ / BN, MBS / BM), 256, 0, stream>>>(
        hidden, W_ba, ba, MBS, BA_DIM_, HID_);
    // 3. gates (eg = exp(g))
    gate_kernel<<<(MBS * HV_) / 256, 256, 0, stream>>>(ba, A_log, dt_bias,
                                                       egbuf, betabuf);
    // 4. causal conv + silu -> qf/kf (fp32), vbuf (bf16)
    conv_silu_kernel<<<(int)(((int64_t)MBS * CONV_DIM_) / 256), 256, 0,
                       stream>>>(qkvz, conv_w, qf, kf, vbuf);
    // 4b. pre-normalize q/k in place (fp32)
    normalize_qk_kernel<<<(MBS * HK_ * 64) / 256, 256, 0, stream>>>(qf, kf);
    // 5. gated delta rule scan -> core (bf16); 512 blocks, XCD-swizzled
    delta_scan_kernel<<<512, 256, 0, stream>>>(qf, kf, vbuf, egbuf, betabuf,
                                               core);
    // 6. gated rmsnorm (in place on bf16 core)
    rmsnorm_gate_kernel<<<(MBS * HV_ * 64) / 256, 256, 0, stream>>>(core, qkvz,
                                                                    norm_w);
    // 7. out = core @ W_out^T (bf16 MFMA -> fp32 out)
    gemm_mfma_nt<0><<<dim3(HID_ / 128, MBS / 128), 256, 0, stream>>>(
        core, Wo_bf, (void*)out, MBS, HID_, VAL_DIM_);
}

// Round 11
// 1285.153 us; speedup vs baseline: 1.1262x; 1.1262x over previous
//
#include <hip/hip_runtime.h>
#include <cstdint>
#include <cstddef>

#define B_ 2
#define S_ 2048
#define HID_ 2048
#define HK_ 16
#define HV_ 32
#define DK_ 128
#define DV_ 128
#define KEY_DIM_ 2048
#define VAL_DIM_ 4096
#define QKVZ_DIM_ 12288
#define BA_DIM_ 64
#define CONV_DIM_ 8192
#define EPS_ 1e-6f

typedef unsigned short bf16;
typedef __attribute__((ext_vector_type(8))) short bf16x8;
typedef __attribute__((ext_vector_type(4))) float f32x4;
typedef __attribute__((ext_vector_type(2))) float f32x2;

__device__ __forceinline__ float silu_f(float x) { return x / (1.f + expf(-x)); }

__device__ __forceinline__ bf16 f2bf(float x) {
    unsigned int u = __float_as_uint(x);
    u += 0x7FFF + ((u >> 16) & 1);   // round-to-nearest-even
    return (bf16)(u >> 16);
}
__device__ __forceinline__ float bf2f(bf16 x) {
    return __uint_as_float((unsigned)x << 16);
}
#define BF2F_LO(u) __uint_as_float((unsigned)(u) << 16)
#define BF2F_HI(u) __uint_as_float((unsigned)(u) & 0xFFFF0000u)

typedef const __attribute__((address_space(1))) unsigned int cgu32;
typedef __attribute__((address_space(3))) unsigned int lsu32;
__device__ __forceinline__ void gld16(const void* g, void* l) {
    __builtin_amdgcn_global_load_lds((cgu32*)g, (lsu32*)l, 16, 0, 0);
}

// ---- packed fp32 math (VOP3P, gfx90a+) ------------------------------------
__device__ __forceinline__ f32x2 pk_mul(f32x2 a, f32x2 b) {
    f32x2 d;
    asm("v_pk_mul_f32 %0, %1, %2" : "=v"(d) : "v"(a), "v"(b));
    return d;
}
__device__ __forceinline__ f32x2 pk_fma(f32x2 a, f32x2 b, f32x2 c) {
    f32x2 d;
    asm("v_pk_fma_f32 %0, %1, %2, %3" : "=v"(d) : "v"(a), "v"(b), "v"(c));
    return d;
}
__device__ __forceinline__ f32x2 pk_add(f32x2 a, f32x2 b) {
    f32x2 d;
    asm("v_pk_add_f32 %0, %1, %2" : "=v"(d) : "v"(a), "v"(b));
    return d;
}

// DPP rotate-add: sum over each 16-lane row (pure VALU, stays off LDS pipe).
template <int CTRL>
__device__ __forceinline__ float dpp_ror_add(float x) {
    const int t =
        __builtin_amdgcn_update_dpp(0, __float_as_int(x), CTRL, 0xF, 0xF, false);
    return x + __int_as_float(t);
}
__device__ __forceinline__ float row16_sum(float x) {
    x = dpp_ror_add<0x128>(x);
    x = dpp_ror_add<0x124>(x);
    x = dpp_ror_add<0x122>(x);
    x = dpp_ror_add<0x121>(x);
    return x;
}

// ---------------------------------------------------------------------------
// fp32 -> bf16 conversion, 4 elems/thread
// ---------------------------------------------------------------------------
__global__ __launch_bounds__(256) void f2bf_kernel(const float* __restrict__ in,
                                                   bf16* __restrict__ out) {
    const int64_t i = (int64_t)blockIdx.x * 256 + threadIdx.x;
    const float4 v = ((const float4*)in)[i];
    ushort4 o;
    o.x = f2bf(v.x); o.y = f2bf(v.y); o.z = f2bf(v.z); o.w = f2bf(v.w);
    ((ushort4*)out)[i] = o;
}

// ---------------------------------------------------------------------------
// bf16 MFMA GEMM NT (m97 structure, unchanged)
// ---------------------------------------------------------------------------
template <int OUTBF16>
__global__ __launch_bounds__(256) void gemm_mfma_nt(const bf16* __restrict__ A,
                                                    const bf16* __restrict__ Bm,
                                                    void* __restrict__ Cv,
                                                    int M, int N, int K) {
    __shared__ bf16 As[128 * 32];
    __shared__ bf16 Bs[128 * 32];
    const int tid = threadIdx.x;
    const int w = tid >> 6;
    const int l = tid & 63;
    const int bm = blockIdx.y, bn = blockIdx.x;

    const int srow = l >> 2;
    const int scol = (l & 3) << 3;
    const bf16* Ag = A + (size_t)(bm * 128 + w * 16 + srow) * K + scol;
    const bf16* Bg = Bm + (size_t)(bn * 128 + w * 16 + srow) * K + scol;
    bf16* Al = As + w * 16 * 32;
    bf16* Bl = Bs + w * 16 * 32;
    const size_t rstep = (size_t)64 * K;

    const int wr = (w >> 1) * 64;
    const int wc = (w & 1) * 64;
    const int fl = l & 15;
    const int fk = (l >> 4) * 8;

    f32x4 acc[4][4];
#pragma unroll
    for (int m = 0; m < 4; ++m)
#pragma unroll
        for (int n = 0; n < 4; ++n) acc[m][n] = (f32x4){0.f, 0.f, 0.f, 0.f};

    for (int k0 = 0; k0 < K; k0 += 32) {
        gld16(Ag + k0, Al);
        gld16(Ag + k0 + rstep, Al + 64 * 32);
        gld16(Bg + k0, Bl);
        gld16(Bg + k0 + rstep, Bl + 64 * 32);
        __syncthreads();

        bf16x8 af[4], bb[4];
#pragma unroll
        for (int m = 0; m < 4; ++m)
            af[m] = *(const bf16x8*)(As + (wr + m * 16 + fl) * 32 + fk);
#pragma unroll
        for (int n = 0; n < 4; ++n)
            bb[n] = *(const bf16x8*)(Bs + (wc + n * 16 + fl) * 32 + fk);
#pragma unroll
        for (int m = 0; m < 4; ++m)
#pragma unroll
            for (int n = 0; n < 4; ++n)
                acc[m][n] = __builtin_amdgcn_mfma_f32_16x16x32_bf16(
                    af[m], bb[n], acc[m][n], 0, 0, 0);
        __syncthreads();
    }

    if (OUTBF16) {
        bf16* C = (bf16*)Cv;
#pragma unroll
        for (int m = 0; m < 4; ++m)
#pragma unroll
            for (int n = 0; n < 4; ++n)
#pragma unroll
                for (int r = 0; r < 4; ++r) {
                    const int row = bm * 128 + wr + m * 16 + (l >> 4) * 4 + r;
                    const int col = bn * 128 + wc + n * 16 + fl;
                    C[(size_t)row * N + col] = f2bf(acc[m][n][r]);
                }
    } else {
        float* C = (float*)Cv;
#pragma unroll
        for (int m = 0; m < 4; ++m)
#pragma unroll
            for (int n = 0; n < 4; ++n)
#pragma unroll
                for (int r = 0; r < 4; ++r) {
                    const int row = bm * 128 + wr + m * 16 + (l >> 4) * 4 + r;
                    const int col = bn * 128 + wc + n * 16 + fl;
                    C[(size_t)row * N + col] = acc[m][n][r];
                }
    }
}

// ---------------------------------------------------------------------------
// fp32 vector GEMM (tiny ba projection)
// ---------------------------------------------------------------------------
#define BM 64
#define BN 64
#define BKK 32

__global__ __launch_bounds__(256) void gemm_nt_f32(const float* __restrict__ A,
                                                   const float* __restrict__ Bm,
                                                   float* __restrict__ C,
                                                   int M, int N, int K) {
    __shared__ float As[BKK][BM + 4];
    __shared__ float Bs[BKK][BN + 4];
    const int tid = threadIdx.x;
    const int tx = tid & 15;
    const int ty = tid >> 4;
    const int bm = blockIdx.y, bn = blockIdx.x;
    const float* Ab = A + (size_t)bm * BM * K;
    const float* Bb = Bm + (size_t)bn * BN * K;
    const int lr = tid >> 2;
    const int lc = (tid & 3) << 3;

    float c[4][4] = {{0.f, 0.f, 0.f, 0.f}, {0.f, 0.f, 0.f, 0.f},
                     {0.f, 0.f, 0.f, 0.f}, {0.f, 0.f, 0.f, 0.f}};

    for (int k0 = 0; k0 < K; k0 += BKK) {
        const float4 a0 = *(const float4*)(Ab + (size_t)lr * K + k0 + lc);
        const float4 a1 = *(const float4*)(Ab + (size_t)lr * K + k0 + lc + 4);
        const float4 b0 = *(const float4*)(Bb + (size_t)lr * K + k0 + lc);
        const float4 b1 = *(const float4*)(Bb + (size_t)lr * K + k0 + lc + 4);
        __syncthreads();
        As[lc + 0][lr] = a0.x; As[lc + 1][lr] = a0.y;
        As[lc + 2][lr] = a0.z; As[lc + 3][lr] = a0.w;
        As[lc + 4][lr] = a1.x; As[lc + 5][lr] = a1.y;
        As[lc + 6][lr] = a1.z; As[lc + 7][lr] = a1.w;
        Bs[lc + 0][lr] = b0.x; Bs[lc + 1][lr] = b0.y;
        Bs[lc + 2][lr] = b0.z; Bs[lc + 3][lr] = b0.w;
        Bs[lc + 4][lr] = b1.x; Bs[lc + 5][lr] = b1.y;
        Bs[lc + 6][lr] = b1.z; Bs[lc + 7][lr] = b1.w;
        __syncthreads();
#pragma unroll
        for (int kk = 0; kk < BKK; ++kk) {
            const float4 Av = *(const float4*)&As[kk][ty << 2];
            const float4 Bv = *(const float4*)&Bs[kk][tx << 2];
            const float aa[4] = {Av.x, Av.y, Av.z, Av.w};
            const float bb[4] = {Bv.x, Bv.y, Bv.z, Bv.w};
#pragma unroll
            for (int i = 0; i < 4; ++i)
#pragma unroll
                for (int j = 0; j < 4; ++j)
                    c[i][j] = fmaf(aa[i], bb[j], c[i][j]);
        }
    }
    float* Cp = C + (size_t)(bm * BM + (ty << 2)) * N + bn * BN + (tx << 2);
#pragma unroll
    for (int i = 0; i < 4; ++i)
        *(float4*)(Cp + (size_t)i * N) =
            make_float4(c[i][0], c[i][1], c[i][2], c[i][3]);
}

// ---------------------------------------------------------------------------
// Causal depthwise conv (K=4) + SiLU.
// q -> qf (fp32), k -> kf (fp32), v -> vbuf (bf16).
// ---------------------------------------------------------------------------
__global__ __launch_bounds__(256) void conv_silu_kernel(
    const bf16* __restrict__ qkvz, const float* __restrict__ cw,
    float* __restrict__ qf, float* __restrict__ kf, bf16* __restrict__ vbuf) {
    const int64_t idx = (int64_t)blockIdx.x * 256 + threadIdx.x;
    const int c = (int)(idx & (CONV_DIM_ - 1));
    const int64_t bs = idx >> 13;
    const int s = (int)(bs & (S_ - 1));

    int col;
    if (c < KEY_DIM_) {
        col = ((c >> 7) * 768) + (c & 127);                       // q
    } else if (c < 2 * KEY_DIM_) {
        const int c2 = c - KEY_DIM_;
        col = ((c2 >> 7) * 768) + 128 + (c2 & 127);               // k
    } else {
        const int c3 = c - 2 * KEY_DIM_;
        col = ((c3 >> 8) * 768) + 256 + (c3 & 255);               // v
    }
    const float w0 = cw[c * 4 + 0], w1 = cw[c * 4 + 1];
    const float w2 = cw[c * 4 + 2], w3 = cw[c * 4 + 3];
    const bf16* xp = qkvz + bs * (int64_t)QKVZ_DIM_ + col;
    float acc = w3 * bf2f(xp[0]);
    if (s >= 1) acc = fmaf(w2, bf2f(xp[-QKVZ_DIM_]), acc);
    if (s >= 2) acc = fmaf(w1, bf2f(xp[-2 * QKVZ_DIM_]), acc);
    if (s >= 3) acc = fmaf(w0, bf2f(xp[-3 * QKVZ_DIM_]), acc);
    const float y = silu_f(acc);
    if (c < KEY_DIM_) {
        qf[bs * KEY_DIM_ + c] = y;
    } else if (c < 2 * KEY_DIM_) {
        kf[bs * KEY_DIM_ + (c - KEY_DIM_)] = y;
    } else {
        vbuf[bs * VAL_DIM_ + (c - 2 * KEY_DIM_)] = f2bf(y);
    }
}

// ---------------------------------------------------------------------------
// Pre-normalize q/k (fp32, in place): q *= DK^-0.5/||q||, k *= 1/||k||.
// ---------------------------------------------------------------------------
__global__ __launch_bounds__(256) void normalize_qk_kernel(
    float* __restrict__ qf, float* __restrict__ kf) {
    const int wid = (blockIdx.x * 256 + threadIdx.x) >> 6;  // B*S*HK
    const int lane = threadIdx.x & 63;
    const int hk = wid & (HK_ - 1);
    const int64_t bs = wid >> 4;
    float* qp = qf + bs * KEY_DIM_ + hk * DK_ + lane * 2;
    float* kp = kf + bs * KEY_DIM_ + hk * DK_ + lane * 2;
    const f32x2 q = *(const f32x2*)qp;
    const f32x2 k = *(const f32x2*)kp;
    float qs = fmaf(q.x, q.x, q.y * q.y);
    float ks = fmaf(k.x, k.x, k.y * k.y);
#pragma unroll
    for (int m = 1; m < 64; m <<= 1) {
        qs += __shfl_xor(qs, m);
        ks += __shfl_xor(ks, m);
    }
    const float qsc = rsqrtf(qs + EPS_) * 0.08838834764831845f;  // DK^-0.5
    const float ksc = rsqrtf(ks + EPS_);
    *(f32x2*)qp = (f32x2){q.x * qsc, q.y * qsc};
    *(f32x2*)kp = (f32x2){k.x * ksc, k.y * ksc};
}

// ---------------------------------------------------------------------------
// Gate precompute: egbuf = exp(g), betabuf = sigmoid(b)
// ---------------------------------------------------------------------------
__global__ __launch_bounds__(256) void gate_kernel(
    const float* __restrict__ ba, const float* __restrict__ A_log,
    const float* __restrict__ dt_bias, float* __restrict__ egbuf,
    float* __restrict__ betabuf) {
    const int idx = blockIdx.x * 256 + threadIdx.x;   // B*S*HV
    const int hv = idx & (HV_ - 1);
    const int bs = idx >> 5;
    const int hk = hv >> 1, j = hv & 1;
    const float* p = ba + (size_t)bs * BA_DIM_ + hk * 4;
    const float bval = p[j];
    const float aval = p[2 + j];
    const float x = aval + dt_bias[hv];
    const float sp = (x > 20.f) ? x : log1pf(expf(x));
    egbuf[idx] = expf(-expf(A_log[hv]) * sp);
    betabuf[idx] = 1.f / (1.f + expf(-bval));
}

// ---------------------------------------------------------------------------
// Gated delta rule scan — hand-pipelined loads (asm global_load + counted
// s_waitcnt vmcnt). R9 structure: wave owns (b,hv,dv-block-of-4), 16-lane
// DPP reduces, XCD swizzle. Loads for step s+2 are ISSUED (volatile asm,
// un-sinkable) before step s's math; vmcnt(8) drains exactly the prior set
// (7 loads; +1 per-step store makes steady-state outstanding 16 -> wait 8;
// invariant to where the compiler places the store, which cannot sink past
// the "memory"-clobbered wait). sched_barrier(0) pins consumers (rule #18).
// ---------------------------------------------------------------------------
__global__ __launch_bounds__(256, 2) void delta_scan_kernel(
    const float* __restrict__ qf, const float* __restrict__ kf,
    const bf16* __restrict__ vbuf, const float* __restrict__ egbuf,
    const float* __restrict__ betabuf, bf16* __restrict__ core) {
    const int w = threadIdx.x >> 6;         // wave in block 0..3
    const int lane = threadIdx.x & 63;
    // --- XCD swizzle (R9, FETCH 57MB proven) ---
    const int xcd = blockIdx.x & 7;
    const int slot = blockIdx.x >> 3;       // 0..63
    const int i = ((slot >> 4) << 3) | xcd; // bhk 0..31
    const int b = i >> 4;
    const int hk = i & 15;
    const int within = slot & 15;           // 0..15
    const int hv = hk * 2 + (within >> 3);
    const int dvb = (within & 7) * 4 + w;   // 0..31
    // --- lane split ---
    const int g = lane & 15;
    const int dvi = lane >> 4;
    const int dv = (dvb << 2) + dvi;

    const float* qbase = qf + (size_t)b * S_ * KEY_DIM_ + hk * DK_ + g * 8;
    const float* kbase = kf + (size_t)b * S_ * KEY_DIM_ + hk * DK_ + g * 8;
    const bf16* vbase = vbuf + (size_t)b * S_ * VAL_DIM_ + hv * DV_ + dv;
    const float* egp = egbuf + (size_t)b * S_ * HV_ + hv;
    const float* bp = betabuf + (size_t)b * S_ * HV_ + hv;
    bf16* op = core + (size_t)b * S_ * VAL_DIM_ + hv * DV_ + dv;

    f32x2 st0 = {0.f, 0.f}, st1 = {0.f, 0.f};
    f32x2 st2 = {0.f, 0.f}, st3 = {0.f, 0.f};

    f32x4 qA0, qA1, kA0, kA1, qB0, qB1, kB0, kB1;
    unsigned vA, vB;
    float egA, btA, egB, btB;

#define ISSUE(Q0, Q1, K0, K1, VU, EG, BT, sidx)                                \
    do {                                                                       \
        const float* _q = qbase + (size_t)(sidx)*KEY_DIM_;                     \
        const float* _k = kbase + (size_t)(sidx)*KEY_DIM_;                     \
        const bf16* _v = vbase + (size_t)(sidx)*VAL_DIM_;                      \
        const float* _e = egp + (size_t)(sidx)*HV_;                            \
        const float* _bt = bp + (size_t)(sidx)*HV_;                            \
        asm volatile("global_load_dwordx4 %0, %1, off"                         \
                     : "=v"(Q0) : "v"(_q));                                    \
        asm volatile("global_load_dwordx4 %0, %1, off"                         \
                     : "=v"(Q1) : "v"(_q + 4));                                \
        asm volatile("global_load_dwordx4 %0, %1, off"                         \
                     : "=v"(K0) : "v"(_k));                                    \
        asm volatile("global_load_dwordx4 %0, %1, off"                         \
                     : "=v"(K1) : "v"(_k + 4));                                \
        asm volatile("global_load_ushort %0, %1, off"                          \
                     : "=v"(VU) : "v"(_v));                                    \
        asm volatile("global_load_dword %0, %1, off"                           \
                     : "=v"(EG) : "v"(_e));                                    \
        asm volatile("global_load_dword %0, %1, off"                           \
                     : "=v"(BT) : "v"(_bt));                                   \
    } while (0)

#define WAITP()                                                                \
    do {                                                                       \
        asm volatile("s_waitcnt vmcnt(7)" ::: "memory");                       \
        __builtin_amdgcn_sched_barrier(0);                                     \
    } while (0)
#define WAITS()                                                                \
    do {                                                                       \
        asm volatile("s_waitcnt vmcnt(8)" ::: "memory");                       \
        __builtin_amdgcn_sched_barrier(0);                                     \
    } while (0)

#define STEP(Q0, Q1, K0, K1, VU, EG, BT, sidx)                                 \
    do {                                                                       \
        const float VV = __uint_as_float((unsigned)(VU) << 16);                \
        const f32x2 k0 = __builtin_shufflevector(K0, K0, 0, 1);                \
        const f32x2 k1 = __builtin_shufflevector(K0, K0, 2, 3);                \
        const f32x2 k2 = __builtin_shufflevector(K1, K1, 0, 1);                \
        const f32x2 k3 = __builtin_shufflevector(K1, K1, 2, 3);                \
        const f32x2 q0 = __builtin_shufflevector(Q0, Q0, 0, 1);                \
        const f32x2 q1 = __builtin_shufflevector(Q0, Q0, 2, 3);                \
        const f32x2 q2 = __builtin_shufflevector(Q1, Q1, 0, 1);                \
        const f32x2 q3 = __builtin_shufflevector(Q1, Q1, 2, 3);                \
        const f32x2 eg2 = {EG, EG};                                            \
        st0 = pk_mul(st0, eg2);                                                \
        st1 = pk_mul(st1, eg2);                                                \
        st2 = pk_mul(st2, eg2);                                                \
        st3 = pk_mul(st3, eg2);                                                \
        f32x2 pa = pk_mul(k0, st0);                                            \
        pa = pk_fma(k1, st1, pa);                                              \
        f32x2 pb = pk_mul(k2, st2);                                            \
        pb = pk_fma(k3, st3, pb);                                              \
        pa = pk_add(pa, pb);                                                   \
        float p = pa.x + pa.y;                                                 \
        p = row16_sum(p);                                                      \
        const float delta = (VV - p) * BT;                                     \
        const f32x2 d2 = {delta, delta};                                       \
        st0 = pk_fma(k0, d2, st0);                                             \
        st1 = pk_fma(k1, d2, st1);                                             \
        st2 = pk_fma(k2, d2, st2);                                             \
        st3 = pk_fma(k3, d2, st3);                                             \
        f32x2 oa = pk_mul(q0, st0);                                            \
        oa = pk_fma(q1, st1, oa);                                              \
        f32x2 ob = pk_mul(q2, st2);                                            \
        ob = pk_fma(q3, st3, ob);                                              \
        oa = pk_add(oa, ob);                                                   \
        float o = oa.x + oa.y;                                                 \
        o = row16_sum(o);                                                      \
        if (g == 0) op[(size_t)(sidx)*VAL_DIM_] = f2bf(o);                     \
    } while (0)

    ISSUE(qA0, qA1, kA0, kA1, vA, egA, btA, 0);
    ISSUE(qB0, qB1, kB0, kB1, vB, egB, btB, 1);
    WAITP();  // A ready (leaves B's 7 in flight)

    for (int s = 0; s < S_; s += 2) {
        STEP(qA0, qA1, kA0, kA1, vA, egA, btA, s);
        ISSUE(qA0, qA1, kA0, kA1, vA, egA, btA, s + 2);
        WAITS();  // B ready
        STEP(qB0, qB1, kB0, kB1, vB, egB, btB, s + 1);
        ISSUE(qB0, qB1, kB0, kB1, vB, egB, btB, s + 3);
        WAITS();  // A ready
    }
#undef ISSUE
#undef WAITP
#undef WAITS
#undef STEP
}

// ---------------------------------------------------------------------------
// Gated RMSNorm in-place on bf16 core; z from bf16 qkvz.
// ---------------------------------------------------------------------------
__global__ __launch_bounds__(256) void rmsnorm_gate_kernel(
    bf16* __restrict__ core, const bf16* __restrict__ qkvz,
    const float* __restrict__ nw) {
    const int wid = (blockIdx.x * 256 + threadIdx.x) >> 6;
    const int lane = threadIdx.x & 63;
    const int hv = wid & (HV_ - 1);
    const int64_t bs = wid >> 5;
    bf16* x = core + (size_t)bs * VAL_DIM_ + hv * DV_;
    const float x0 = bf2f(x[lane]);
    const float x1 = bf2f(x[lane + 64]);
    float ss = fmaf(x0, x0, x1 * x1);
#pragma unroll
    for (int m = 1; m < 64; m <<= 1) ss += __shfl_xor(ss, m);
    const float inv = rsqrtf(ss * (1.f / 128.f) + EPS_);
    const bf16* z =
        qkvz + (size_t)bs * QKVZ_DIM_ + (hv >> 1) * 768 + 512 + (hv & 1) * 128;
    x[lane] = f2bf(x0 * inv * nw[lane] * silu_f(bf2f(z[lane])));
    x[lane + 64] =
        f2bf(x1 * inv * nw[lane + 64] * silu_f(bf2f(z[lane + 64])));
}

// ---------------------------------------------------------------------------
extern "C" void kernel_launch(void* const* d_in, const int* in_sizes, int n_in,
                              void* d_out, int out_size, void* d_ws,
                              size_t ws_size, hipStream_t stream) {
    const float* hidden  = (const float*)d_in[0];
    const float* W_qkvz  = (const float*)d_in[1];
    const float* W_ba    = (const float*)d_in[2];
    const float* conv_w  = (const float*)d_in[3];
    const float* dt_bias = (const float*)d_in[4];
    const float* A_log   = (const float*)d_in[5];
    const float* norm_w  = (const float*)d_in[6];
    const float* W_out   = (const float*)d_in[7];
    float* out = (float*)d_out;

    // workspace: ~321.1 MB (< run-proven 337.5 MB)
    bf16* hidden_bf = (bf16*)d_ws;                        //  8,388,608 e
    bf16* Wq_bf  = hidden_bf + (size_t)8388608;           // 25,165,824 e
    bf16* Wo_bf  = Wq_bf + (size_t)25165824;              //  8,388,608 e
    bf16* qkvz   = Wo_bf + (size_t)8388608;               // 50,331,648 e
    float* qf    = (float*)(qkvz + (size_t)50331648);     //  8,388,608 f
    float* kf    = qf + (size_t)8388608;                  //  8,388,608 f
    bf16* vbuf   = (bf16*)(kf + (size_t)8388608);         // 16,777,216 e
    bf16* core   = vbuf + (size_t)16777216;               // 16,777,216 e
    float* ba      = (float*)(core + (size_t)16777216);   //    262,144 f
    float* egbuf   = ba + 262144;                         //    131,072 f
    float* betabuf = egbuf + 131072;                      //    131,072 f

    const int MBS = B_ * S_;  // 4096

    // 0. fp32 -> bf16 operand conversion
    f2bf_kernel<<<8388608 / 1024, 256, 0, stream>>>(hidden, hidden_bf);
    f2bf_kernel<<<25165824 / 1024, 256, 0, stream>>>(W_qkvz, Wq_bf);
    f2bf_kernel<<<8388608 / 1024, 256, 0, stream>>>(W_out, Wo_bf);

    // 1. qkvz = hidden @ W_qkvz^T (bf16 MFMA)
    gemm_mfma_nt<1><<<dim3(QKVZ_DIM_ / 128, MBS / 128), 256, 0, stream>>>(
        hidden_bf, Wq_bf, (void*)qkvz, MBS, QKVZ_DIM_, HID_);
    // 2. ba = hidden @ W_ba^T (fp32 vector)
    gemm_nt_f32<<<dim3(BA_DIM_ / BN, MBS / BM), 256, 0, stream>>>(
        hidden, W_ba, ba, MBS, BA_DIM_, HID_);
    // 3. gates (eg = exp(g))
    gate_kernel<<<(MBS * HV_) / 256, 256, 0, stream>>>(ba, A_log, dt_bias,
                                                       egbuf, betabuf);
    // 4. causal conv + silu -> qf/kf (fp32), vbuf (bf16)
    conv_silu_kernel<<<(int)(((int64_t)MBS * CONV_DIM_) / 256), 256, 0,
                       stream>>>(qkvz, conv_w, qf, kf, vbuf);
    // 4b. pre-normalize q/k in place (fp32)
    normalize_qk_kernel<<<(MBS * HK_ * 64) / 256, 256, 0, stream>>>(qf, kf);
    // 5. gated delta rule scan -> core (bf16); 512 blocks, XCD-swizzled
    delta_scan_kernel<<<512, 256, 0, stream>>>(qf, kf, vbuf, egbuf, betabuf,
                                               core);
    // 6. gated rmsnorm (in place on bf16 core)
    rmsnorm_gate_kernel<<<(MBS * HV_ * 64) / 256, 256, 0, stream>>>(core, qkvz,
                                                                    norm_w);
    // 7. out = core @ W_out^T (bf16 MFMA -> fp32 out)
    gemm_mfma_nt<0><<<dim3(HID_ / 128, MBS / 128), 256, 0, stream>>>(
        core, Wo_bf, (void*)out, MBS, HID_, VAL_DIM_);
}

// Round 12
// 1089.903 us; speedup vs baseline: 1.3280x; 1.1791x over previous
//
#include <hip/hip_runtime.h>
#include <cstdint>
#include <cstddef>

#define B_ 2
#define S_ 2048
#define HID_ 2048
#define HK_ 16
#define HV_ 32
#define DK_ 128
#define DV_ 128
#define KEY_DIM_ 2048
#define VAL_DIM_ 4096
#define QKVZ_DIM_ 12288
#define BA_DIM_ 64
#define CONV_DIM_ 8192
#define EPS_ 1e-6f
#define NCHUNK_ 32
#define CL_ 64   // chunk length

typedef unsigned short bf16;
typedef __attribute__((ext_vector_type(8))) short bf16x8;
typedef __attribute__((ext_vector_type(4))) float f32x4;

__device__ __forceinline__ float silu_f(float x) { return x / (1.f + expf(-x)); }

__device__ __forceinline__ bf16 f2bf(float x) {
    unsigned int u = __float_as_uint(x);
    u += 0x7FFF + ((u >> 16) & 1);   // round-to-nearest-even
    return (bf16)(u >> 16);
}
__device__ __forceinline__ float bf2f(bf16 x) {
    return __uint_as_float((unsigned)x << 16);
}

typedef const __attribute__((address_space(1))) unsigned int cgu32;
typedef __attribute__((address_space(3))) unsigned int lsu32;
__device__ __forceinline__ void gld16(const void* g, void* l) {
    __builtin_amdgcn_global_load_lds((cgu32*)g, (lsu32*)l, 16, 0, 0);
}

#define MFMA16(a, b, c) __builtin_amdgcn_mfma_f32_16x16x32_bf16((a), (b), (c), 0, 0, 0)

// ---------------------------------------------------------------------------
// fp32 -> bf16 conversion, 4 elems/thread
// ---------------------------------------------------------------------------
__global__ __launch_bounds__(256) void f2bf_kernel(const float* __restrict__ in,
                                                   bf16* __restrict__ out) {
    const int64_t i = (int64_t)blockIdx.x * 256 + threadIdx.x;
    const float4 v = ((const float4*)in)[i];
    ushort4 o;
    o.x = f2bf(v.x); o.y = f2bf(v.y); o.z = f2bf(v.z); o.w = f2bf(v.w);
    ((ushort4*)out)[i] = o;
}

// ---------------------------------------------------------------------------
// bf16 MFMA GEMM NT (m97 structure, unchanged; verified R5-R11)
// ---------------------------------------------------------------------------
template <int OUTBF16>
__global__ __launch_bounds__(256) void gemm_mfma_nt(const bf16* __restrict__ A,
                                                    const bf16* __restrict__ Bm,
                                                    void* __restrict__ Cv,
                                                    int M, int N, int K) {
    __shared__ bf16 As[128 * 32];
    __shared__ bf16 Bs[128 * 32];
    const int tid = threadIdx.x;
    const int w = tid >> 6;
    const int l = tid & 63;
    const int bm = blockIdx.y, bn = blockIdx.x;

    const int srow = l >> 2;
    const int scol = (l & 3) << 3;
    const bf16* Ag = A + (size_t)(bm * 128 + w * 16 + srow) * K + scol;
    const bf16* Bg = Bm + (size_t)(bn * 128 + w * 16 + srow) * K + scol;
    bf16* Al = As + w * 16 * 32;
    bf16* Bl = Bs + w * 16 * 32;
    const size_t rstep = (size_t)64 * K;

    const int wr = (w >> 1) * 64;
    const int wc = (w & 1) * 64;
    const int fl = l & 15;
    const int fk = (l >> 4) * 8;

    f32x4 acc[4][4];
#pragma unroll
    for (int m = 0; m < 4; ++m)
#pragma unroll
        for (int n = 0; n < 4; ++n) acc[m][n] = (f32x4){0.f, 0.f, 0.f, 0.f};

    for (int k0 = 0; k0 < K; k0 += 32) {
        gld16(Ag + k0, Al);
        gld16(Ag + k0 + rstep, Al + 64 * 32);
        gld16(Bg + k0, Bl);
        gld16(Bg + k0 + rstep, Bl + 64 * 32);
        __syncthreads();

        bf16x8 af[4], bb[4];
#pragma unroll
        for (int m = 0; m < 4; ++m)
            af[m] = *(const bf16x8*)(As + (wr + m * 16 + fl) * 32 + fk);
#pragma unroll
        for (int n = 0; n < 4; ++n)
            bb[n] = *(const bf16x8*)(Bs + (wc + n * 16 + fl) * 32 + fk);
#pragma unroll
        for (int m = 0; m < 4; ++m)
#pragma unroll
            for (int n = 0; n < 4; ++n)
                acc[m][n] = MFMA16(af[m], bb[n], acc[m][n]);
        __syncthreads();
    }

    if (OUTBF16) {
        bf16* C = (bf16*)Cv;
#pragma unroll
        for (int m = 0; m < 4; ++m)
#pragma unroll
            for (int n = 0; n < 4; ++n)
#pragma unroll
                for (int r = 0; r < 4; ++r) {
                    const int row = bm * 128 + wr + m * 16 + (l >> 4) * 4 + r;
                    const int col = bn * 128 + wc + n * 16 + fl;
                    C[(size_t)row * N + col] = f2bf(acc[m][n][r]);
                }
    } else {
        float* C = (float*)Cv;
#pragma unroll
        for (int m = 0; m < 4; ++m)
#pragma unroll
            for (int n = 0; n < 4; ++n)
#pragma unroll
                for (int r = 0; r < 4; ++r) {
                    const int row = bm * 128 + wr + m * 16 + (l >> 4) * 4 + r;
                    const int col = bn * 128 + wc + n * 16 + fl;
                    C[(size_t)row * N + col] = acc[m][n][r];
                }
    }
}

// ---------------------------------------------------------------------------
// fp32 vector GEMM (tiny ba projection)
// ---------------------------------------------------------------------------
#define BM 64
#define BN 64
#define BKK 32

__global__ __launch_bounds__(256) void gemm_nt_f32(const float* __restrict__ A,
                                                   const float* __restrict__ Bm,
                                                   float* __restrict__ C,
                                                   int M, int N, int K) {
    __shared__ float As[BKK][BM + 4];
    __shared__ float Bs[BKK][BN + 4];
    const int tid = threadIdx.x;
    const int tx = tid & 15;
    const int ty = tid >> 4;
    const int bm = blockIdx.y, bn = blockIdx.x;
    const float* Ab = A + (size_t)bm * BM * K;
    const float* Bb = Bm + (size_t)bn * BN * K;
    const int lr = tid >> 2;
    const int lc = (tid & 3) << 3;

    float c[4][4] = {{0.f, 0.f, 0.f, 0.f}, {0.f, 0.f, 0.f, 0.f},
                     {0.f, 0.f, 0.f, 0.f}, {0.f, 0.f, 0.f, 0.f}};

    for (int k0 = 0; k0 < K; k0 += BKK) {
        const float4 a0 = *(const float4*)(Ab + (size_t)lr * K + k0 + lc);
        const float4 a1 = *(const float4*)(Ab + (size_t)lr * K + k0 + lc + 4);
        const float4 b0 = *(const float4*)(Bb + (size_t)lr * K + k0 + lc);
        const float4 b1 = *(const float4*)(Bb + (size_t)lr * K + k0 + lc + 4);
        __syncthreads();
        As[lc + 0][lr] = a0.x; As[lc + 1][lr] = a0.y;
        As[lc + 2][lr] = a0.z; As[lc + 3][lr] = a0.w;
        As[lc + 4][lr] = a1.x; As[lc + 5][lr] = a1.y;
        As[lc + 6][lr] = a1.z; As[lc + 7][lr] = a1.w;
        Bs[lc + 0][lr] = b0.x; Bs[lc + 1][lr] = b0.y;
        Bs[lc + 2][lr] = b0.z; Bs[lc + 3][lr] = b0.w;
        Bs[lc + 4][lr] = b1.x; Bs[lc + 5][lr] = b1.y;
        Bs[lc + 6][lr] = b1.z; Bs[lc + 7][lr] = b1.w;
        __syncthreads();
#pragma unroll
        for (int kk = 0; kk < BKK; ++kk) {
            const float4 Av = *(const float4*)&As[kk][ty << 2];
            const float4 Bv = *(const float4*)&Bs[kk][tx << 2];
            const float aa[4] = {Av.x, Av.y, Av.z, Av.w};
            const float bb[4] = {Bv.x, Bv.y, Bv.z, Bv.w};
#pragma unroll
            for (int i = 0; i < 4; ++i)
#pragma unroll
                for (int j = 0; j < 4; ++j)
                    c[i][j] = fmaf(aa[i], bb[j], c[i][j]);
        }
    }
    float* Cp = C + (size_t)(bm * BM + (ty << 2)) * N + bn * BN + (tx << 2);
#pragma unroll
    for (int i = 0; i < 4; ++i)
        *(float4*)(Cp + (size_t)i * N) =
            make_float4(c[i][0], c[i][1], c[i][2], c[i][3]);
}

// ---------------------------------------------------------------------------
// Causal depthwise conv (K=4) + SiLU: qkvz(bf16) -> qbf, kbf, vbuf (all bf16)
// ---------------------------------------------------------------------------
__global__ __launch_bounds__(256) void conv_silu_kernel(
    const bf16* __restrict__ qkvz, const float* __restrict__ cw,
    bf16* __restrict__ qbf, bf16* __restrict__ kbf, bf16* __restrict__ vbuf) {
    const int64_t idx = (int64_t)blockIdx.x * 256 + threadIdx.x;
    const int c = (int)(idx & (CONV_DIM_ - 1));
    const int64_t bs = idx >> 13;
    const int s = (int)(bs & (S_ - 1));

    int col;
    if (c < KEY_DIM_) {
        col = ((c >> 7) * 768) + (c & 127);                       // q
    } else if (c < 2 * KEY_DIM_) {
        const int c2 = c - KEY_DIM_;
        col = ((c2 >> 7) * 768) + 128 + (c2 & 127);               // k
    } else {
        const int c3 = c - 2 * KEY_DIM_;
        col = ((c3 >> 8) * 768) + 256 + (c3 & 255);               // v
    }
    const float w0 = cw[c * 4 + 0], w1 = cw[c * 4 + 1];
    const float w2 = cw[c * 4 + 2], w3 = cw[c * 4 + 3];
    const bf16* xp = qkvz + bs * (int64_t)QKVZ_DIM_ + col;
    float acc = w3 * bf2f(xp[0]);
    if (s >= 1) acc = fmaf(w2, bf2f(xp[-QKVZ_DIM_]), acc);
    if (s >= 2) acc = fmaf(w1, bf2f(xp[-2 * QKVZ_DIM_]), acc);
    if (s >= 3) acc = fmaf(w0, bf2f(xp[-3 * QKVZ_DIM_]), acc);
    const bf16 y = f2bf(silu_f(acc));
    if (c < KEY_DIM_) {
        qbf[bs * KEY_DIM_ + c] = y;
    } else if (c < 2 * KEY_DIM_) {
        kbf[bs * KEY_DIM_ + (c - KEY_DIM_)] = y;
    } else {
        vbuf[bs * VAL_DIM_ + (c - 2 * KEY_DIM_)] = y;
    }
}

// ---------------------------------------------------------------------------
// z extraction: qkvz -> zbuf[b][s][hv*128+dv]  (frees qkvz region for P1)
// ---------------------------------------------------------------------------
__global__ __launch_bounds__(256) void zcopy_kernel(const bf16* __restrict__ qkvz,
                                                    bf16* __restrict__ zbuf) {
    const int64_t idx = (int64_t)blockIdx.x * 256 + threadIdx.x;
    const int c = (int)(idx & (VAL_DIM_ - 1));
    const int64_t bs = idx >> 12;
    const int hv = c >> 7, dv = c & 127;
    zbuf[idx] =
        qkvz[bs * QKVZ_DIM_ + (hv >> 1) * 768 + 512 + (hv & 1) * 128 + dv];
}

// ---------------------------------------------------------------------------
// Pre-normalize q/k (bf16 in/out, fp32 math)
// ---------------------------------------------------------------------------
__global__ __launch_bounds__(256) void normalize_qk_kernel(
    bf16* __restrict__ qbf, bf16* __restrict__ kbf) {
    const int wid = (blockIdx.x * 256 + threadIdx.x) >> 6;  // B*S*HK
    const int lane = threadIdx.x & 63;
    const int hk = wid & (HK_ - 1);
    const int64_t bs = wid >> 4;
    bf16* qp = qbf + bs * KEY_DIM_ + hk * DK_ + lane * 2;
    bf16* kp = kbf + bs * KEY_DIM_ + hk * DK_ + lane * 2;
    const ushort2 qw = *(const ushort2*)qp;
    const ushort2 kw = *(const ushort2*)kp;
    const float q0 = bf2f(qw.x), q1 = bf2f(qw.y);
    const float k0 = bf2f(kw.x), k1 = bf2f(kw.y);
    float qs = fmaf(q0, q0, q1 * q1);
    float ks = fmaf(k0, k0, k1 * k1);
#pragma unroll
    for (int m = 1; m < 64; m <<= 1) {
        qs += __shfl_xor(qs, m);
        ks += __shfl_xor(ks, m);
    }
    const float qsc = rsqrtf(qs + EPS_) * 0.08838834764831845f;  // DK^-0.5
    const float ksc = rsqrtf(ks + EPS_);
    ushort2 oq, ok;
    oq.x = f2bf(q0 * qsc); oq.y = f2bf(q1 * qsc);
    ok.x = f2bf(k0 * ksc); ok.y = f2bf(k1 * ksc);
    *(ushort2*)qp = oq;
    *(ushort2*)kp = ok;
}

// ---------------------------------------------------------------------------
// Gate precompute: gbuf = g (RAW, log-space), betabuf = sigmoid(b)
// ---------------------------------------------------------------------------
__global__ __launch_bounds__(256) void gate_kernel(
    const float* __restrict__ ba, const float* __restrict__ A_log,
    const float* __restrict__ dt_bias, float* __restrict__ gbuf,
    float* __restrict__ betabuf) {
    const int idx = blockIdx.x * 256 + threadIdx.x;   // B*S*HV
    const int hv = idx & (HV_ - 1);
    const int bs = idx >> 5;
    const int hk = hv >> 1, j = hv & 1;
    const float* p = ba + (size_t)bs * BA_DIM_ + hk * 4;
    const float bval = p[j];
    const float aval = p[2 + j];
    const float x = aval + dt_bias[hv];
    const float sp = (x > 20.f) ? x : log1pf(expf(x));
    gbuf[idx] = -expf(A_log[hv]) * sp;
    betabuf[idx] = 1.f / (1.f + expf(-bval));
}

// ---------------------------------------------------------------------------
// PASS 1 (per chunk-head, 2048 WGs x 256 thr): precompute
//   A=tril(beta_t e^{Gt-Gs} kt.ks), T=(I+A)^-1, U=T(bV), Wk=T(b e^G K),
//   L=trilinc(e^{Gt-Gs} qt.ks), Qg=e^{Gt} q, Kg2T[dk][s]=k_s e^{GC-Gs}, gC.
// ---------------------------------------------------------------------------
__global__ __launch_bounds__(256) void p1_kernel(
    const bf16* __restrict__ qbf, const bf16* __restrict__ kbf,
    const bf16* __restrict__ vbuf, const float* __restrict__ gbuf,
    const float* __restrict__ betabuf, bf16* __restrict__ WkA,
    bf16* __restrict__ QgA, bf16* __restrict__ Kg2A, bf16* __restrict__ UA,
    bf16* __restrict__ LA, float* __restrict__ gcArr) {
    const int ch = blockIdx.x;          // bh*32 + c
    const int bh = ch >> 5, c = ch & 31;
    const int b = bh >> 5, hv = bh & 31;
    const int hk = hv >> 1;
    const int tid = threadIdx.x;
    const int w = tid >> 6, l = tid & 63;
    const int fl = l & 15, fk = (l >> 4) * 8;

    __shared__ float Gls[CL_];
    __shared__ float Bls[CL_];
    __shared__ float A_ls[CL_][CL_ + 1];
    __shared__ float T_ls[CL_][CL_];
    __shared__ bf16 Tbf[CL_ * CL_];
    __shared__ bf16 Vt[128 * 72];
    __shared__ bf16 Kt[128 * 72];

    // --- G cumsum + beta (wave 0) ---
    if (tid < 64) {
        float G = gbuf[((size_t)(b * S_ + c * 64 + tid)) * HV_ + hv];
        Bls[tid] = betabuf[((size_t)(b * S_ + c * 64 + tid)) * HV_ + hv];
#pragma unroll
        for (int d = 1; d < 64; d <<= 1) {
            const float n = __shfl_up(G, d, 64);
            if (tid >= d) G += n;
        }
        Gls[tid] = G;
        if (tid == 63) gcArr[ch] = expf(G);
    }
    __syncthreads();

    // --- KK^T and QK^T (MFMA), scale+mask -> A_ls (f32), L (global bf16) ---
    const bf16* kc = kbf + ((size_t)(b * S_ + c * 64)) * KEY_DIM_ + hk * DK_;
    const bf16* qc = qbf + ((size_t)(b * S_ + c * 64)) * KEY_DIM_ + hk * DK_;
    bf16* LC = LA + (size_t)ch * 4096;

    f32x4 accK[4], accQ[4];
#pragma unroll
    for (int n = 0; n < 4; ++n) {
        accK[n] = (f32x4){0.f, 0.f, 0.f, 0.f};
        accQ[n] = (f32x4){0.f, 0.f, 0.f, 0.f};
    }
#pragma unroll
    for (int kk = 0; kk < 4; ++kk) {
        const bf16x8 aK =
            *(const bf16x8*)(kc + (size_t)(w * 16 + fl) * KEY_DIM_ + fk + 32 * kk);
        const bf16x8 aQ =
            *(const bf16x8*)(qc + (size_t)(w * 16 + fl) * KEY_DIM_ + fk + 32 * kk);
#pragma unroll
        for (int n = 0; n < 4; ++n) {
            const bf16x8 bK = *(const bf16x8*)(kc + (size_t)(n * 16 + fl) * KEY_DIM_ +
                                               fk + 32 * kk);
            accK[n] = MFMA16(aK, bK, accK[n]);
            accQ[n] = MFMA16(aQ, bK, accQ[n]);
        }
    }
#pragma unroll
    for (int n = 0; n < 4; ++n)
#pragma unroll
        for (int r = 0; r < 4; ++r) {
            const int t = w * 16 + (l >> 4) * 4 + r;
            const int s = n * 16 + fl;
            const float eg = expf(Gls[t] - Gls[s]);
            A_ls[t][s] = (s < t) ? Bls[t] * eg * accK[n][r] : 0.f;
            const float lv = (s <= t) ? eg * accQ[n][r] : 0.f;
            LC[t * 64 + s] = f2bf(lv);
        }
    __syncthreads();

    // --- T = (I+A)^-1 forward substitution (wave 0; lane j = column) ---
    if (tid < 64) {
        const int j = tid;
        for (int t = 0; t < 64; ++t) {
            float acc = (t == j) ? 1.f : 0.f;
            for (int s = 0; s < t; ++s) acc -= A_ls[t][s] * T_ls[s][j];
            T_ls[t][j] = acc;
        }
    }
    __syncthreads();

    // --- Tbf convert; stage Vt = (beta V)^T, Kt = (beta e^G K)^T ---
    for (int i = tid; i < 4096; i += 256)
        Tbf[i] = f2bf(T_ls[i >> 6][i & 63]);
    for (int i = tid; i < 8192; i += 256) {
        const int d = i & 127, s = i >> 7;
        const float bs_ = Bls[s];
        Vt[d * 72 + s] =
            f2bf(bf2f(vbuf[((size_t)(b * S_ + c * 64 + s)) * VAL_DIM_ + hv * DV_ + d]) * bs_);
        Kt[d * 72 + s] =
            f2bf(bf2f(kc[(size_t)s * KEY_DIM_ + d]) * bs_ * expf(Gls[s]));
    }
    __syncthreads();

    // --- U = T@(bV), Wk = T@(b e^G K) ---
    bf16* UC = UA + (size_t)ch * 8192;
    bf16* WkC = WkA + (size_t)ch * 8192;
    f32x4 accU[8], accW[8];
#pragma unroll
    for (int n = 0; n < 8; ++n) {
        accU[n] = (f32x4){0.f, 0.f, 0.f, 0.f};
        accW[n] = (f32x4){0.f, 0.f, 0.f, 0.f};
    }
#pragma unroll
    for (int kk = 0; kk < 2; ++kk) {
        const bf16x8 aT = *(const bf16x8*)(Tbf + (w * 16 + fl) * 64 + fk + 32 * kk);
#pragma unroll
        for (int n = 0; n < 8; ++n) {
            const bf16x8 bV = *(const bf16x8*)(Vt + (n * 16 + fl) * 72 + fk + 32 * kk);
            const bf16x8 bK2 = *(const bf16x8*)(Kt + (n * 16 + fl) * 72 + fk + 32 * kk);
            accU[n] = MFMA16(aT, bV, accU[n]);
            accW[n] = MFMA16(aT, bK2, accW[n]);
        }
    }
#pragma unroll
    for (int n = 0; n < 8; ++n)
#pragma unroll
        for (int r = 0; r < 4; ++r) {
            const int t = w * 16 + (l >> 4) * 4 + r;
            const int col = n * 16 + fl;
            UC[t * 128 + col] = f2bf(accU[n][r]);
            WkC[t * 128 + col] = f2bf(accW[n][r]);
        }

    // --- Qg, Kg2T (elementwise) ---
    const float G63 = Gls[63];
    bf16* QgC = QgA + (size_t)ch * 8192;
    bf16* KgC = Kg2A + (size_t)ch * 8192;
    for (int i = tid; i < 8192; i += 256) {
        const int d = i & 127, t = i >> 7;
        QgC[t * 128 + d] =
            f2bf(bf2f(qc[(size_t)t * KEY_DIM_ + d]) * expf(Gls[t]));
        KgC[d * 64 + t] =
            f2bf(bf2f(kc[(size_t)t * KEY_DIM_ + d]) * expf(G63 - Gls[t]));
    }
}

// ---------------------------------------------------------------------------
// PASS 2: sequential over 32 chunks. 256 WGs = 64 heads x 4 dv-blocks(32),
// XCD-swizzled so a head's 4 WGs share one XCD's L2. State S[128,32] in f32
// MFMA accumulators + bf16 LDS copy Sbf[dv][dk].
//   Delta = U - Wk@S ; O = Qg@S + L@Delta ; S = gC*S + Kg2T@Delta
// ---------------------------------------------------------------------------
__global__ __launch_bounds__(256) void p2_kernel(
    const bf16* __restrict__ WkA, const bf16* __restrict__ QgA,
    const bf16* __restrict__ Kg2A, const bf16* __restrict__ UA,
    const bf16* __restrict__ LA, const float* __restrict__ gcArr,
    bf16* __restrict__ core) {
    const int xcd = blockIdx.x & 7;
    const int rr = blockIdx.x >> 3;       // 0..31
    const int bh = xcd * 8 + (rr & 7);    // 0..63
    const int dvb = rr >> 3;              // 0..3
    const int b = bh >> 5, hv = bh & 31;
    const int tid = threadIdx.x;
    const int w = tid >> 6, l = tid & 63;
    const int fl = l & 15, fk = (l >> 4) * 8;

    __shared__ bf16 Sbf[32 * 136];
    __shared__ bf16 Dbf[32 * 72];

    for (int i = tid; i < 32 * 136; i += 256) Sbf[i] = 0;
    f32x4 accS[2][2];
#pragma unroll
    for (int m = 0; m < 2; ++m)
#pragma unroll
        for (int n = 0; n < 2; ++n) accS[m][n] = (f32x4){0.f, 0.f, 0.f, 0.f};
    __syncthreads();

    for (int c = 0; c < NCHUNK_; ++c) {
        const size_t ch = (size_t)bh * 32 + c;
        const bf16* WkC = WkA + ch * 8192;
        const bf16* QgC = QgA + ch * 8192;
        const bf16* KgC = Kg2A + ch * 8192;
        const bf16* UC = UA + ch * 8192;
        const bf16* LC = LA + ch * 4096;

        // (a)+(b): Draw = Wk@S, Opart = Qg@S  (N-tiles n=0,1 over this dv-blk)
        f32x4 accD[2], accO[2];
#pragma unroll
        for (int n = 0; n < 2; ++n) {
            accD[n] = (f32x4){0.f, 0.f, 0.f, 0.f};
            accO[n] = (f32x4){0.f, 0.f, 0.f, 0.f};
        }
#pragma unroll
        for (int kk = 0; kk < 4; ++kk) {
            const bf16x8 bS0 = *(const bf16x8*)(Sbf + (0 * 16 + fl) * 136 + fk + 32 * kk);
            const bf16x8 bS1 = *(const bf16x8*)(Sbf + (1 * 16 + fl) * 136 + fk + 32 * kk);
            const bf16x8 aW = *(const bf16x8*)(WkC + (w * 16 + fl) * 128 + fk + 32 * kk);
            const bf16x8 aQ = *(const bf16x8*)(QgC + (w * 16 + fl) * 128 + fk + 32 * kk);
            accD[0] = MFMA16(aW, bS0, accD[0]);
            accD[1] = MFMA16(aW, bS1, accD[1]);
            accO[0] = MFMA16(aQ, bS0, accO[0]);
            accO[1] = MFMA16(aQ, bS1, accO[1]);
        }
        // Delta = U - Draw -> Dbf[dv_local][t]
#pragma unroll
        for (int n = 0; n < 2; ++n)
#pragma unroll
            for (int r = 0; r < 4; ++r) {
                const int t = w * 16 + (l >> 4) * 4 + r;
                const int dvl = n * 16 + fl;
                const float u = bf2f(UC[t * 128 + dvb * 32 + dvl]);
                Dbf[dvl * 72 + t] = f2bf(u - accD[n][r]);
            }
        __syncthreads();

        // (c): O += L@Delta
#pragma unroll
        for (int kk = 0; kk < 2; ++kk) {
            const bf16x8 bD0 = *(const bf16x8*)(Dbf + (0 * 16 + fl) * 72 + fk + 32 * kk);
            const bf16x8 bD1 = *(const bf16x8*)(Dbf + (1 * 16 + fl) * 72 + fk + 32 * kk);
            const bf16x8 aL = *(const bf16x8*)(LC + (w * 16 + fl) * 64 + fk + 32 * kk);
            accO[0] = MFMA16(aL, bD0, accO[0]);
            accO[1] = MFMA16(aL, bD1, accO[1]);
        }
        // write O
#pragma unroll
        for (int n = 0; n < 2; ++n)
#pragma unroll
            for (int r = 0; r < 4; ++r) {
                const int t = w * 16 + (l >> 4) * 4 + r;
                const int col = hv * 128 + dvb * 32 + n * 16 + fl;
                core[((size_t)(b * S_ + c * 64 + t)) * VAL_DIM_ + col] =
                    f2bf(accO[n][r]);
            }

        // (d): S = gC*S + Kg2T@Delta
        const float gc = gcArr[ch];
#pragma unroll
        for (int m = 0; m < 2; ++m)
#pragma unroll
            for (int n = 0; n < 2; ++n)
#pragma unroll
                for (int r = 0; r < 4; ++r) accS[m][n][r] *= gc;
#pragma unroll
        for (int kk = 0; kk < 2; ++kk) {
            const bf16x8 bD0 = *(const bf16x8*)(Dbf + (0 * 16 + fl) * 72 + fk + 32 * kk);
            const bf16x8 bD1 = *(const bf16x8*)(Dbf + (1 * 16 + fl) * 72 + fk + 32 * kk);
#pragma unroll
            for (int m = 0; m < 2; ++m) {
                const bf16x8 aK =
                    *(const bf16x8*)(KgC + ((2 * w + m) * 16 + fl) * 64 + fk + 32 * kk);
                accS[m][0] = MFMA16(aK, bD0, accS[m][0]);
                accS[m][1] = MFMA16(aK, bD1, accS[m][1]);
            }
        }
        __syncthreads();
        // Sbf <- accS (bf16 copy for next chunk's matmuls)
#pragma unroll
        for (int m = 0; m < 2; ++m)
#pragma unroll
            for (int n = 0; n < 2; ++n)
#pragma unroll
                for (int r = 0; r < 4; ++r) {
                    const int dk = (2 * w + m) * 16 + (l >> 4) * 4 + r;
                    const int dvl = n * 16 + fl;
                    Sbf[dvl * 136 + dk] = f2bf(accS[m][n][r]);
                }
        __syncthreads();
    }
}

// ---------------------------------------------------------------------------
// Gated RMSNorm in-place on bf16 core; z from zbuf (contiguous).
// ---------------------------------------------------------------------------
__global__ __launch_bounds__(256) void rmsnorm_gate_kernel(
    bf16* __restrict__ core, const bf16* __restrict__ zbuf,
    const float* __restrict__ nw) {
    const int wid = (blockIdx.x * 256 + threadIdx.x) >> 6;
    const int lane = threadIdx.x & 63;
    const int hv = wid & (HV_ - 1);
    const int64_t bs = wid >> 5;
    bf16* x = core + (size_t)bs * VAL_DIM_ + hv * DV_;
    const float x0 = bf2f(x[lane]);
    const float x1 = bf2f(x[lane + 64]);
    float ss = fmaf(x0, x0, x1 * x1);
#pragma unroll
    for (int m = 1; m < 64; m <<= 1) ss += __shfl_xor(ss, m);
    const float inv = rsqrtf(ss * (1.f / 128.f) + EPS_);
    const bf16* z = zbuf + (size_t)bs * VAL_DIM_ + hv * DV_;
    x[lane] = f2bf(x0 * inv * nw[lane] * silu_f(bf2f(z[lane])));
    x[lane + 64] =
        f2bf(x1 * inv * nw[lane + 64] * silu_f(bf2f(z[lane + 64])));
}

// ---------------------------------------------------------------------------
extern "C" void kernel_launch(void* const* d_in, const int* in_sizes, int n_in,
                              void* d_out, int out_size, void* d_ws,
                              size_t ws_size, hipStream_t stream) {
    const float* hidden  = (const float*)d_in[0];
    const float* W_qkvz  = (const float*)d_in[1];
    const float* W_ba    = (const float*)d_in[2];
    const float* conv_w  = (const float*)d_in[3];
    const float* dt_bias = (const float*)d_in[4];
    const float* A_log   = (const float*)d_in[5];
    const float* norm_w  = (const float*)d_in[6];
    const float* W_out   = (const float*)d_in[7];
    float* out = (float*)d_out;

    // ---- workspace (320.9 MB <= proven 321.1) ----
    // Region R (167.77 MB): GEMM staging, later ALIASED by pass-1 outputs.
    bf16* R = (bf16*)d_ws;
    bf16* hidden_bf = R;                         //  8,388,608 e
    bf16* Wq_bf = R + (size_t)8388608;           // 25,165,824 e
    bf16* qkvz  = R + (size_t)33554432;          // 50,331,648 e
    // P1 aliases (valid after conv+zcopy consume qkvz):
    bf16* WkA  = R;                              // 16,777,216 e
    bf16* QgA  = R + (size_t)16777216;           // 16,777,216 e
    bf16* Kg2A = R + (size_t)33554432;           // 16,777,216 e
    bf16* UA   = R + (size_t)50331648;           // 16,777,216 e
    bf16* LA   = R + (size_t)67108864;           //  8,388,608 e
    // non-aliased:
    bf16* Wo_bf = R + (size_t)83886080;          //  8,388,608 e
    bf16* qbf   = Wo_bf + (size_t)8388608;       //  8,388,608 e
    bf16* kbf   = qbf + (size_t)8388608;         //  8,388,608 e
    bf16* vbuf  = kbf + (size_t)8388608;         // 16,777,216 e
    bf16* zbuf  = vbuf + (size_t)16777216;       // 16,777,216 e
    bf16* core  = zbuf + (size_t)16777216;       // 16,777,216 e
    float* ba      = (float*)(core + (size_t)16777216);  // 262,144 f
    float* gbuf    = ba + 262144;                        // 131,072 f
    float* betabuf = gbuf + 131072;                      // 131,072 f
    float* gcArr   = betabuf + 131072;                   //   2,048 f

    const int MBS = B_ * S_;  // 4096

    // 0. fp32 -> bf16 operand conversion
    f2bf_kernel<<<8388608 / 1024, 256, 0, stream>>>(hidden, hidden_bf);
    f2bf_kernel<<<25165824 / 1024, 256, 0, stream>>>(W_qkvz, Wq_bf);
    f2bf_kernel<<<8388608 / 1024, 256, 0, stream>>>(W_out, Wo_bf);

    // 1. qkvz = hidden @ W_qkvz^T (bf16 MFMA)
    gemm_mfma_nt<1><<<dim3(QKVZ_DIM_ / 128, MBS / 128), 256, 0, stream>>>(
        hidden_bf, Wq_bf, (void*)qkvz, MBS, QKVZ_DIM_, HID_);
    // 2. ba = hidden @ W_ba^T (fp32 vector)
    gemm_nt_f32<<<dim3(BA_DIM_ / BN, MBS / BM), 256, 0, stream>>>(
        hidden, W_ba, ba, MBS, BA_DIM_, HID_);
    // 3. gates (raw g + beta)
    gate_kernel<<<(MBS * HV_) / 256, 256, 0, stream>>>(ba, A_log, dt_bias,
                                                       gbuf, betabuf);
    // 4. conv + silu -> qbf/kbf/vbuf ; z extraction -> zbuf
    conv_silu_kernel<<<(int)(((int64_t)MBS * CONV_DIM_) / 256), 256, 0,
                       stream>>>(qkvz, conv_w, qbf, kbf, vbuf);
    zcopy_kernel<<<(int)(((int64_t)MBS * VAL_DIM_) / 256), 256, 0, stream>>>(
        qkvz, zbuf);
    // 4b. normalize q/k
    normalize_qk_kernel<<<(MBS * HK_ * 64) / 256, 256, 0, stream>>>(qbf, kbf);
    // 5. chunked delta rule: pass 1 (parallel) + pass 2 (sequential chunks)
    p1_kernel<<<2048, 256, 0, stream>>>(qbf, kbf, vbuf, gbuf, betabuf, WkA,
                                        QgA, Kg2A, UA, LA, gcArr);
    p2_kernel<<<256, 256, 0, stream>>>(WkA, QgA, Kg2A, UA, LA, gcArr, core);
    // 6. gated rmsnorm (in place on core, z from zbuf)
    rmsnorm_gate_kernel<<<(MBS * HV_ * 64) / 256, 256, 0, stream>>>(core, zbuf,
                                                                    norm_w);
    // 7. out = core @ W_out^T (bf16 MFMA -> fp32 out)
    gemm_mfma_nt<0><<<dim3(HID_ / 128, MBS / 128), 256, 0, stream>>>(
        core, Wo_bf, (void*)out, MBS, HID_, VAL_DIM_);
}

// Round 13
// 979.970 us; speedup vs baseline: 1.4769x; 1.1122x over previous
//
#include <hip/hip_runtime.h>
#include <cstdint>
#include <cstddef>

#define B_ 2
#define S_ 2048
#define HID_ 2048
#define HK_ 16
#define HV_ 32
#define DK_ 128
#define DV_ 128
#define KEY_DIM_ 2048
#define VAL_DIM_ 4096
#define QKVZ_DIM_ 12288
#define BA_DIM_ 64
#define CONV_DIM_ 8192
#define EPS_ 1e-6f
#define NCHUNK_ 32
#define CL_ 64   // chunk length

typedef unsigned short bf16;
typedef __attribute__((ext_vector_type(8))) short bf16x8;
typedef __attribute__((ext_vector_type(8))) unsigned short u16x8;
typedef __attribute__((ext_vector_type(4))) float f32x4;

__device__ __forceinline__ float silu_f(float x) { return x / (1.f + expf(-x)); }

__device__ __forceinline__ bf16 f2bf(float x) {
    unsigned int u = __float_as_uint(x);
    u += 0x7FFF + ((u >> 16) & 1);   // round-to-nearest-even
    return (bf16)(u >> 16);
}
__device__ __forceinline__ float bf2f(bf16 x) {
    return __uint_as_float((unsigned)x << 16);
}
#define BF2F_LO(u) __uint_as_float((unsigned)(u) << 16)
#define BF2F_HI(u) __uint_as_float((unsigned)(u) & 0xFFFF0000u)

__device__ __forceinline__ float bf_lane(const uint4& x, int j) {
    const unsigned wv = (&x.x)[j >> 1];
    return (j & 1) ? BF2F_HI(wv) : BF2F_LO(wv);
}

typedef const __attribute__((address_space(1))) unsigned int cgu32;
typedef __attribute__((address_space(3))) unsigned int lsu32;
__device__ __forceinline__ void gld16(const void* g, void* l) {
    __builtin_amdgcn_global_load_lds((cgu32*)g, (lsu32*)l, 16, 0, 0);
}

#define MFMA16(a, b, c) __builtin_amdgcn_mfma_f32_16x16x32_bf16((a), (b), (c), 0, 0, 0)

// ---------------------------------------------------------------------------
// fp32 -> bf16 conversion, 4 elems/thread
// ---------------------------------------------------------------------------
__global__ __launch_bounds__(256) void f2bf_kernel(const float* __restrict__ in,
                                                   bf16* __restrict__ out) {
    const int64_t i = (int64_t)blockIdx.x * 256 + threadIdx.x;
    const float4 v = ((const float4*)in)[i];
    ushort4 o;
    o.x = f2bf(v.x); o.y = f2bf(v.y); o.z = f2bf(v.z); o.w = f2bf(v.w);
    ((ushort4*)out)[i] = o;
}

// ---------------------------------------------------------------------------
// bf16 MFMA GEMM NT (m97 structure) + bijective XCD swizzle (nwg%8==0).
// COLMAJOR picks the chunk orientation so each XCD's contiguous logical
// chunk shares the LARGER operand: COLMAJOR=1 -> chunk = few bn-columns
// (share full A), 0 -> chunk = few bm-rows (share full B).
// ---------------------------------------------------------------------------
template <int OUTBF16, int COLMAJOR>
__global__ __launch_bounds__(256) void gemm_mfma_nt(const bf16* __restrict__ A,
                                                    const bf16* __restrict__ Bm,
                                                    void* __restrict__ Cv,
                                                    int M, int N, int K) {
    __shared__ bf16 As[128 * 32];
    __shared__ bf16 Bs[128 * 32];
    const int tid = threadIdx.x;
    const int w = tid >> 6;
    const int l = tid & 63;
    // --- XCD swizzle ---
    const int nwg = gridDim.x * gridDim.y;
    const int orig = blockIdx.y * gridDim.x + blockIdx.x;
    const int swz = ((orig & 7) * (nwg >> 3)) + (orig >> 3);
    int bn, bm;
    if (COLMAJOR) {
        bm = swz % gridDim.y;
        bn = swz / gridDim.y;
    } else {
        bn = swz % gridDim.x;
        bm = swz / gridDim.x;
    }

    const int srow = l >> 2;
    const int scol = (l & 3) << 3;
    const bf16* Ag = A + (size_t)(bm * 128 + w * 16 + srow) * K + scol;
    const bf16* Bg = Bm + (size_t)(bn * 128 + w * 16 + srow) * K + scol;
    bf16* Al = As + w * 16 * 32;
    bf16* Bl = Bs + w * 16 * 32;
    const size_t rstep = (size_t)64 * K;

    const int wr = (w >> 1) * 64;
    const int wc = (w & 1) * 64;
    const int fl = l & 15;
    const int fk = (l >> 4) * 8;

    f32x4 acc[4][4];
#pragma unroll
    for (int m = 0; m < 4; ++m)
#pragma unroll
        for (int n = 0; n < 4; ++n) acc[m][n] = (f32x4){0.f, 0.f, 0.f, 0.f};

    for (int k0 = 0; k0 < K; k0 += 32) {
        gld16(Ag + k0, Al);
        gld16(Ag + k0 + rstep, Al + 64 * 32);
        gld16(Bg + k0, Bl);
        gld16(Bg + k0 + rstep, Bl + 64 * 32);
        __syncthreads();

        bf16x8 af[4], bb[4];
#pragma unroll
        for (int m = 0; m < 4; ++m)
            af[m] = *(const bf16x8*)(As + (wr + m * 16 + fl) * 32 + fk);
#pragma unroll
        for (int n = 0; n < 4; ++n)
            bb[n] = *(const bf16x8*)(Bs + (wc + n * 16 + fl) * 32 + fk);
#pragma unroll
        for (int m = 0; m < 4; ++m)
#pragma unroll
            for (int n = 0; n < 4; ++n)
                acc[m][n] = MFMA16(af[m], bb[n], acc[m][n]);
        __syncthreads();
    }

    if (OUTBF16) {
        bf16* C = (bf16*)Cv;
#pragma unroll
        for (int m = 0; m < 4; ++m)
#pragma unroll
            for (int n = 0; n < 4; ++n)
#pragma unroll
                for (int r = 0; r < 4; ++r) {
                    const int row = bm * 128 + wr + m * 16 + (l >> 4) * 4 + r;
                    const int col = bn * 128 + wc + n * 16 + fl;
                    C[(size_t)row * N + col] = f2bf(acc[m][n][r]);
                }
    } else {
        float* C = (float*)Cv;
#pragma unroll
        for (int m = 0; m < 4; ++m)
#pragma unroll
            for (int n = 0; n < 4; ++n)
#pragma unroll
                for (int r = 0; r < 4; ++r) {
                    const int row = bm * 128 + wr + m * 16 + (l >> 4) * 4 + r;
                    const int col = bn * 128 + wc + n * 16 + fl;
                    C[(size_t)row * N + col] = acc[m][n][r];
                }
    }
}

// ---------------------------------------------------------------------------
// ba projection, fp32, K-split x4 (grid (4,64) = 256 blocks -> all CUs).
// Cpart[ks][4096][64]; gate_kernel sums the 4 partials (deterministic).
// ---------------------------------------------------------------------------
#define BM 64
#define BN 64
#define BKK 32

__global__ __launch_bounds__(256) void gemm_ba_ksplit(
    const float* __restrict__ A, const float* __restrict__ Bm,
    float* __restrict__ Cpart) {
    __shared__ float As[BKK][BM + 4];
    __shared__ float Bs[BKK][BN + 4];
    const int tid = threadIdx.x;
    const int tx = tid & 15;
    const int ty = tid >> 4;
    const int ks = blockIdx.x;     // 0..3
    const int bm = blockIdx.y;     // 0..63
    const float* Ab = A + (size_t)bm * BM * HID_;
    const float* Bb = Bm;
    const int lr = tid >> 2;
    const int lc = (tid & 3) << 3;

    float c[4][4] = {{0.f, 0.f, 0.f, 0.f}, {0.f, 0.f, 0.f, 0.f},
                     {0.f, 0.f, 0.f, 0.f}, {0.f, 0.f, 0.f, 0.f}};

    const int kbeg = ks * 512;
    for (int k0 = kbeg; k0 < kbeg + 512; k0 += BKK) {
        const float4 a0 = *(const float4*)(Ab + (size_t)lr * HID_ + k0 + lc);
        const float4 a1 = *(const float4*)(Ab + (size_t)lr * HID_ + k0 + lc + 4);
        const float4 b0 = *(const float4*)(Bb + (size_t)lr * HID_ + k0 + lc);
        const float4 b1 = *(const float4*)(Bb + (size_t)lr * HID_ + k0 + lc + 4);
        __syncthreads();
        As[lc + 0][lr] = a0.x; As[lc + 1][lr] = a0.y;
        As[lc + 2][lr] = a0.z; As[lc + 3][lr] = a0.w;
        As[lc + 4][lr] = a1.x; As[lc + 5][lr] = a1.y;
        As[lc + 6][lr] = a1.z; As[lc + 7][lr] = a1.w;
        Bs[lc + 0][lr] = b0.x; Bs[lc + 1][lr] = b0.y;
        Bs[lc + 2][lr] = b0.z; Bs[lc + 3][lr] = b0.w;
        Bs[lc + 4][lr] = b1.x; Bs[lc + 5][lr] = b1.y;
        Bs[lc + 6][lr] = b1.z; Bs[lc + 7][lr] = b1.w;
        __syncthreads();
#pragma unroll
        for (int kk = 0; kk < BKK; ++kk) {
            const float4 Av = *(const float4*)&As[kk][ty << 2];
            const float4 Bv = *(const float4*)&Bs[kk][tx << 2];
            const float aa[4] = {Av.x, Av.y, Av.z, Av.w};
            const float bb[4] = {Bv.x, Bv.y, Bv.z, Bv.w};
#pragma unroll
            for (int i = 0; i < 4; ++i)
#pragma unroll
                for (int j = 0; j < 4; ++j)
                    c[i][j] = fmaf(aa[i], bb[j], c[i][j]);
        }
    }
    float* Cp = Cpart + (size_t)ks * ((size_t)B_ * S_ * 64) +
                (size_t)(bm * BM + (ty << 2)) * 64 + (tx << 2);
#pragma unroll
    for (int i = 0; i < 4; ++i)
        *(float4*)(Cp + (size_t)i * 64) =
            make_float4(c[i][0], c[i][1], c[i][2], c[i][3]);
}

// ---------------------------------------------------------------------------
// Causal depthwise conv (K=4) + SiLU, 8 channels/thread (uint4 loads,
// ushort8 stores). Also copies z channels (no conv) -> zbuf.
// Channel groups: [0,2048)q [2048,4096)k [4096,8192)v [8192,12288)z
// ---------------------------------------------------------------------------
__global__ __launch_bounds__(256) void conv_silu_kernel(
    const bf16* __restrict__ qkvz, const float* __restrict__ cw,
    bf16* __restrict__ qbf, bf16* __restrict__ kbf, bf16* __restrict__ vbuf,
    bf16* __restrict__ zbuf) {
    const int64_t idx = (int64_t)blockIdx.x * 256 + threadIdx.x;
    const int cg = (int)(idx % 1536);
    const int64_t bs = idx / 1536;
    const int s = (int)(bs & (S_ - 1));
    const int c0 = cg << 3;

    int col;
    bf16* outp;
    if (c0 < KEY_DIM_) {
        col = ((c0 >> 7) * 768) + (c0 & 127);
        outp = qbf + bs * KEY_DIM_ + c0;
    } else if (c0 < 2 * KEY_DIM_) {
        const int c2 = c0 - KEY_DIM_;
        col = ((c2 >> 7) * 768) + 128 + (c2 & 127);
        outp = kbf + bs * KEY_DIM_ + c2;
    } else if (c0 < 2 * KEY_DIM_ + VAL_DIM_) {
        const int c3 = c0 - 2 * KEY_DIM_;
        col = ((c3 >> 8) * 768) + 256 + (c3 & 255);
        outp = vbuf + bs * VAL_DIM_ + c3;
    } else {
        const int zc = c0 - (2 * KEY_DIM_ + VAL_DIM_);
        const int hv = zc >> 7;
        col = (hv >> 1) * 768 + 512 + (hv & 1) * 128 + (zc & 127);
        outp = zbuf + bs * VAL_DIM_ + zc;
    }
    const bf16* xp = qkvz + bs * (int64_t)QKVZ_DIM_ + col;
    if (c0 >= 2 * KEY_DIM_ + VAL_DIM_) {
        *(uint4*)outp = *(const uint4*)xp;   // z passthrough
        return;
    }
    const uint4 zero4 = {0u, 0u, 0u, 0u};
    const uint4 x0 = *(const uint4*)xp;
    const uint4 x1 = (s >= 1) ? *(const uint4*)(xp - QKVZ_DIM_) : zero4;
    const uint4 x2 = (s >= 2) ? *(const uint4*)(xp - 2 * QKVZ_DIM_) : zero4;
    const uint4 x3 = (s >= 3) ? *(const uint4*)(xp - 3 * QKVZ_DIM_) : zero4;
    u16x8 o;
#pragma unroll
    for (int j = 0; j < 8; ++j) {
        const float4 wv = *(const float4*)(cw + (size_t)(c0 + j) * 4);
        float acc = wv.w * bf_lane(x0, j);
        acc = fmaf(wv.z, bf_lane(x1, j), acc);
        acc = fmaf(wv.y, bf_lane(x2, j), acc);
        acc = fmaf(wv.x, bf_lane(x3, j), acc);
        o[j] = f2bf(silu_f(acc));
    }
    *(u16x8*)outp = o;
}

// ---------------------------------------------------------------------------
// Pre-normalize q/k (bf16 in/out, fp32 math)
// ---------------------------------------------------------------------------
__global__ __launch_bounds__(256) void normalize_qk_kernel(
    bf16* __restrict__ qbf, bf16* __restrict__ kbf) {
    const int wid = (blockIdx.x * 256 + threadIdx.x) >> 6;  // B*S*HK
    const int lane = threadIdx.x & 63;
    const int hk = wid & (HK_ - 1);
    const int64_t bs = wid >> 4;
    bf16* qp = qbf + bs * KEY_DIM_ + hk * DK_ + lane * 2;
    bf16* kp = kbf + bs * KEY_DIM_ + hk * DK_ + lane * 2;
    const ushort2 qw = *(const ushort2*)qp;
    const ushort2 kw = *(const ushort2*)kp;
    const float q0 = bf2f(qw.x), q1 = bf2f(qw.y);
    const float k0 = bf2f(kw.x), k1 = bf2f(kw.y);
    float qs = fmaf(q0, q0, q1 * q1);
    float ks = fmaf(k0, k0, k1 * k1);
#pragma unroll
    for (int m = 1; m < 64; m <<= 1) {
        qs += __shfl_xor(qs, m);
        ks += __shfl_xor(ks, m);
    }
    const float qsc = rsqrtf(qs + EPS_) * 0.08838834764831845f;  // DK^-0.5
    const float ksc = rsqrtf(ks + EPS_);
    ushort2 oq, ok;
    oq.x = f2bf(q0 * qsc); oq.y = f2bf(q1 * qsc);
    ok.x = f2bf(k0 * ksc); ok.y = f2bf(k1 * ksc);
    *(ushort2*)qp = oq;
    *(ushort2*)kp = ok;
}

// ---------------------------------------------------------------------------
// Gate precompute from 4 K-split partials: gbuf = g (raw), betabuf = sigmoid
// ---------------------------------------------------------------------------
__global__ __launch_bounds__(256) void gate_kernel(
    const float* __restrict__ ba_part, const float* __restrict__ A_log,
    const float* __restrict__ dt_bias, float* __restrict__ gbuf,
    float* __restrict__ betabuf) {
    const int idx = blockIdx.x * 256 + threadIdx.x;   // B*S*HV
    const int hv = idx & (HV_ - 1);
    const int bs = idx >> 5;
    const int hk = hv >> 1, j = hv & 1;
    const size_t SP = (size_t)B_ * S_ * 64;  // 262144
    const float* p = ba_part + (size_t)bs * 64 + hk * 4;
    const float bval = p[j] + p[SP + j] + p[2 * SP + j] + p[3 * SP + j];
    const float aval =
        p[2 + j] + p[SP + 2 + j] + p[2 * SP + 2 + j] + p[3 * SP + 2 + j];
    const float x = aval + dt_bias[hv];
    const float sp = (x > 20.f) ? x : log1pf(expf(x));
    gbuf[idx] = -expf(A_log[hv]) * sp;
    betabuf[idx] = 1.f / (1.f + expf(-bval));
}

// ---------------------------------------------------------------------------
// PASS 1 (per chunk-head, 2048 WGs x 256 thr) — unchanged from R12.
// ---------------------------------------------------------------------------
__global__ __launch_bounds__(256) void p1_kernel(
    const bf16* __restrict__ qbf, const bf16* __restrict__ kbf,
    const bf16* __restrict__ vbuf, const float* __restrict__ gbuf,
    const float* __restrict__ betabuf, bf16* __restrict__ WkA,
    bf16* __restrict__ QgA, bf16* __restrict__ Kg2A, bf16* __restrict__ UA,
    bf16* __restrict__ LA, float* __restrict__ gcArr) {
    const int ch = blockIdx.x;          // bh*32 + c
    const int bh = ch >> 5, c = ch & 31;
    const int b = bh >> 5, hv = bh & 31;
    const int hk = hv >> 1;
    const int tid = threadIdx.x;
    const int w = tid >> 6, l = tid & 63;
    const int fl = l & 15, fk = (l >> 4) * 8;

    __shared__ float Gls[CL_];
    __shared__ float Bls[CL_];
    __shared__ float A_ls[CL_][CL_ + 1];
    __shared__ float T_ls[CL_][CL_];
    __shared__ bf16 Tbf[CL_ * CL_];
    __shared__ bf16 Vt[128 * 72];
    __shared__ bf16 Kt[128 * 72];

    if (tid < 64) {
        float G = gbuf[((size_t)(b * S_ + c * 64 + tid)) * HV_ + hv];
        Bls[tid] = betabuf[((size_t)(b * S_ + c * 64 + tid)) * HV_ + hv];
#pragma unroll
        for (int d = 1; d < 64; d <<= 1) {
            const float n = __shfl_up(G, d, 64);
            if (tid >= d) G += n;
        }
        Gls[tid] = G;
        if (tid == 63) gcArr[ch] = expf(G);
    }
    __syncthreads();

    const bf16* kc = kbf + ((size_t)(b * S_ + c * 64)) * KEY_DIM_ + hk * DK_;
    const bf16* qc = qbf + ((size_t)(b * S_ + c * 64)) * KEY_DIM_ + hk * DK_;
    bf16* LC = LA + (size_t)ch * 4096;

    f32x4 accK[4], accQ[4];
#pragma unroll
    for (int n = 0; n < 4; ++n) {
        accK[n] = (f32x4){0.f, 0.f, 0.f, 0.f};
        accQ[n] = (f32x4){0.f, 0.f, 0.f, 0.f};
    }
#pragma unroll
    for (int kk = 0; kk < 4; ++kk) {
        const bf16x8 aK =
            *(const bf16x8*)(kc + (size_t)(w * 16 + fl) * KEY_DIM_ + fk + 32 * kk);
        const bf16x8 aQ =
            *(const bf16x8*)(qc + (size_t)(w * 16 + fl) * KEY_DIM_ + fk + 32 * kk);
#pragma unroll
        for (int n = 0; n < 4; ++n) {
            const bf16x8 bK = *(const bf16x8*)(kc + (size_t)(n * 16 + fl) * KEY_DIM_ +
                                               fk + 32 * kk);
            accK[n] = MFMA16(aK, bK, accK[n]);
            accQ[n] = MFMA16(aQ, bK, accQ[n]);
        }
    }
#pragma unroll
    for (int n = 0; n < 4; ++n)
#pragma unroll
        for (int r = 0; r < 4; ++r) {
            const int t = w * 16 + (l >> 4) * 4 + r;
            const int s = n * 16 + fl;
            const float eg = expf(Gls[t] - Gls[s]);
            A_ls[t][s] = (s < t) ? Bls[t] * eg * accK[n][r] : 0.f;
            const float lv = (s <= t) ? eg * accQ[n][r] : 0.f;
            LC[t * 64 + s] = f2bf(lv);
        }
    __syncthreads();

    if (tid < 64) {
        const int j = tid;
        for (int t = 0; t < 64; ++t) {
            float acc = (t == j) ? 1.f : 0.f;
            for (int s = 0; s < t; ++s) acc -= A_ls[t][s] * T_ls[s][j];
            T_ls[t][j] = acc;
        }
    }
    __syncthreads();

    for (int i = tid; i < 4096; i += 256)
        Tbf[i] = f2bf(T_ls[i >> 6][i & 63]);
    for (int i = tid; i < 8192; i += 256) {
        const int d = i & 127, s = i >> 7;
        const float bs_ = Bls[s];
        Vt[d * 72 + s] =
            f2bf(bf2f(vbuf[((size_t)(b * S_ + c * 64 + s)) * VAL_DIM_ + hv * DV_ + d]) * bs_);
        Kt[d * 72 + s] =
            f2bf(bf2f(kc[(size_t)s * KEY_DIM_ + d]) * bs_ * expf(Gls[s]));
    }
    __syncthreads();

    bf16* UC = UA + (size_t)ch * 8192;
    bf16* WkC = WkA + (size_t)ch * 8192;
    f32x4 accU[8], accW[8];
#pragma unroll
    for (int n = 0; n < 8; ++n) {
        accU[n] = (f32x4){0.f, 0.f, 0.f, 0.f};
        accW[n] = (f32x4){0.f, 0.f, 0.f, 0.f};
    }
#pragma unroll
    for (int kk = 0; kk < 2; ++kk) {
        const bf16x8 aT = *(const bf16x8*)(Tbf + (w * 16 + fl) * 64 + fk + 32 * kk);
#pragma unroll
        for (int n = 0; n < 8; ++n) {
            const bf16x8 bV = *(const bf16x8*)(Vt + (n * 16 + fl) * 72 + fk + 32 * kk);
            const bf16x8 bK2 = *(const bf16x8*)(Kt + (n * 16 + fl) * 72 + fk + 32 * kk);
            accU[n] = MFMA16(aT, bV, accU[n]);
            accW[n] = MFMA16(aT, bK2, accW[n]);
        }
    }
#pragma unroll
    for (int n = 0; n < 8; ++n)
#pragma unroll
        for (int r = 0; r < 4; ++r) {
            const int t = w * 16 + (l >> 4) * 4 + r;
            const int col = n * 16 + fl;
            UC[t * 128 + col] = f2bf(accU[n][r]);
            WkC[t * 128 + col] = f2bf(accW[n][r]);
        }

    const float G63 = Gls[63];
    bf16* QgC = QgA + (size_t)ch * 8192;
    bf16* KgC = Kg2A + (size_t)ch * 8192;
    for (int i = tid; i < 8192; i += 256) {
        const int d = i & 127, t = i >> 7;
        QgC[t * 128 + d] =
            f2bf(bf2f(qc[(size_t)t * KEY_DIM_ + d]) * expf(Gls[t]));
        KgC[d * 64 + t] =
            f2bf(bf2f(kc[(size_t)t * KEY_DIM_ + d]) * expf(G63 - Gls[t]));
    }
}

// ---------------------------------------------------------------------------
// PASS 2 — unchanged from R12 (sequential chunks, MFMA state update).
// ---------------------------------------------------------------------------
__global__ __launch_bounds__(256) void p2_kernel(
    const bf16* __restrict__ WkA, const bf16* __restrict__ QgA,
    const bf16* __restrict__ Kg2A, const bf16* __restrict__ UA,
    const bf16* __restrict__ LA, const float* __restrict__ gcArr,
    bf16* __restrict__ core) {
    const int xcd = blockIdx.x & 7;
    const int rr = blockIdx.x >> 3;       // 0..31
    const int bh = xcd * 8 + (rr & 7);    // 0..63
    const int dvb = rr >> 3;              // 0..3
    const int b = bh >> 5, hv = bh & 31;
    const int tid = threadIdx.x;
    const int w = tid >> 6, l = tid & 63;
    const int fl = l & 15, fk = (l >> 4) * 8;

    __shared__ bf16 Sbf[32 * 136];
    __shared__ bf16 Dbf[32 * 72];

    for (int i = tid; i < 32 * 136; i += 256) Sbf[i] = 0;
    f32x4 accS[2][2];
#pragma unroll
    for (int m = 0; m < 2; ++m)
#pragma unroll
        for (int n = 0; n < 2; ++n) accS[m][n] = (f32x4){0.f, 0.f, 0.f, 0.f};
    __syncthreads();

    for (int c = 0; c < NCHUNK_; ++c) {
        const size_t ch = (size_t)bh * 32 + c;
        const bf16* WkC = WkA + ch * 8192;
        const bf16* QgC = QgA + ch * 8192;
        const bf16* KgC = Kg2A + ch * 8192;
        const bf16* UC = UA + ch * 8192;
        const bf16* LC = LA + ch * 4096;

        f32x4 accD[2], accO[2];
#pragma unroll
        for (int n = 0; n < 2; ++n) {
            accD[n] = (f32x4){0.f, 0.f, 0.f, 0.f};
            accO[n] = (f32x4){0.f, 0.f, 0.f, 0.f};
        }
#pragma unroll
        for (int kk = 0; kk < 4; ++kk) {
            const bf16x8 bS0 = *(const bf16x8*)(Sbf + (0 * 16 + fl) * 136 + fk + 32 * kk);
            const bf16x8 bS1 = *(const bf16x8*)(Sbf + (1 * 16 + fl) * 136 + fk + 32 * kk);
            const bf16x8 aW = *(const bf16x8*)(WkC + (w * 16 + fl) * 128 + fk + 32 * kk);
            const bf16x8 aQ = *(const bf16x8*)(QgC + (w * 16 + fl) * 128 + fk + 32 * kk);
            accD[0] = MFMA16(aW, bS0, accD[0]);
            accD[1] = MFMA16(aW, bS1, accD[1]);
            accO[0] = MFMA16(aQ, bS0, accO[0]);
            accO[1] = MFMA16(aQ, bS1, accO[1]);
        }
#pragma unroll
        for (int n = 0; n < 2; ++n)
#pragma unroll
            for (int r = 0; r < 4; ++r) {
                const int t = w * 16 + (l >> 4) * 4 + r;
                const int dvl = n * 16 + fl;
                const float u = bf2f(UC[t * 128 + dvb * 32 + dvl]);
                Dbf[dvl * 72 + t] = f2bf(u - accD[n][r]);
            }
        __syncthreads();

#pragma unroll
        for (int kk = 0; kk < 2; ++kk) {
            const bf16x8 bD0 = *(const bf16x8*)(Dbf + (0 * 16 + fl) * 72 + fk + 32 * kk);
            const bf16x8 bD1 = *(const bf16x8*)(Dbf + (1 * 16 + fl) * 72 + fk + 32 * kk);
            const bf16x8 aL = *(const bf16x8*)(LC + (w * 16 + fl) * 64 + fk + 32 * kk);
            accO[0] = MFMA16(aL, bD0, accO[0]);
            accO[1] = MFMA16(aL, bD1, accO[1]);
        }
#pragma unroll
        for (int n = 0; n < 2; ++n)
#pragma unroll
            for (int r = 0; r < 4; ++r) {
                const int t = w * 16 + (l >> 4) * 4 + r;
                const int col = hv * 128 + dvb * 32 + n * 16 + fl;
                core[((size_t)(b * S_ + c * 64 + t)) * VAL_DIM_ + col] =
                    f2bf(accO[n][r]);
            }

        const float gc = gcArr[ch];
#pragma unroll
        for (int m = 0; m < 2; ++m)
#pragma unroll
            for (int n = 0; n < 2; ++n)
#pragma unroll
                for (int r = 0; r < 4; ++r) accS[m][n][r] *= gc;
#pragma unroll
        for (int kk = 0; kk < 2; ++kk) {
            const bf16x8 bD0 = *(const bf16x8*)(Dbf + (0 * 16 + fl) * 72 + fk + 32 * kk);
            const bf16x8 bD1 = *(const bf16x8*)(Dbf + (1 * 16 + fl) * 72 + fk + 32 * kk);
#pragma unroll
            for (int m = 0; m < 2; ++m) {
                const bf16x8 aK =
                    *(const bf16x8*)(KgC + ((2 * w + m) * 16 + fl) * 64 + fk + 32 * kk);
                accS[m][0] = MFMA16(aK, bD0, accS[m][0]);
                accS[m][1] = MFMA16(aK, bD1, accS[m][1]);
            }
        }
        __syncthreads();
#pragma unroll
        for (int m = 0; m < 2; ++m)
#pragma unroll
            for (int n = 0; n < 2; ++n)
#pragma unroll
                for (int r = 0; r < 4; ++r) {
                    const int dk = (2 * w + m) * 16 + (l >> 4) * 4 + r;
                    const int dvl = n * 16 + fl;
                    Sbf[dvl * 136 + dk] = f2bf(accS[m][n][r]);
                }
        __syncthreads();
    }
}

// ---------------------------------------------------------------------------
// Gated RMSNorm in-place on bf16 core; z from zbuf (contiguous).
// ---------------------------------------------------------------------------
__global__ __launch_bounds__(256) void rmsnorm_gate_kernel(
    bf16* __restrict__ core, const bf16* __restrict__ zbuf,
    const float* __restrict__ nw) {
    const int wid = (blockIdx.x * 256 + threadIdx.x) >> 6;
    const int lane = threadIdx.x & 63;
    const int hv = wid & (HV_ - 1);
    const int64_t bs = wid >> 5;
    bf16* x = core + (size_t)bs * VAL_DIM_ + hv * DV_;
    const float x0 = bf2f(x[lane]);
    const float x1 = bf2f(x[lane + 64]);
    float ss = fmaf(x0, x0, x1 * x1);
#pragma unroll
    for (int m = 1; m < 64; m <<= 1) ss += __shfl_xor(ss, m);
    const float inv = rsqrtf(ss * (1.f / 128.f) + EPS_);
    const bf16* z = zbuf + (size_t)bs * VAL_DIM_ + hv * DV_;
    x[lane] = f2bf(x0 * inv * nw[lane] * silu_f(bf2f(z[lane])));
    x[lane + 64] =
        f2bf(x1 * inv * nw[lane + 64] * silu_f(bf2f(z[lane + 64])));
}

// ---------------------------------------------------------------------------
extern "C" void kernel_launch(void* const* d_in, const int* in_sizes, int n_in,
                              void* d_out, int out_size, void* d_ws,
                              size_t ws_size, hipStream_t stream) {
    const float* hidden  = (const float*)d_in[0];
    const float* W_qkvz  = (const float*)d_in[1];
    const float* W_ba    = (const float*)d_in[2];
    const float* conv_w  = (const float*)d_in[3];
    const float* dt_bias = (const float*)d_in[4];
    const float* A_log   = (const float*)d_in[5];
    const float* norm_w  = (const float*)d_in[6];
    const float* W_out   = (const float*)d_in[7];
    float* out = (float*)d_out;

    // ---- workspace (~324 MB <= proven 337.5) ----
    bf16* R = (bf16*)d_ws;
    bf16* hidden_bf = R;                         //  8,388,608 e
    bf16* Wq_bf = R + (size_t)8388608;           // 25,165,824 e
    bf16* qkvz  = R + (size_t)33554432;          // 50,331,648 e
    // P1 aliases (valid once conv has consumed qkvz):
    bf16* WkA  = R;                              // 16,777,216 e
    bf16* QgA  = R + (size_t)16777216;           // 16,777,216 e
    bf16* Kg2A = R + (size_t)33554432;           // 16,777,216 e
    bf16* UA   = R + (size_t)50331648;           // 16,777,216 e
    bf16* LA   = R + (size_t)67108864;           //  8,388,608 e
    // non-aliased:
    bf16* Wo_bf = R + (size_t)83886080;          //  8,388,608 e
    bf16* qbf   = Wo_bf + (size_t)8388608;       //  8,388,608 e
    bf16* kbf   = qbf + (size_t)8388608;         //  8,388,608 e
    bf16* vbuf  = kbf + (size_t)8388608;         // 16,777,216 e
    bf16* zbuf  = vbuf + (size_t)16777216;       // 16,777,216 e
    bf16* core  = zbuf + (size_t)16777216;       // 16,777,216 e
    float* ba_part = (float*)(core + (size_t)16777216);  // 1,048,576 f
    float* gbuf    = ba_part + 1048576;                  //   131,072 f
    float* betabuf = gbuf + 131072;                      //   131,072 f
    float* gcArr   = betabuf + 131072;                   //     2,048 f

    const int MBS = B_ * S_;  // 4096

    // 0. fp32 -> bf16 operand conversion
    f2bf_kernel<<<8388608 / 1024, 256, 0, stream>>>(hidden, hidden_bf);
    f2bf_kernel<<<25165824 / 1024, 256, 0, stream>>>(W_qkvz, Wq_bf);
    f2bf_kernel<<<8388608 / 1024, 256, 0, stream>>>(W_out, Wo_bf);

    // 1. qkvz = hidden @ W_qkvz^T (bf16 MFMA, XCD col-chunks: share W 50MB)
    gemm_mfma_nt<1, 1><<<dim3(QKVZ_DIM_ / 128, MBS / 128), 256, 0, stream>>>(
        hidden_bf, Wq_bf, (void*)qkvz, MBS, QKVZ_DIM_, HID_);
    // 2. ba = hidden @ W_ba^T (fp32, K-split x4 -> 256 blocks)
    gemm_ba_ksplit<<<dim3(4, 64), 256, 0, stream>>>(hidden, W_ba, ba_part);
    // 3. gates (sum partials; raw g + beta)
    gate_kernel<<<(MBS * HV_) / 256, 256, 0, stream>>>(ba_part, A_log, dt_bias,
                                                       gbuf, betabuf);
    // 4. conv + silu (8-wide) + z copy
    conv_silu_kernel<<<(int)(((int64_t)MBS * 1536) / 256), 256, 0, stream>>>(
        qkvz, conv_w, qbf, kbf, vbuf, zbuf);
    // 4b. normalize q/k
    normalize_qk_kernel<<<(MBS * HK_ * 64) / 256, 256, 0, stream>>>(qbf, kbf);
    // 5. chunked delta rule
    p1_kernel<<<2048, 256, 0, stream>>>(qbf, kbf, vbuf, gbuf, betabuf, WkA,
                                        QgA, Kg2A, UA, LA, gcArr);
    p2_kernel<<<256, 256, 0, stream>>>(WkA, QgA, Kg2A, UA, LA, gcArr, core);
    // 6. gated rmsnorm
    rmsnorm_gate_kernel<<<(MBS * HV_ * 64) / 256, 256, 0, stream>>>(core, zbuf,
                                                                    norm_w);
    // 7. out = core @ W_out^T (bf16 MFMA, XCD row-chunks: share core 33MB)
    gemm_mfma_nt<0, 0><<<dim3(HID_ / 128, MBS / 128), 256, 0, stream>>>(
        core, Wo_bf, (void*)out, MBS, HID_, VAL_DIM_);
}

// Round 14
// 904.139 us; speedup vs baseline: 1.6008x; 1.0839x over previous
//
#include <hip/hip_runtime.h>
#include <cstdint>
#include <cstddef>

#define B_ 2
#define S_ 2048
#define HID_ 2048
#define HK_ 16
#define HV_ 32
#define DK_ 128
#define DV_ 128
#define KEY_DIM_ 2048
#define VAL_DIM_ 4096
#define QKVZ_DIM_ 12288
#define BA_DIM_ 64
#define CONV_DIM_ 8192
#define EPS_ 1e-6f
#define NCHUNK_ 32
#define CL_ 64   // chunk length

typedef unsigned short bf16;
typedef __attribute__((ext_vector_type(8))) short bf16x8;
typedef __attribute__((ext_vector_type(8))) unsigned short u16x8;
typedef __attribute__((ext_vector_type(4))) float f32x4;

__device__ __forceinline__ float silu_f(float x) { return x / (1.f + expf(-x)); }

__device__ __forceinline__ bf16 f2bf(float x) {
    unsigned int u = __float_as_uint(x);
    u += 0x7FFF + ((u >> 16) & 1);   // round-to-nearest-even
    return (bf16)(u >> 16);
}
__device__ __forceinline__ float bf2f(bf16 x) {
    return __uint_as_float((unsigned)x << 16);
}
#define BF2F_LO(u) __uint_as_float((unsigned)(u) << 16)
#define BF2F_HI(u) __uint_as_float((unsigned)(u) & 0xFFFF0000u)

__device__ __forceinline__ float bf_lane(const uint4& x, int j) {
    const unsigned wv = (&x.x)[j >> 1];
    return (j & 1) ? BF2F_HI(wv) : BF2F_LO(wv);
}

typedef const __attribute__((address_space(1))) unsigned int cgu32;
typedef __attribute__((address_space(3))) unsigned int lsu32;
__device__ __forceinline__ void gld16(const void* g, void* l) {
    __builtin_amdgcn_global_load_lds((cgu32*)g, (lsu32*)l, 16, 0, 0);
}

#define MFMA16(a, b, c) __builtin_amdgcn_mfma_f32_16x16x32_bf16((a), (b), (c), 0, 0, 0)

// ---------------------------------------------------------------------------
// fp32 -> bf16 conversion, 4 elems/thread
// ---------------------------------------------------------------------------
__global__ __launch_bounds__(256) void f2bf_kernel(const float* __restrict__ in,
                                                   bf16* __restrict__ out) {
    const int64_t i = (int64_t)blockIdx.x * 256 + threadIdx.x;
    const float4 v = ((const float4*)in)[i];
    ushort4 o;
    o.x = f2bf(v.x); o.y = f2bf(v.y); o.z = f2bf(v.z); o.w = f2bf(v.w);
    ((ushort4*)out)[i] = o;
}

// ---------------------------------------------------------------------------
// 256x256-tile bf16 MFMA GEMM NT, 512 threads (8 waves, 2Mx4N), BK=32,
// 3-slot LDS ring (96 KB), counted vmcnt(4) (loads stay in flight across
// barriers), one raw s_barrier/iter, setprio around MFMA cluster.
// Race-free by construction: tile t+2 stages into slot (t+2)%3, whose reads
// finished at iteration t-1 (full iteration of slack before data can land).
// LDS chunk-XOR swizzle (chunk ^= row&3, 16B units) applied on BOTH the
// pre-swizzled global source and the ds_read offset (involution).
// ---------------------------------------------------------------------------
__global__ __launch_bounds__(512, 2) void gemm256_nt(
    const bf16* __restrict__ A, const bf16* __restrict__ Bm,
    bf16* __restrict__ C, int M, int N, int K) {
    __shared__ bf16 ringA[3][8192];   // [slot][256 rows x 32 k]
    __shared__ bf16 ringB[3][8192];
    const int tid = threadIdx.x;
    const int w = tid >> 6;           // 0..7
    const int l = tid & 63;
    const int wm = w >> 2;            // 0..1
    const int wn = w & 3;             // 0..3
    const int fl = l & 15;
    const int fk = (l >> 4) * 8;
    const int bm = blockIdx.y, bn = blockIdx.x;

    // --- staging addresses (per thread): row = j*128 + tid/4, chunk swz ---
    const int srow = tid >> 2;                         // 0..127
    const int scol = (((tid & 3) ^ ((tid >> 2) & 3)) << 3);  // swizzled src k
    const bf16* Ag0 = A + (size_t)(bm * 256 + srow) * K + scol;
    const bf16* Ag1 = A + (size_t)(bm * 256 + 128 + srow) * K + scol;
    const bf16* Bg0 = Bm + (size_t)(bn * 256 + srow) * K + scol;
    const bf16* Bg1 = Bm + (size_t)(bn * 256 + 128 + srow) * K + scol;

    // --- ds_read element offsets (swizzled): row*32 + (fk ^ ((fl&3)*8)) ---
    const int kswz = fk ^ ((fl & 3) << 3);
    int aoff[8], boff[4];
#pragma unroll
    for (int mi = 0; mi < 8; ++mi)
        aoff[mi] = (wm * 128 + mi * 16 + fl) * 32 + kswz;
#pragma unroll
    for (int ni = 0; ni < 4; ++ni)
        boff[ni] = (wn * 64 + ni * 16 + fl) * 32 + kswz;

    f32x4 acc[8][4];
#pragma unroll
    for (int mi = 0; mi < 8; ++mi)
#pragma unroll
        for (int ni = 0; ni < 4; ++ni) acc[mi][ni] = (f32x4){0.f, 0.f, 0.f, 0.f};

#define STAGE256(kt, slot)                                                     \
    do {                                                                       \
        const int _k = (kt) * 32;                                              \
        gld16(Ag0 + _k, &ringA[slot][w * 512]);                                \
        gld16(Ag1 + _k, &ringA[slot][4096 + w * 512]);                         \
        gld16(Bg0 + _k, &ringB[slot][w * 512]);                                \
        gld16(Bg1 + _k, &ringB[slot][4096 + w * 512]);                         \
    } while (0)

    const int nkt = K >> 5;           // 64 for K=2048
    STAGE256(0, 0);
    STAGE256(1, 1);

    for (int t = 0; t < nkt; ++t) {
        asm volatile("s_waitcnt vmcnt(4)" ::: "memory");  // tile t landed
        __builtin_amdgcn_s_barrier();
        __builtin_amdgcn_sched_barrier(0);
        const int slot = t % 3;
        const bf16* As_ = ringA[slot];
        const bf16* Bs_ = ringB[slot];
        bf16x8 af[8], bfr[4];
#pragma unroll
        for (int mi = 0; mi < 8; ++mi)
            af[mi] = *(const bf16x8*)(As_ + aoff[mi]);
#pragma unroll
        for (int ni = 0; ni < 4; ++ni)
            bfr[ni] = *(const bf16x8*)(Bs_ + boff[ni]);
        // stage tile t+2 (clamped at tail to keep vmcnt counting uniform;
        // clamped writes land in slots never read again)
        const int kt2 = (t + 2 < nkt) ? (t + 2) : (nkt - 1);
        STAGE256(kt2, (t + 2) % 3);
        asm volatile("s_waitcnt lgkmcnt(0)" ::: "memory");
        __builtin_amdgcn_sched_barrier(0);
        __builtin_amdgcn_s_setprio(1);
#pragma unroll
        for (int mi = 0; mi < 8; ++mi)
#pragma unroll
            for (int ni = 0; ni < 4; ++ni)
                acc[mi][ni] = MFMA16(af[mi], bfr[ni], acc[mi][ni]);
        __builtin_amdgcn_s_setprio(0);
    }
#undef STAGE256

    // epilogue: C/D map col=lane&15, row=(lane>>4)*4+r (verified)
#pragma unroll
    for (int mi = 0; mi < 8; ++mi)
#pragma unroll
        for (int ni = 0; ni < 4; ++ni)
#pragma unroll
            for (int r = 0; r < 4; ++r) {
                const int row = bm * 256 + wm * 128 + mi * 16 + (l >> 4) * 4 + r;
                const int col = bn * 256 + wn * 64 + ni * 16 + fl;
                C[(size_t)row * N + col] = f2bf(acc[mi][ni][r]);
            }
}

// ---------------------------------------------------------------------------
// bf16 MFMA GEMM NT (m97 structure, R12 plain mapping) — used for out-GEMM.
// ---------------------------------------------------------------------------
template <int OUTBF16>
__global__ __launch_bounds__(256) void gemm_mfma_nt(const bf16* __restrict__ A,
                                                    const bf16* __restrict__ Bm,
                                                    void* __restrict__ Cv,
                                                    int M, int N, int K) {
    __shared__ bf16 As[128 * 32];
    __shared__ bf16 Bs[128 * 32];
    const int tid = threadIdx.x;
    const int w = tid >> 6;
    const int l = tid & 63;
    const int bm = blockIdx.y, bn = blockIdx.x;

    const int srow = l >> 2;
    const int scol = (l & 3) << 3;
    const bf16* Ag = A + (size_t)(bm * 128 + w * 16 + srow) * K + scol;
    const bf16* Bg = Bm + (size_t)(bn * 128 + w * 16 + srow) * K + scol;
    bf16* Al = As + w * 16 * 32;
    bf16* Bl = Bs + w * 16 * 32;
    const size_t rstep = (size_t)64 * K;

    const int wr = (w >> 1) * 64;
    const int wc = (w & 1) * 64;
    const int fl = l & 15;
    const int fk = (l >> 4) * 8;

    f32x4 acc[4][4];
#pragma unroll
    for (int m = 0; m < 4; ++m)
#pragma unroll
        for (int n = 0; n < 4; ++n) acc[m][n] = (f32x4){0.f, 0.f, 0.f, 0.f};

    for (int k0 = 0; k0 < K; k0 += 32) {
        gld16(Ag + k0, Al);
        gld16(Ag + k0 + rstep, Al + 64 * 32);
        gld16(Bg + k0, Bl);
        gld16(Bg + k0 + rstep, Bl + 64 * 32);
        __syncthreads();

        bf16x8 af[4], bb[4];
#pragma unroll
        for (int m = 0; m < 4; ++m)
            af[m] = *(const bf16x8*)(As + (wr + m * 16 + fl) * 32 + fk);
#pragma unroll
        for (int n = 0; n < 4; ++n)
            bb[n] = *(const bf16x8*)(Bs + (wc + n * 16 + fl) * 32 + fk);
#pragma unroll
        for (int m = 0; m < 4; ++m)
#pragma unroll
            for (int n = 0; n < 4; ++n)
                acc[m][n] = MFMA16(af[m], bb[n], acc[m][n]);
        __syncthreads();
    }

    if (OUTBF16) {
        bf16* C = (bf16*)Cv;
#pragma unroll
        for (int m = 0; m < 4; ++m)
#pragma unroll
            for (int n = 0; n < 4; ++n)
#pragma unroll
                for (int r = 0; r < 4; ++r) {
                    const int row = bm * 128 + wr + m * 16 + (l >> 4) * 4 + r;
                    const int col = bn * 128 + wc + n * 16 + fl;
                    C[(size_t)row * N + col] = f2bf(acc[m][n][r]);
                }
    } else {
        float* C = (float*)Cv;
#pragma unroll
        for (int m = 0; m < 4; ++m)
#pragma unroll
            for (int n = 0; n < 4; ++n)
#pragma unroll
                for (int r = 0; r < 4; ++r) {
                    const int row = bm * 128 + wr + m * 16 + (l >> 4) * 4 + r;
                    const int col = bn * 128 + wc + n * 16 + fl;
                    C[(size_t)row * N + col] = acc[m][n][r];
                }
    }
}

// ---------------------------------------------------------------------------
// ba projection, fp32, K-split x4 (grid (4,64) = 256 blocks -> all CUs).
// ---------------------------------------------------------------------------
#define BM 64
#define BN 64
#define BKK 32

__global__ __launch_bounds__(256) void gemm_ba_ksplit(
    const float* __restrict__ A, const float* __restrict__ Bm,
    float* __restrict__ Cpart) {
    __shared__ float As[BKK][BM + 4];
    __shared__ float Bs[BKK][BN + 4];
    const int tid = threadIdx.x;
    const int tx = tid & 15;
    const int ty = tid >> 4;
    const int ks = blockIdx.x;     // 0..3
    const int bm = blockIdx.y;     // 0..63
    const float* Ab = A + (size_t)bm * BM * HID_;
    const float* Bb = Bm;
    const int lr = tid >> 2;
    const int lc = (tid & 3) << 3;

    float c[4][4] = {{0.f, 0.f, 0.f, 0.f}, {0.f, 0.f, 0.f, 0.f},
                     {0.f, 0.f, 0.f, 0.f}, {0.f, 0.f, 0.f, 0.f}};

    const int kbeg = ks * 512;
    for (int k0 = kbeg; k0 < kbeg + 512; k0 += BKK) {
        const float4 a0 = *(const float4*)(Ab + (size_t)lr * HID_ + k0 + lc);
        const float4 a1 = *(const float4*)(Ab + (size_t)lr * HID_ + k0 + lc + 4);
        const float4 b0 = *(const float4*)(Bb + (size_t)lr * HID_ + k0 + lc);
        const float4 b1 = *(const float4*)(Bb + (size_t)lr * HID_ + k0 + lc + 4);
        __syncthreads();
        As[lc + 0][lr] = a0.x; As[lc + 1][lr] = a0.y;
        As[lc + 2][lr] = a0.z; As[lc + 3][lr] = a0.w;
        As[lc + 4][lr] = a1.x; As[lc + 5][lr] = a1.y;
        As[lc + 6][lr] = a1.z; As[lc + 7][lr] = a1.w;
        Bs[lc + 0][lr] = b0.x; Bs[lc + 1][lr] = b0.y;
        Bs[lc + 2][lr] = b0.z; Bs[lc + 3][lr] = b0.w;
        Bs[lc + 4][lr] = b1.x; Bs[lc + 5][lr] = b1.y;
        Bs[lc + 6][lr] = b1.z; Bs[lc + 7][lr] = b1.w;
        __syncthreads();
#pragma unroll
        for (int kk = 0; kk < BKK; ++kk) {
            const float4 Av = *(const float4*)&As[kk][ty << 2];
            const float4 Bv = *(const float4*)&Bs[kk][tx << 2];
            const float aa[4] = {Av.x, Av.y, Av.z, Av.w};
            const float bb[4] = {Bv.x, Bv.y, Bv.z, Bv.w};
#pragma unroll
            for (int i = 0; i < 4; ++i)
#pragma unroll
                for (int j = 0; j < 4; ++j)
                    c[i][j] = fmaf(aa[i], bb[j], c[i][j]);
        }
    }
    float* Cp = Cpart + (size_t)ks * ((size_t)B_ * S_ * 64) +
                (size_t)(bm * BM + (ty << 2)) * 64 + (tx << 2);
#pragma unroll
    for (int i = 0; i < 4; ++i)
        *(float4*)(Cp + (size_t)i * 64) =
            make_float4(c[i][0], c[i][1], c[i][2], c[i][3]);
}

// ---------------------------------------------------------------------------
// Causal depthwise conv (K=4) + SiLU, 8 channels/thread + z passthrough.
// ---------------------------------------------------------------------------
__global__ __launch_bounds__(256) void conv_silu_kernel(
    const bf16* __restrict__ qkvz, const float* __restrict__ cw,
    bf16* __restrict__ qbf, bf16* __restrict__ kbf, bf16* __restrict__ vbuf,
    bf16* __restrict__ zbuf) {
    const int64_t idx = (int64_t)blockIdx.x * 256 + threadIdx.x;
    const int cg = (int)(idx % 1536);
    const int64_t bs = idx / 1536;
    const int s = (int)(bs & (S_ - 1));
    const int c0 = cg << 3;

    int col;
    bf16* outp;
    if (c0 < KEY_DIM_) {
        col = ((c0 >> 7) * 768) + (c0 & 127);
        outp = qbf + bs * KEY_DIM_ + c0;
    } else if (c0 < 2 * KEY_DIM_) {
        const int c2 = c0 - KEY_DIM_;
        col = ((c2 >> 7) * 768) + 128 + (c2 & 127);
        outp = kbf + bs * KEY_DIM_ + c2;
    } else if (c0 < 2 * KEY_DIM_ + VAL_DIM_) {
        const int c3 = c0 - 2 * KEY_DIM_;
        col = ((c3 >> 8) * 768) + 256 + (c3 & 255);
        outp = vbuf + bs * VAL_DIM_ + c3;
    } else {
        const int zc = c0 - (2 * KEY_DIM_ + VAL_DIM_);
        const int hv = zc >> 7;
        col = (hv >> 1) * 768 + 512 + (hv & 1) * 128 + (zc & 127);
        outp = zbuf + bs * VAL_DIM_ + zc;
    }
    const bf16* xp = qkvz + bs * (int64_t)QKVZ_DIM_ + col;
    if (c0 >= 2 * KEY_DIM_ + VAL_DIM_) {
        *(uint4*)outp = *(const uint4*)xp;   // z passthrough
        return;
    }
    const uint4 zero4 = {0u, 0u, 0u, 0u};
    const uint4 x0 = *(const uint4*)xp;
    const uint4 x1 = (s >= 1) ? *(const uint4*)(xp - QKVZ_DIM_) : zero4;
    const uint4 x2 = (s >= 2) ? *(const uint4*)(xp - 2 * QKVZ_DIM_) : zero4;
    const uint4 x3 = (s >= 3) ? *(const uint4*)(xp - 3 * QKVZ_DIM_) : zero4;
    u16x8 o;
#pragma unroll
    for (int j = 0; j < 8; ++j) {
        const float4 wv = *(const float4*)(cw + (size_t)(c0 + j) * 4);
        float acc = wv.w * bf_lane(x0, j);
        acc = fmaf(wv.z, bf_lane(x1, j), acc);
        acc = fmaf(wv.y, bf_lane(x2, j), acc);
        acc = fmaf(wv.x, bf_lane(x3, j), acc);
        o[j] = f2bf(silu_f(acc));
    }
    *(u16x8*)outp = o;
}

// ---------------------------------------------------------------------------
// Pre-normalize q/k (bf16 in/out, fp32 math)
// ---------------------------------------------------------------------------
__global__ __launch_bounds__(256) void normalize_qk_kernel(
    bf16* __restrict__ qbf, bf16* __restrict__ kbf) {
    const int wid = (blockIdx.x * 256 + threadIdx.x) >> 6;  // B*S*HK
    const int lane = threadIdx.x & 63;
    const int hk = wid & (HK_ - 1);
    const int64_t bs = wid >> 4;
    bf16* qp = qbf + bs * KEY_DIM_ + hk * DK_ + lane * 2;
    bf16* kp = kbf + bs * KEY_DIM_ + hk * DK_ + lane * 2;
    const ushort2 qw = *(const ushort2*)qp;
    const ushort2 kw = *(const ushort2*)kp;
    const float q0 = bf2f(qw.x), q1 = bf2f(qw.y);
    const float k0 = bf2f(kw.x), k1 = bf2f(kw.y);
    float qs = fmaf(q0, q0, q1 * q1);
    float ks = fmaf(k0, k0, k1 * k1);
#pragma unroll
    for (int m = 1; m < 64; m <<= 1) {
        qs += __shfl_xor(qs, m);
        ks += __shfl_xor(ks, m);
    }
    const float qsc = rsqrtf(qs + EPS_) * 0.08838834764831845f;  // DK^-0.5
    const float ksc = rsqrtf(ks + EPS_);
    ushort2 oq, ok;
    oq.x = f2bf(q0 * qsc); oq.y = f2bf(q1 * qsc);
    ok.x = f2bf(k0 * ksc); ok.y = f2bf(k1 * ksc);
    *(ushort2*)qp = oq;
    *(ushort2*)kp = ok;
}

// ---------------------------------------------------------------------------
// Gate precompute from 4 K-split partials
// ---------------------------------------------------------------------------
__global__ __launch_bounds__(256) void gate_kernel(
    const float* __restrict__ ba_part, const float* __restrict__ A_log,
    const float* __restrict__ dt_bias, float* __restrict__ gbuf,
    float* __restrict__ betabuf) {
    const int idx = blockIdx.x * 256 + threadIdx.x;   // B*S*HV
    const int hv = idx & (HV_ - 1);
    const int bs = idx >> 5;
    const int hk = hv >> 1, j = hv & 1;
    const size_t SP = (size_t)B_ * S_ * 64;  // 262144
    const float* p = ba_part + (size_t)bs * 64 + hk * 4;
    const float bval = p[j] + p[SP + j] + p[2 * SP + j] + p[3 * SP + j];
    const float aval =
        p[2 + j] + p[SP + 2 + j] + p[2 * SP + 2 + j] + p[3 * SP + 2 + j];
    const float x = aval + dt_bias[hv];
    const float sp = (x > 20.f) ? x : log1pf(expf(x));
    gbuf[idx] = -expf(A_log[hv]) * sp;
    betabuf[idx] = 1.f / (1.f + expf(-bval));
}

// ---------------------------------------------------------------------------
// PASS 1 (per chunk-head, 2048 WGs x 256 thr) — unchanged from R12.
// ---------------------------------------------------------------------------
__global__ __launch_bounds__(256) void p1_kernel(
    const bf16* __restrict__ qbf, const bf16* __restrict__ kbf,
    const bf16* __restrict__ vbuf, const float* __restrict__ gbuf,
    const float* __restrict__ betabuf, bf16* __restrict__ WkA,
    bf16* __restrict__ QgA, bf16* __restrict__ Kg2A, bf16* __restrict__ UA,
    bf16* __restrict__ LA, float* __restrict__ gcArr) {
    const int ch = blockIdx.x;          // bh*32 + c
    const int bh = ch >> 5, c = ch & 31;
    const int b = bh >> 5, hv = bh & 31;
    const int hk = hv >> 1;
    const int tid = threadIdx.x;
    const int w = tid >> 6, l = tid & 63;
    const int fl = l & 15, fk = (l >> 4) * 8;

    __shared__ float Gls[CL_];
    __shared__ float Bls[CL_];
    __shared__ float A_ls[CL_][CL_ + 1];
    __shared__ float T_ls[CL_][CL_];
    __shared__ bf16 Tbf[CL_ * CL_];
    __shared__ bf16 Vt[128 * 72];
    __shared__ bf16 Kt[128 * 72];

    if (tid < 64) {
        float G = gbuf[((size_t)(b * S_ + c * 64 + tid)) * HV_ + hv];
        Bls[tid] = betabuf[((size_t)(b * S_ + c * 64 + tid)) * HV_ + hv];
#pragma unroll
        for (int d = 1; d < 64; d <<= 1) {
            const float n = __shfl_up(G, d, 64);
            if (tid >= d) G += n;
        }
        Gls[tid] = G;
        if (tid == 63) gcArr[ch] = expf(G);
    }
    __syncthreads();

    const bf16* kc = kbf + ((size_t)(b * S_ + c * 64)) * KEY_DIM_ + hk * DK_;
    const bf16* qc = qbf + ((size_t)(b * S_ + c * 64)) * KEY_DIM_ + hk * DK_;
    bf16* LC = LA + (size_t)ch * 4096;

    f32x4 accK[4], accQ[4];
#pragma unroll
    for (int n = 0; n < 4; ++n) {
        accK[n] = (f32x4){0.f, 0.f, 0.f, 0.f};
        accQ[n] = (f32x4){0.f, 0.f, 0.f, 0.f};
    }
#pragma unroll
    for (int kk = 0; kk < 4; ++kk) {
        const bf16x8 aK =
            *(const bf16x8*)(kc + (size_t)(w * 16 + fl) * KEY_DIM_ + fk + 32 * kk);
        const bf16x8 aQ =
            *(const bf16x8*)(qc + (size_t)(w * 16 + fl) * KEY_DIM_ + fk + 32 * kk);
#pragma unroll
        for (int n = 0; n < 4; ++n) {
            const bf16x8 bK = *(const bf16x8*)(kc + (size_t)(n * 16 + fl) * KEY_DIM_ +
                                               fk + 32 * kk);
            accK[n] = MFMA16(aK, bK, accK[n]);
            accQ[n] = MFMA16(aQ, bK, accQ[n]);
        }
    }
#pragma unroll
    for (int n = 0; n < 4; ++n)
#pragma unroll
        for (int r = 0; r < 4; ++r) {
            const int t = w * 16 + (l >> 4) * 4 + r;
            const int s = n * 16 + fl;
            const float eg = expf(Gls[t] - Gls[s]);
            A_ls[t][s] = (s < t) ? Bls[t] * eg * accK[n][r] : 0.f;
            const float lv = (s <= t) ? eg * accQ[n][r] : 0.f;
            LC[t * 64 + s] = f2bf(lv);
        }
    __syncthreads();

    if (tid < 64) {
        const int j = tid;
        for (int t = 0; t < 64; ++t) {
            float acc = (t == j) ? 1.f : 0.f;
            for (int s = 0; s < t; ++s) acc -= A_ls[t][s] * T_ls[s][j];
            T_ls[t][j] = acc;
        }
    }
    __syncthreads();

    for (int i = tid; i < 4096; i += 256)
        Tbf[i] = f2bf(T_ls[i >> 6][i & 63]);
    for (int i = tid; i < 8192; i += 256) {
        const int d = i & 127, s = i >> 7;
        const float bs_ = Bls[s];
        Vt[d * 72 + s] =
            f2bf(bf2f(vbuf[((size_t)(b * S_ + c * 64 + s)) * VAL_DIM_ + hv * DV_ + d]) * bs_);
        Kt[d * 72 + s] =
            f2bf(bf2f(kc[(size_t)s * KEY_DIM_ + d]) * bs_ * expf(Gls[s]));
    }
    __syncthreads();

    bf16* UC = UA + (size_t)ch * 8192;
    bf16* WkC = WkA + (size_t)ch * 8192;
    f32x4 accU[8], accW[8];
#pragma unroll
    for (int n = 0; n < 8; ++n) {
        accU[n] = (f32x4){0.f, 0.f, 0.f, 0.f};
        accW[n] = (f32x4){0.f, 0.f, 0.f, 0.f};
    }
#pragma unroll
    for (int kk = 0; kk < 2; ++kk) {
        const bf16x8 aT = *(const bf16x8*)(Tbf + (w * 16 + fl) * 64 + fk + 32 * kk);
#pragma unroll
        for (int n = 0; n < 8; ++n) {
            const bf16x8 bV = *(const bf16x8*)(Vt + (n * 16 + fl) * 72 + fk + 32 * kk);
            const bf16x8 bK2 = *(const bf16x8*)(Kt + (n * 16 + fl) * 72 + fk + 32 * kk);
            accU[n] = MFMA16(aT, bV, accU[n]);
            accW[n] = MFMA16(aT, bK2, accW[n]);
        }
    }
#pragma unroll
    for (int n = 0; n < 8; ++n)
#pragma unroll
        for (int r = 0; r < 4; ++r) {
            const int t = w * 16 + (l >> 4) * 4 + r;
            const int col = n * 16 + fl;
            UC[t * 128 + col] = f2bf(accU[n][r]);
            WkC[t * 128 + col] = f2bf(accW[n][r]);
        }

    const float G63 = Gls[63];
    bf16* QgC = QgA + (size_t)ch * 8192;
    bf16* KgC = Kg2A + (size_t)ch * 8192;
    for (int i = tid; i < 8192; i += 256) {
        const int d = i & 127, t = i >> 7;
        QgC[t * 128 + d] =
            f2bf(bf2f(qc[(size_t)t * KEY_DIM_ + d]) * expf(Gls[t]));
        KgC[d * 64 + t] =
            f2bf(bf2f(kc[(size_t)t * KEY_DIM_ + d]) * expf(G63 - Gls[t]));
    }
}

// ---------------------------------------------------------------------------
// PASS 2 — unchanged from R12.
// ---------------------------------------------------------------------------
__global__ __launch_bounds__(256) void p2_kernel(
    const bf16* __restrict__ WkA, const bf16* __restrict__ QgA,
    const bf16* __restrict__ Kg2A, const bf16* __restrict__ UA,
    const bf16* __restrict__ LA, const float* __restrict__ gcArr,
    bf16* __restrict__ core) {
    const int xcd = blockIdx.x & 7;
    const int rr = blockIdx.x >> 3;       // 0..31
    const int bh = xcd * 8 + (rr & 7);    // 0..63
    const int dvb = rr >> 3;              // 0..3
    const int b = bh >> 5, hv = bh & 31;
    const int tid = threadIdx.x;
    const int w = tid >> 6, l = tid & 63;
    const int fl = l & 15, fk = (l >> 4) * 8;

    __shared__ bf16 Sbf[32 * 136];
    __shared__ bf16 Dbf[32 * 72];

    for (int i = tid; i < 32 * 136; i += 256) Sbf[i] = 0;
    f32x4 accS[2][2];
#pragma unroll
    for (int m = 0; m < 2; ++m)
#pragma unroll
        for (int n = 0; n < 2; ++n) accS[m][n] = (f32x4){0.f, 0.f, 0.f, 0.f};
    __syncthreads();

    for (int c = 0; c < NCHUNK_; ++c) {
        const size_t ch = (size_t)bh * 32 + c;
        const bf16* WkC = WkA + ch * 8192;
        const bf16* QgC = QgA + ch * 8192;
        const bf16* KgC = Kg2A + ch * 8192;
        const bf16* UC = UA + ch * 8192;
        const bf16* LC = LA + ch * 4096;

        f32x4 accD[2], accO[2];
#pragma unroll
        for (int n = 0; n < 2; ++n) {
            accD[n] = (f32x4){0.f, 0.f, 0.f, 0.f};
            accO[n] = (f32x4){0.f, 0.f, 0.f, 0.f};
        }
#pragma unroll
        for (int kk = 0; kk < 4; ++kk) {
            const bf16x8 bS0 = *(const bf16x8*)(Sbf + (0 * 16 + fl) * 136 + fk + 32 * kk);
            const bf16x8 bS1 = *(const bf16x8*)(Sbf + (1 * 16 + fl) * 136 + fk + 32 * kk);
            const bf16x8 aW = *(const bf16x8*)(WkC + (w * 16 + fl) * 128 + fk + 32 * kk);
            const bf16x8 aQ = *(const bf16x8*)(QgC + (w * 16 + fl) * 128 + fk + 32 * kk);
            accD[0] = MFMA16(aW, bS0, accD[0]);
            accD[1] = MFMA16(aW, bS1, accD[1]);
            accO[0] = MFMA16(aQ, bS0, accO[0]);
            accO[1] = MFMA16(aQ, bS1, accO[1]);
        }
#pragma unroll
        for (int n = 0; n < 2; ++n)
#pragma unroll
            for (int r = 0; r < 4; ++r) {
                const int t = w * 16 + (l >> 4) * 4 + r;
                const int dvl = n * 16 + fl;
                const float u = bf2f(UC[t * 128 + dvb * 32 + dvl]);
                Dbf[dvl * 72 + t] = f2bf(u - accD[n][r]);
            }
        __syncthreads();

#pragma unroll
        for (int kk = 0; kk < 2; ++kk) {
            const bf16x8 bD0 = *(const bf16x8*)(Dbf + (0 * 16 + fl) * 72 + fk + 32 * kk);
            const bf16x8 bD1 = *(const bf16x8*)(Dbf + (1 * 16 + fl) * 72 + fk + 32 * kk);
            const bf16x8 aL = *(const bf16x8*)(LC + (w * 16 + fl) * 64 + fk + 32 * kk);
            accO[0] = MFMA16(aL, bD0, accO[0]);
            accO[1] = MFMA16(aL, bD1, accO[1]);
        }
#pragma unroll
        for (int n = 0; n < 2; ++n)
#pragma unroll
            for (int r = 0; r < 4; ++r) {
                const int t = w * 16 + (l >> 4) * 4 + r;
                const int col = hv * 128 + dvb * 32 + n * 16 + fl;
                core[((size_t)(b * S_ + c * 64 + t)) * VAL_DIM_ + col] =
                    f2bf(accO[n][r]);
            }

        const float gc = gcArr[ch];
#pragma unroll
        for (int m = 0; m < 2; ++m)
#pragma unroll
            for (int n = 0; n < 2; ++n)
#pragma unroll
                for (int r = 0; r < 4; ++r) accS[m][n][r] *= gc;
#pragma unroll
        for (int kk = 0; kk < 2; ++kk) {
            const bf16x8 bD0 = *(const bf16x8*)(Dbf + (0 * 16 + fl) * 72 + fk + 32 * kk);
            const bf16x8 bD1 = *(const bf16x8*)(Dbf + (1 * 16 + fl) * 72 + fk + 32 * kk);
#pragma unroll
            for (int m = 0; m < 2; ++m) {
                const bf16x8 aK =
                    *(const bf16x8*)(KgC + ((2 * w + m) * 16 + fl) * 64 + fk + 32 * kk);
                accS[m][0] = MFMA16(aK, bD0, accS[m][0]);
                accS[m][1] = MFMA16(aK, bD1, accS[m][1]);
            }
        }
        __syncthreads();
#pragma unroll
        for (int m = 0; m < 2; ++m)
#pragma unroll
            for (int n = 0; n < 2; ++n)
#pragma unroll
                for (int r = 0; r < 4; ++r) {
                    const int dk = (2 * w + m) * 16 + (l >> 4) * 4 + r;
                    const int dvl = n * 16 + fl;
                    Sbf[dvl * 136 + dk] = f2bf(accS[m][n][r]);
                }
        __syncthreads();
    }
}

// ---------------------------------------------------------------------------
// Gated RMSNorm in-place on bf16 core; z from zbuf (contiguous).
// ---------------------------------------------------------------------------
__global__ __launch_bounds__(256) void rmsnorm_gate_kernel(
    bf16* __restrict__ core, const bf16* __restrict__ zbuf,
    const float* __restrict__ nw) {
    const int wid = (blockIdx.x * 256 + threadIdx.x) >> 6;
    const int lane = threadIdx.x & 63;
    const int hv = wid & (HV_ - 1);
    const int64_t bs = wid >> 5;
    bf16* x = core + (size_t)bs * VAL_DIM_ + hv * DV_;
    const float x0 = bf2f(x[lane]);
    const float x1 = bf2f(x[lane + 64]);
    float ss = fmaf(x0, x0, x1 * x1);
#pragma unroll
    for (int m = 1; m < 64; m <<= 1) ss += __shfl_xor(ss, m);
    const float inv = rsqrtf(ss * (1.f / 128.f) + EPS_);
    const bf16* z = zbuf + (size_t)bs * VAL_DIM_ + hv * DV_;
    x[lane] = f2bf(x0 * inv * nw[lane] * silu_f(bf2f(z[lane])));
    x[lane + 64] =
        f2bf(x1 * inv * nw[lane + 64] * silu_f(bf2f(z[lane + 64])));
}

// ---------------------------------------------------------------------------
extern "C" void kernel_launch(void* const* d_in, const int* in_sizes, int n_in,
                              void* d_out, int out_size, void* d_ws,
                              size_t ws_size, hipStream_t stream) {
    const float* hidden  = (const float*)d_in[0];
    const float* W_qkvz  = (const float*)d_in[1];
    const float* W_ba    = (const float*)d_in[2];
    const float* conv_w  = (const float*)d_in[3];
    const float* dt_bias = (const float*)d_in[4];
    const float* A_log   = (const float*)d_in[5];
    const float* norm_w  = (const float*)d_in[6];
    const float* W_out   = (const float*)d_in[7];
    float* out = (float*)d_out;

    // ---- workspace (~324 MB <= proven 337.5) ----
    bf16* R = (bf16*)d_ws;
    bf16* hidden_bf = R;                         //  8,388,608 e
    bf16* Wq_bf = R + (size_t)8388608;           // 25,165,824 e
    bf16* qkvz  = R + (size_t)33554432;          // 50,331,648 e
    // P1 aliases (valid once conv has consumed qkvz):
    bf16* WkA  = R;                              // 16,777,216 e
    bf16* QgA  = R + (size_t)16777216;           // 16,777,216 e
    bf16* Kg2A = R + (size_t)33554432;           // 16,777,216 e
    bf16* UA   = R + (size_t)50331648;           // 16,777,216 e
    bf16* LA   = R + (size_t)67108864;           //  8,388,608 e
    // non-aliased:
    bf16* Wo_bf = R + (size_t)83886080;          //  8,388,608 e
    bf16* qbf   = Wo_bf + (size_t)8388608;       //  8,388,608 e
    bf16* kbf   = qbf + (size_t)8388608;         //  8,388,608 e
    bf16* vbuf  = kbf + (size_t)8388608;         // 16,777,216 e
    bf16* zbuf  = vbuf + (size_t)16777216;       // 16,777,216 e
    bf16* core  = zbuf + (size_t)16777216;       // 16,777,216 e
    float* ba_part = (float*)(core + (size_t)16777216);  // 1,048,576 f
    float* gbuf    = ba_part + 1048576;                  //   131,072 f
    float* betabuf = gbuf + 131072;                      //   131,072 f
    float* gcArr   = betabuf + 131072;                   //     2,048 f

    const int MBS = B_ * S_;  // 4096

    // 0. fp32 -> bf16 operand conversion
    f2bf_kernel<<<8388608 / 1024, 256, 0, stream>>>(hidden, hidden_bf);
    f2bf_kernel<<<25165824 / 1024, 256, 0, stream>>>(W_qkvz, Wq_bf);
    f2bf_kernel<<<8388608 / 1024, 256, 0, stream>>>(W_out, Wo_bf);

    // 1. qkvz = hidden @ W_qkvz^T (256^2-tile counted-vmcnt MFMA GEMM)
    gemm256_nt<<<dim3(QKVZ_DIM_ / 256, MBS / 256), 512, 0, stream>>>(
        hidden_bf, Wq_bf, qkvz, MBS, QKVZ_DIM_, HID_);
    // 2. ba = hidden @ W_ba^T (fp32, K-split x4)
    gemm_ba_ksplit<<<dim3(4, 64), 256, 0, stream>>>(hidden, W_ba, ba_part);
    // 3. gates
    gate_kernel<<<(MBS * HV_) / 256, 256, 0, stream>>>(ba_part, A_log, dt_bias,
                                                       gbuf, betabuf);
    // 4. conv + silu (8-wide) + z copy
    conv_silu_kernel<<<(int)(((int64_t)MBS * 1536) / 256), 256, 0, stream>>>(
        qkvz, conv_w, qbf, kbf, vbuf, zbuf);
    // 4b. normalize q/k
    normalize_qk_kernel<<<(MBS * HK_ * 64) / 256, 256, 0, stream>>>(qbf, kbf);
    // 5. chunked delta rule
    p1_kernel<<<2048, 256, 0, stream>>>(qbf, kbf, vbuf, gbuf, betabuf, WkA,
                                        QgA, Kg2A, UA, LA, gcArr);
    p2_kernel<<<256, 256, 0, stream>>>(WkA, QgA, Kg2A, UA, LA, gcArr, core);
    // 6. gated rmsnorm
    rmsnorm_gate_kernel<<<(MBS * HV_ * 64) / 256, 256, 0, stream>>>(core, zbuf,
                                                                    norm_w);
    // 7. out = core @ W_out^T (m97 structure, plain mapping)
    gemm_mfma_nt<0><<<dim3(HID_ / 128, MBS / 128), 256, 0, stream>>>(
        core, Wo_bf, (void*)out, MBS, HID_, VAL_DIM_);
}

// Round 15
// 777.703 us; speedup vs baseline: 1.8610x; 1.1626x over previous
//
#include <hip/hip_runtime.h>
#include <cstdint>
#include <cstddef>

#define B_ 2
#define S_ 2048
#define HID_ 2048
#define HK_ 16
#define HV_ 32
#define DK_ 128
#define DV_ 128
#define KEY_DIM_ 2048
#define VAL_DIM_ 4096
#define QKVZ_DIM_ 12288
#define BA_DIM_ 64
#define CONV_DIM_ 8192
#define EPS_ 1e-6f
#define NCHUNK_ 32
#define CL_ 64   // chunk length

typedef unsigned short bf16;
typedef __attribute__((ext_vector_type(8))) short bf16x8;
typedef __attribute__((ext_vector_type(8))) unsigned short u16x8;
typedef __attribute__((ext_vector_type(4))) float f32x4;

__device__ __forceinline__ float silu_f(float x) { return x / (1.f + expf(-x)); }

__device__ __forceinline__ bf16 f2bf(float x) {
    unsigned int u = __float_as_uint(x);
    u += 0x7FFF + ((u >> 16) & 1);   // round-to-nearest-even
    return (bf16)(u >> 16);
}
__device__ __forceinline__ float bf2f(bf16 x) {
    return __uint_as_float((unsigned)x << 16);
}
#define BF2F_LO(u) __uint_as_float((unsigned)(u) << 16)
#define BF2F_HI(u) __uint_as_float((unsigned)(u) & 0xFFFF0000u)

__device__ __forceinline__ float bf_lane(const uint4& x, int j) {
    const unsigned wv = (&x.x)[j >> 1];
    return (j & 1) ? BF2F_HI(wv) : BF2F_LO(wv);
}

typedef const __attribute__((address_space(1))) unsigned int cgu32;
typedef __attribute__((address_space(3))) unsigned int lsu32;
__device__ __forceinline__ void gld16(const void* g, void* l) {
    __builtin_amdgcn_global_load_lds((cgu32*)g, (lsu32*)l, 16, 0, 0);
}

#define MFMA16(a, b, c) __builtin_amdgcn_mfma_f32_16x16x32_bf16((a), (b), (c), 0, 0, 0)

// ---------------------------------------------------------------------------
// fp32 -> bf16 conversion, 4 elems/thread
// ---------------------------------------------------------------------------
__global__ __launch_bounds__(256) void f2bf_kernel(const float* __restrict__ in,
                                                   bf16* __restrict__ out) {
    const int64_t i = (int64_t)blockIdx.x * 256 + threadIdx.x;
    const float4 v = ((const float4*)in)[i];
    ushort4 o;
    o.x = f2bf(v.x); o.y = f2bf(v.y); o.z = f2bf(v.z); o.w = f2bf(v.w);
    ((ushort4*)out)[i] = o;
}

// ---------------------------------------------------------------------------
// 256x256-tile bf16 MFMA GEMM NT (R14, unchanged — verified)
// ---------------------------------------------------------------------------
__global__ __launch_bounds__(512, 2) void gemm256_nt(
    const bf16* __restrict__ A, const bf16* __restrict__ Bm,
    bf16* __restrict__ C, int M, int N, int K) {
    __shared__ bf16 ringA[3][8192];
    __shared__ bf16 ringB[3][8192];
    const int tid = threadIdx.x;
    const int w = tid >> 6;
    const int l = tid & 63;
    const int wm = w >> 2;
    const int wn = w & 3;
    const int fl = l & 15;
    const int fk = (l >> 4) * 8;
    const int bm = blockIdx.y, bn = blockIdx.x;

    const int srow = tid >> 2;
    const int scol = (((tid & 3) ^ ((tid >> 2) & 3)) << 3);
    const bf16* Ag0 = A + (size_t)(bm * 256 + srow) * K + scol;
    const bf16* Ag1 = A + (size_t)(bm * 256 + 128 + srow) * K + scol;
    const bf16* Bg0 = Bm + (size_t)(bn * 256 + srow) * K + scol;
    const bf16* Bg1 = Bm + (size_t)(bn * 256 + 128 + srow) * K + scol;

    const int kswz = fk ^ ((fl & 3) << 3);
    int aoff[8], boff[4];
#pragma unroll
    for (int mi = 0; mi < 8; ++mi)
        aoff[mi] = (wm * 128 + mi * 16 + fl) * 32 + kswz;
#pragma unroll
    for (int ni = 0; ni < 4; ++ni)
        boff[ni] = (wn * 64 + ni * 16 + fl) * 32 + kswz;

    f32x4 acc[8][4];
#pragma unroll
    for (int mi = 0; mi < 8; ++mi)
#pragma unroll
        for (int ni = 0; ni < 4; ++ni) acc[mi][ni] = (f32x4){0.f, 0.f, 0.f, 0.f};

#define STAGE256(kt, slot)                                                     \
    do {                                                                       \
        const int _k = (kt) * 32;                                              \
        gld16(Ag0 + _k, &ringA[slot][w * 512]);                                \
        gld16(Ag1 + _k, &ringA[slot][4096 + w * 512]);                         \
        gld16(Bg0 + _k, &ringB[slot][w * 512]);                                \
        gld16(Bg1 + _k, &ringB[slot][4096 + w * 512]);                         \
    } while (0)

    const int nkt = K >> 5;
    STAGE256(0, 0);
    STAGE256(1, 1);

    for (int t = 0; t < nkt; ++t) {
        asm volatile("s_waitcnt vmcnt(4)" ::: "memory");
        __builtin_amdgcn_s_barrier();
        __builtin_amdgcn_sched_barrier(0);
        const int slot = t % 3;
        const bf16* As_ = ringA[slot];
        const bf16* Bs_ = ringB[slot];
        bf16x8 af[8], bfr[4];
#pragma unroll
        for (int mi = 0; mi < 8; ++mi)
            af[mi] = *(const bf16x8*)(As_ + aoff[mi]);
#pragma unroll
        for (int ni = 0; ni < 4; ++ni)
            bfr[ni] = *(const bf16x8*)(Bs_ + boff[ni]);
        const int kt2 = (t + 2 < nkt) ? (t + 2) : (nkt - 1);
        STAGE256(kt2, (t + 2) % 3);
        asm volatile("s_waitcnt lgkmcnt(0)" ::: "memory");
        __builtin_amdgcn_sched_barrier(0);
        __builtin_amdgcn_s_setprio(1);
#pragma unroll
        for (int mi = 0; mi < 8; ++mi)
#pragma unroll
            for (int ni = 0; ni < 4; ++ni)
                acc[mi][ni] = MFMA16(af[mi], bfr[ni], acc[mi][ni]);
        __builtin_amdgcn_s_setprio(0);
    }
#undef STAGE256

#pragma unroll
    for (int mi = 0; mi < 8; ++mi)
#pragma unroll
        for (int ni = 0; ni < 4; ++ni)
#pragma unroll
            for (int r = 0; r < 4; ++r) {
                const int row = bm * 256 + wm * 128 + mi * 16 + (l >> 4) * 4 + r;
                const int col = bn * 256 + wn * 64 + ni * 16 + fl;
                C[(size_t)row * N + col] = f2bf(acc[mi][ni][r]);
            }
}

// ---------------------------------------------------------------------------
// bf16 MFMA GEMM NT (m97 structure) — out-GEMM.
// ---------------------------------------------------------------------------
template <int OUTBF16>
__global__ __launch_bounds__(256) void gemm_mfma_nt(const bf16* __restrict__ A,
                                                    const bf16* __restrict__ Bm,
                                                    void* __restrict__ Cv,
                                                    int M, int N, int K) {
    __shared__ bf16 As[128 * 32];
    __shared__ bf16 Bs[128 * 32];
    const int tid = threadIdx.x;
    const int w = tid >> 6;
    const int l = tid & 63;
    const int bm = blockIdx.y, bn = blockIdx.x;

    const int srow = l >> 2;
    const int scol = (l & 3) << 3;
    const bf16* Ag = A + (size_t)(bm * 128 + w * 16 + srow) * K + scol;
    const bf16* Bg = Bm + (size_t)(bn * 128 + w * 16 + srow) * K + scol;
    bf16* Al = As + w * 16 * 32;
    bf16* Bl = Bs + w * 16 * 32;
    const size_t rstep = (size_t)64 * K;

    const int wr = (w >> 1) * 64;
    const int wc = (w & 1) * 64;
    const int fl = l & 15;
    const int fk = (l >> 4) * 8;

    f32x4 acc[4][4];
#pragma unroll
    for (int m = 0; m < 4; ++m)
#pragma unroll
        for (int n = 0; n < 4; ++n) acc[m][n] = (f32x4){0.f, 0.f, 0.f, 0.f};

    for (int k0 = 0; k0 < K; k0 += 32) {
        gld16(Ag + k0, Al);
        gld16(Ag + k0 + rstep, Al + 64 * 32);
        gld16(Bg + k0, Bl);
        gld16(Bg + k0 + rstep, Bl + 64 * 32);
        __syncthreads();

        bf16x8 af[4], bb[4];
#pragma unroll
        for (int m = 0; m < 4; ++m)
            af[m] = *(const bf16x8*)(As + (wr + m * 16 + fl) * 32 + fk);
#pragma unroll
        for (int n = 0; n < 4; ++n)
            bb[n] = *(const bf16x8*)(Bs + (wc + n * 16 + fl) * 32 + fk);
#pragma unroll
        for (int m = 0; m < 4; ++m)
#pragma unroll
            for (int n = 0; n < 4; ++n)
                acc[m][n] = MFMA16(af[m], bb[n], acc[m][n]);
        __syncthreads();
    }

    if (OUTBF16) {
        bf16* C = (bf16*)Cv;
#pragma unroll
        for (int m = 0; m < 4; ++m)
#pragma unroll
            for (int n = 0; n < 4; ++n)
#pragma unroll
                for (int r = 0; r < 4; ++r) {
                    const int row = bm * 128 + wr + m * 16 + (l >> 4) * 4 + r;
                    const int col = bn * 128 + wc + n * 16 + fl;
                    C[(size_t)row * N + col] = f2bf(acc[m][n][r]);
                }
    } else {
        float* C = (float*)Cv;
#pragma unroll
        for (int m = 0; m < 4; ++m)
#pragma unroll
            for (int n = 0; n < 4; ++n)
#pragma unroll
                for (int r = 0; r < 4; ++r) {
                    const int row = bm * 128 + wr + m * 16 + (l >> 4) * 4 + r;
                    const int col = bn * 128 + wc + n * 16 + fl;
                    C[(size_t)row * N + col] = acc[m][n][r];
                }
    }
}

// ---------------------------------------------------------------------------
// ba projection, fp32, K-split x4
// ---------------------------------------------------------------------------
#define BM 64
#define BN 64
#define BKK 32

__global__ __launch_bounds__(256) void gemm_ba_ksplit(
    const float* __restrict__ A, const float* __restrict__ Bm,
    float* __restrict__ Cpart) {
    __shared__ float As[BKK][BM + 4];
    __shared__ float Bs[BKK][BN + 4];
    const int tid = threadIdx.x;
    const int tx = tid & 15;
    const int ty = tid >> 4;
    const int ks = blockIdx.x;     // 0..3
    const int bm = blockIdx.y;     // 0..63
    const float* Ab = A + (size_t)bm * BM * HID_;
    const float* Bb = Bm;
    const int lr = tid >> 2;
    const int lc = (tid & 3) << 3;

    float c[4][4] = {{0.f, 0.f, 0.f, 0.f}, {0.f, 0.f, 0.f, 0.f},
                     {0.f, 0.f, 0.f, 0.f}, {0.f, 0.f, 0.f, 0.f}};

    const int kbeg = ks * 512;
    for (int k0 = kbeg; k0 < kbeg + 512; k0 += BKK) {
        const float4 a0 = *(const float4*)(Ab + (size_t)lr * HID_ + k0 + lc);
        const float4 a1 = *(const float4*)(Ab + (size_t)lr * HID_ + k0 + lc + 4);
        const float4 b0 = *(const float4*)(Bb + (size_t)lr * HID_ + k0 + lc);
        const float4 b1 = *(const float4*)(Bb + (size_t)lr * HID_ + k0 + lc + 4);
        __syncthreads();
        As[lc + 0][lr] = a0.x; As[lc + 1][lr] = a0.y;
        As[lc + 2][lr] = a0.z; As[lc + 3][lr] = a0.w;
        As[lc + 4][lr] = a1.x; As[lc + 5][lr] = a1.y;
        As[lc + 6][lr] = a1.z; As[lc + 7][lr] = a1.w;
        Bs[lc + 0][lr] = b0.x; Bs[lc + 1][lr] = b0.y;
        Bs[lc + 2][lr] = b0.z; Bs[lc + 3][lr] = b0.w;
        Bs[lc + 4][lr] = b1.x; Bs[lc + 5][lr] = b1.y;
        Bs[lc + 6][lr] = b1.z; Bs[lc + 7][lr] = b1.w;
        __syncthreads();
#pragma unroll
        for (int kk = 0; kk < BKK; ++kk) {
            const float4 Av = *(const float4*)&As[kk][ty << 2];
            const float4 Bv = *(const float4*)&Bs[kk][tx << 2];
            const float aa[4] = {Av.x, Av.y, Av.z, Av.w};
            const float bb[4] = {Bv.x, Bv.y, Bv.z, Bv.w};
#pragma unroll
            for (int i = 0; i < 4; ++i)
#pragma unroll
                for (int j = 0; j < 4; ++j)
                    c[i][j] = fmaf(aa[i], bb[j], c[i][j]);
        }
    }
    float* Cp = Cpart + (size_t)ks * ((size_t)B_ * S_ * 64) +
                (size_t)(bm * BM + (ty << 2)) * 64 + (tx << 2);
#pragma unroll
    for (int i = 0; i < 4; ++i)
        *(float4*)(Cp + (size_t)i * 64) =
            make_float4(c[i][0], c[i][1], c[i][2], c[i][3]);
}

// ---------------------------------------------------------------------------
// Causal depthwise conv (K=4) + SiLU, 8 channels/thread + z passthrough.
// ---------------------------------------------------------------------------
__global__ __launch_bounds__(256) void conv_silu_kernel(
    const bf16* __restrict__ qkvz, const float* __restrict__ cw,
    bf16* __restrict__ qbf, bf16* __restrict__ kbf, bf16* __restrict__ vbuf,
    bf16* __restrict__ zbuf) {
    const int64_t idx = (int64_t)blockIdx.x * 256 + threadIdx.x;
    const int cg = (int)(idx % 1536);
    const int64_t bs = idx / 1536;
    const int s = (int)(bs & (S_ - 1));
    const int c0 = cg << 3;

    int col;
    bf16* outp;
    if (c0 < KEY_DIM_) {
        col = ((c0 >> 7) * 768) + (c0 & 127);
        outp = qbf + bs * KEY_DIM_ + c0;
    } else if (c0 < 2 * KEY_DIM_) {
        const int c2 = c0 - KEY_DIM_;
        col = ((c2 >> 7) * 768) + 128 + (c2 & 127);
        outp = kbf + bs * KEY_DIM_ + c2;
    } else if (c0 < 2 * KEY_DIM_ + VAL_DIM_) {
        const int c3 = c0 - 2 * KEY_DIM_;
        col = ((c3 >> 8) * 768) + 256 + (c3 & 255);
        outp = vbuf + bs * VAL_DIM_ + c3;
    } else {
        const int zc = c0 - (2 * KEY_DIM_ + VAL_DIM_);
        const int hv = zc >> 7;
        col = (hv >> 1) * 768 + 512 + (hv & 1) * 128 + (zc & 127);
        outp = zbuf + bs * VAL_DIM_ + zc;
    }
    const bf16* xp = qkvz + bs * (int64_t)QKVZ_DIM_ + col;
    if (c0 >= 2 * KEY_DIM_ + VAL_DIM_) {
        *(uint4*)outp = *(const uint4*)xp;   // z passthrough
        return;
    }
    const uint4 zero4 = {0u, 0u, 0u, 0u};
    const uint4 x0 = *(const uint4*)xp;
    const uint4 x1 = (s >= 1) ? *(const uint4*)(xp - QKVZ_DIM_) : zero4;
    const uint4 x2 = (s >= 2) ? *(const uint4*)(xp - 2 * QKVZ_DIM_) : zero4;
    const uint4 x3 = (s >= 3) ? *(const uint4*)(xp - 3 * QKVZ_DIM_) : zero4;
    u16x8 o;
#pragma unroll
    for (int j = 0; j < 8; ++j) {
        const float4 wv = *(const float4*)(cw + (size_t)(c0 + j) * 4);
        float acc = wv.w * bf_lane(x0, j);
        acc = fmaf(wv.z, bf_lane(x1, j), acc);
        acc = fmaf(wv.y, bf_lane(x2, j), acc);
        acc = fmaf(wv.x, bf_lane(x3, j), acc);
        o[j] = f2bf(silu_f(acc));
    }
    *(u16x8*)outp = o;
}

// ---------------------------------------------------------------------------
// Pre-normalize q/k (bf16 in/out, fp32 math)
// ---------------------------------------------------------------------------
__global__ __launch_bounds__(256) void normalize_qk_kernel(
    bf16* __restrict__ qbf, bf16* __restrict__ kbf) {
    const int wid = (blockIdx.x * 256 + threadIdx.x) >> 6;  // B*S*HK
    const int lane = threadIdx.x & 63;
    const int hk = wid & (HK_ - 1);
    const int64_t bs = wid >> 4;
    bf16* qp = qbf + bs * KEY_DIM_ + hk * DK_ + lane * 2;
    bf16* kp = kbf + bs * KEY_DIM_ + hk * DK_ + lane * 2;
    const ushort2 qw = *(const ushort2*)qp;
    const ushort2 kw = *(const ushort2*)kp;
    const float q0 = bf2f(qw.x), q1 = bf2f(qw.y);
    const float k0 = bf2f(kw.x), k1 = bf2f(kw.y);
    float qs = fmaf(q0, q0, q1 * q1);
    float ks = fmaf(k0, k0, k1 * k1);
#pragma unroll
    for (int m = 1; m < 64; m <<= 1) {
        qs += __shfl_xor(qs, m);
        ks += __shfl_xor(ks, m);
    }
    const float qsc = rsqrtf(qs + EPS_) * 0.08838834764831845f;  // DK^-0.5
    const float ksc = rsqrtf(ks + EPS_);
    ushort2 oq, ok;
    oq.x = f2bf(q0 * qsc); oq.y = f2bf(q1 * qsc);
    ok.x = f2bf(k0 * ksc); ok.y = f2bf(k1 * ksc);
    *(ushort2*)qp = oq;
    *(ushort2*)kp = ok;
}

// ---------------------------------------------------------------------------
// Gate precompute from 4 K-split partials
// ---------------------------------------------------------------------------
__global__ __launch_bounds__(256) void gate_kernel(
    const float* __restrict__ ba_part, const float* __restrict__ A_log,
    const float* __restrict__ dt_bias, float* __restrict__ gbuf,
    float* __restrict__ betabuf) {
    const int idx = blockIdx.x * 256 + threadIdx.x;   // B*S*HV
    const int hv = idx & (HV_ - 1);
    const int bs = idx >> 5;
    const int hk = hv >> 1, j = hv & 1;
    const size_t SP = (size_t)B_ * S_ * 64;  // 262144
    const float* p = ba_part + (size_t)bs * 64 + hk * 4;
    const float bval = p[j] + p[SP + j] + p[2 * SP + j] + p[3 * SP + j];
    const float aval =
        p[2 + j] + p[SP + 2 + j] + p[2 * SP + 2 + j] + p[3 * SP + 2 + j];
    const float x = aval + dt_bias[hv];
    const float sp = (x > 20.f) ? x : log1pf(expf(x));
    gbuf[idx] = -expf(A_log[hv]) * sp;
    betabuf[idx] = 1.f / (1.f + expf(-bval));
}

// ---------------------------------------------------------------------------
// PASS 1 — de-serialized. Forward substitution runs in wave-0 REGISTERS
// (column-per-lane, fully unrolled: only LDS broadcast reads of A, no LDS
// write->read chain). Waves 1-3 concurrently stage Vt/Kt and write Qg/Kg.
// exp(G) tables precomputed once per chunk.
// ---------------------------------------------------------------------------
__global__ __launch_bounds__(256) void p1_kernel(
    const bf16* __restrict__ qbf, const bf16* __restrict__ kbf,
    const bf16* __restrict__ vbuf, const float* __restrict__ gbuf,
    const float* __restrict__ betabuf, bf16* __restrict__ WkA,
    bf16* __restrict__ QgA, bf16* __restrict__ Kg2A, bf16* __restrict__ UA,
    bf16* __restrict__ LA, float* __restrict__ gcArr) {
    const int ch = blockIdx.x;          // bh*32 + c
    const int bh = ch >> 5, c = ch & 31;
    const int b = bh >> 5, hv = bh & 31;
    const int hk = hv >> 1;
    const int tid = threadIdx.x;
    const int w = tid >> 6, l = tid & 63;
    const int fl = l & 15, fk = (l >> 4) * 8;

    __shared__ float Gls[CL_];
    __shared__ float Bls[CL_];
    __shared__ float Egt[CL_];          // exp(G_t)
    __shared__ float Egc[CL_];          // exp(G63 - G_t)
    __shared__ float A_ls[CL_][CL_ + 1];
    __shared__ bf16 Tbf[CL_ * CL_];
    __shared__ bf16 Vt[128 * 72];
    __shared__ bf16 Kt[128 * 72];

    // --- G cumsum + beta + exp tables (wave 0) ---
    if (tid < 64) {
        float G = gbuf[((size_t)(b * S_ + c * 64 + tid)) * HV_ + hv];
        Bls[tid] = betabuf[((size_t)(b * S_ + c * 64 + tid)) * HV_ + hv];
#pragma unroll
        for (int d = 1; d < 64; d <<= 1) {
            const float n = __shfl_up(G, d, 64);
            if (tid >= d) G += n;
        }
        Gls[tid] = G;
        const float eg = expf(G);
        Egt[tid] = eg;
        Egc[tid] = expf(__shfl(G, 63, 64) - G);
        if (tid == 63) gcArr[ch] = eg;
    }
    __syncthreads();

    // --- KK^T and QK^T (MFMA), scale+mask -> A_ls (f32), L (global bf16) ---
    const bf16* kc = kbf + ((size_t)(b * S_ + c * 64)) * KEY_DIM_ + hk * DK_;
    const bf16* qc = qbf + ((size_t)(b * S_ + c * 64)) * KEY_DIM_ + hk * DK_;
    bf16* LC = LA + (size_t)ch * 4096;

    f32x4 accK[4], accQ[4];
#pragma unroll
    for (int n = 0; n < 4; ++n) {
        accK[n] = (f32x4){0.f, 0.f, 0.f, 0.f};
        accQ[n] = (f32x4){0.f, 0.f, 0.f, 0.f};
    }
#pragma unroll
    for (int kk = 0; kk < 4; ++kk) {
        const bf16x8 aK =
            *(const bf16x8*)(kc + (size_t)(w * 16 + fl) * KEY_DIM_ + fk + 32 * kk);
        const bf16x8 aQ =
            *(const bf16x8*)(qc + (size_t)(w * 16 + fl) * KEY_DIM_ + fk + 32 * kk);
#pragma unroll
        for (int n = 0; n < 4; ++n) {
            const bf16x8 bK = *(const bf16x8*)(kc + (size_t)(n * 16 + fl) * KEY_DIM_ +
                                               fk + 32 * kk);
            accK[n] = MFMA16(aK, bK, accK[n]);
            accQ[n] = MFMA16(aQ, bK, accQ[n]);
        }
    }
#pragma unroll
    for (int n = 0; n < 4; ++n)
#pragma unroll
        for (int r = 0; r < 4; ++r) {
            const int t = w * 16 + (l >> 4) * 4 + r;
            const int s = n * 16 + fl;
            const float eg = expf(Gls[t] - Gls[s]);
            A_ls[t][s] = (s < t) ? Bls[t] * eg * accK[n][r] : 0.f;
            const float lv = (s <= t) ? eg * accQ[n][r] : 0.f;
            LC[t * 64 + s] = f2bf(lv);
        }
    __syncthreads();

    bf16* QgC = QgA + (size_t)ch * 8192;
    bf16* KgC = Kg2A + (size_t)ch * 8192;

    if (w == 0) {
        // --- T = (I+A)^-1: column l in registers; only broadcast A reads ---
        float Tcol[64];
#pragma unroll
        for (int t = 0; t < 64; ++t) {
            float acc = (t == l) ? 1.f : 0.f;
#pragma unroll
            for (int s = 0; s < t; ++s)
                acc = fmaf(-A_ls[t][s], Tcol[s], acc);
            Tcol[t] = acc;
            Tbf[t * 64 + l] = f2bf(acc);
        }
    } else if (w == 1) {
        // Vt = (beta V)^T
        for (int i = l; i < 8192; i += 64) {
            const int d = i & 127, s = i >> 7;
            Vt[d * 72 + s] = f2bf(
                bf2f(vbuf[((size_t)(b * S_ + c * 64 + s)) * VAL_DIM_ + hv * DV_ + d]) *
                Bls[s]);
        }
    } else if (w == 2) {
        // Kt = (beta e^G K)^T
        for (int i = l; i < 8192; i += 64) {
            const int d = i & 127, s = i >> 7;
            Kt[d * 72 + s] =
                f2bf(bf2f(kc[(size_t)s * KEY_DIM_ + d]) * Bls[s] * Egt[s]);
        }
    } else {
        // Qg, Kg2T global writes
        for (int i = l; i < 8192; i += 64) {
            const int d = i & 127, t = i >> 7;
            QgC[t * 128 + d] = f2bf(bf2f(qc[(size_t)t * KEY_DIM_ + d]) * Egt[t]);
            KgC[d * 64 + t] = f2bf(bf2f(kc[(size_t)t * KEY_DIM_ + d]) * Egc[t]);
        }
    }
    __syncthreads();

    // --- U = T@(bV), Wk = T@(b e^G K) ---
    bf16* UC = UA + (size_t)ch * 8192;
    bf16* WkC = WkA + (size_t)ch * 8192;
    f32x4 accU[8], accW[8];
#pragma unroll
    for (int n = 0; n < 8; ++n) {
        accU[n] = (f32x4){0.f, 0.f, 0.f, 0.f};
        accW[n] = (f32x4){0.f, 0.f, 0.f, 0.f};
    }
#pragma unroll
    for (int kk = 0; kk < 2; ++kk) {
        const bf16x8 aT = *(const bf16x8*)(Tbf + (w * 16 + fl) * 64 + fk + 32 * kk);
#pragma unroll
        for (int n = 0; n < 8; ++n) {
            const bf16x8 bV = *(const bf16x8*)(Vt + (n * 16 + fl) * 72 + fk + 32 * kk);
            const bf16x8 bK2 = *(const bf16x8*)(Kt + (n * 16 + fl) * 72 + fk + 32 * kk);
            accU[n] = MFMA16(aT, bV, accU[n]);
            accW[n] = MFMA16(aT, bK2, accW[n]);
        }
    }
#pragma unroll
    for (int n = 0; n < 8; ++n)
#pragma unroll
        for (int r = 0; r < 4; ++r) {
            const int t = w * 16 + (l >> 4) * 4 + r;
            const int col = n * 16 + fl;
            UC[t * 128 + col] = f2bf(accU[n][r]);
            WkC[t * 128 + col] = f2bf(accW[n][r]);
        }
}

// ---------------------------------------------------------------------------
// PASS 2 — unchanged from R12.
// ---------------------------------------------------------------------------
__global__ __launch_bounds__(256) void p2_kernel(
    const bf16* __restrict__ WkA, const bf16* __restrict__ QgA,
    const bf16* __restrict__ Kg2A, const bf16* __restrict__ UA,
    const bf16* __restrict__ LA, const float* __restrict__ gcArr,
    bf16* __restrict__ core) {
    const int xcd = blockIdx.x & 7;
    const int rr = blockIdx.x >> 3;       // 0..31
    const int bh = xcd * 8 + (rr & 7);    // 0..63
    const int dvb = rr >> 3;              // 0..3
    const int b = bh >> 5, hv = bh & 31;
    const int tid = threadIdx.x;
    const int w = tid >> 6, l = tid & 63;
    const int fl = l & 15, fk = (l >> 4) * 8;

    __shared__ bf16 Sbf[32 * 136];
    __shared__ bf16 Dbf[32 * 72];

    for (int i = tid; i < 32 * 136; i += 256) Sbf[i] = 0;
    f32x4 accS[2][2];
#pragma unroll
    for (int m = 0; m < 2; ++m)
#pragma unroll
        for (int n = 0; n < 2; ++n) accS[m][n] = (f32x4){0.f, 0.f, 0.f, 0.f};
    __syncthreads();

    for (int c = 0; c < NCHUNK_; ++c) {
        const size_t ch = (size_t)bh * 32 + c;
        const bf16* WkC = WkA + ch * 8192;
        const bf16* QgC = QgA + ch * 8192;
        const bf16* KgC = Kg2A + ch * 8192;
        const bf16* UC = UA + ch * 8192;
        const bf16* LC = LA + ch * 4096;

        f32x4 accD[2], accO[2];
#pragma unroll
        for (int n = 0; n < 2; ++n) {
            accD[n] = (f32x4){0.f, 0.f, 0.f, 0.f};
            accO[n] = (f32x4){0.f, 0.f, 0.f, 0.f};
        }
#pragma unroll
        for (int kk = 0; kk < 4; ++kk) {
            const bf16x8 bS0 = *(const bf16x8*)(Sbf + (0 * 16 + fl) * 136 + fk + 32 * kk);
            const bf16x8 bS1 = *(const bf16x8*)(Sbf + (1 * 16 + fl) * 136 + fk + 32 * kk);
            const bf16x8 aW = *(const bf16x8*)(WkC + (w * 16 + fl) * 128 + fk + 32 * kk);
            const bf16x8 aQ = *(const bf16x8*)(QgC + (w * 16 + fl) * 128 + fk + 32 * kk);
            accD[0] = MFMA16(aW, bS0, accD[0]);
            accD[1] = MFMA16(aW, bS1, accD[1]);
            accO[0] = MFMA16(aQ, bS0, accO[0]);
            accO[1] = MFMA16(aQ, bS1, accO[1]);
        }
#pragma unroll
        for (int n = 0; n < 2; ++n)
#pragma unroll
            for (int r = 0; r < 4; ++r) {
                const int t = w * 16 + (l >> 4) * 4 + r;
                const int dvl = n * 16 + fl;
                const float u = bf2f(UC[t * 128 + dvb * 32 + dvl]);
                Dbf[dvl * 72 + t] = f2bf(u - accD[n][r]);
            }
        __syncthreads();

#pragma unroll
        for (int kk = 0; kk < 2; ++kk) {
            const bf16x8 bD0 = *(const bf16x8*)(Dbf + (0 * 16 + fl) * 72 + fk + 32 * kk);
            const bf16x8 bD1 = *(const bf16x8*)(Dbf + (1 * 16 + fl) * 72 + fk + 32 * kk);
            const bf16x8 aL = *(const bf16x8*)(LC + (w * 16 + fl) * 64 + fk + 32 * kk);
            accO[0] = MFMA16(aL, bD0, accO[0]);
            accO[1] = MFMA16(aL, bD1, accO[1]);
        }
#pragma unroll
        for (int n = 0; n < 2; ++n)
#pragma unroll
            for (int r = 0; r < 4; ++r) {
                const int t = w * 16 + (l >> 4) * 4 + r;
                const int col = hv * 128 + dvb * 32 + n * 16 + fl;
                core[((size_t)(b * S_ + c * 64 + t)) * VAL_DIM_ + col] =
                    f2bf(accO[n][r]);
            }

        const float gc = gcArr[ch];
#pragma unroll
        for (int m = 0; m < 2; ++m)
#pragma unroll
            for (int n = 0; n < 2; ++n)
#pragma unroll
                for (int r = 0; r < 4; ++r) accS[m][n][r] *= gc;
#pragma unroll
        for (int kk = 0; kk < 2; ++kk) {
            const bf16x8 bD0 = *(const bf16x8*)(Dbf + (0 * 16 + fl) * 72 + fk + 32 * kk);
            const bf16x8 bD1 = *(const bf16x8*)(Dbf + (1 * 16 + fl) * 72 + fk + 32 * kk);
#pragma unroll
            for (int m = 0; m < 2; ++m) {
                const bf16x8 aK =
                    *(const bf16x8*)(KgC + ((2 * w + m) * 16 + fl) * 64 + fk + 32 * kk);
                accS[m][0] = MFMA16(aK, bD0, accS[m][0]);
                accS[m][1] = MFMA16(aK, bD1, accS[m][1]);
            }
        }
        __syncthreads();
#pragma unroll
        for (int m = 0; m < 2; ++m)
#pragma unroll
            for (int n = 0; n < 2; ++n)
#pragma unroll
                for (int r = 0; r < 4; ++r) {
                    const int dk = (2 * w + m) * 16 + (l >> 4) * 4 + r;
                    const int dvl = n * 16 + fl;
                    Sbf[dvl * 136 + dk] = f2bf(accS[m][n][r]);
                }
        __syncthreads();
    }
}

// ---------------------------------------------------------------------------
// Gated RMSNorm in-place on bf16 core; z from zbuf (contiguous).
// ---------------------------------------------------------------------------
__global__ __launch_bounds__(256) void rmsnorm_gate_kernel(
    bf16* __restrict__ core, const bf16* __restrict__ zbuf,
    const float* __restrict__ nw) {
    const int wid = (blockIdx.x * 256 + threadIdx.x) >> 6;
    const int lane = threadIdx.x & 63;
    const int hv = wid & (HV_ - 1);
    const int64_t bs = wid >> 5;
    bf16* x = core + (size_t)bs * VAL_DIM_ + hv * DV_;
    const float x0 = bf2f(x[lane]);
    const float x1 = bf2f(x[lane + 64]);
    float ss = fmaf(x0, x0, x1 * x1);
#pragma unroll
    for (int m = 1; m < 64; m <<= 1) ss += __shfl_xor(ss, m);
    const float inv = rsqrtf(ss * (1.f / 128.f) + EPS_);
    const bf16* z = zbuf + (size_t)bs * VAL_DIM_ + hv * DV_;
    x[lane] = f2bf(x0 * inv * nw[lane] * silu_f(bf2f(z[lane])));
    x[lane + 64] =
        f2bf(x1 * inv * nw[lane + 64] * silu_f(bf2f(z[lane + 64])));
}

// ---------------------------------------------------------------------------
extern "C" void kernel_launch(void* const* d_in, const int* in_sizes, int n_in,
                              void* d_out, int out_size, void* d_ws,
                              size_t ws_size, hipStream_t stream) {
    const float* hidden  = (const float*)d_in[0];
    const float* W_qkvz  = (const float*)d_in[1];
    const float* W_ba    = (const float*)d_in[2];
    const float* conv_w  = (const float*)d_in[3];
    const float* dt_bias = (const float*)d_in[4];
    const float* A_log   = (const float*)d_in[5];
    const float* norm_w  = (const float*)d_in[6];
    const float* W_out   = (const float*)d_in[7];
    float* out = (float*)d_out;

    // ---- workspace (~324 MB <= proven 337.5) ----
    bf16* R = (bf16*)d_ws;
    bf16* hidden_bf = R;                         //  8,388,608 e
    bf16* Wq_bf = R + (size_t)8388608;           // 25,165,824 e
    bf16* qkvz  = R + (size_t)33554432;          // 50,331,648 e
    // P1 aliases (valid once conv has consumed qkvz):
    bf16* WkA  = R;                              // 16,777,216 e
    bf16* QgA  = R + (size_t)16777216;           // 16,777,216 e
    bf16* Kg2A = R + (size_t)33554432;           // 16,777,216 e
    bf16* UA   = R + (size_t)50331648;           // 16,777,216 e
    bf16* LA   = R + (size_t)67108864;           //  8,388,608 e
    // non-aliased:
    bf16* Wo_bf = R + (size_t)83886080;          //  8,388,608 e
    bf16* qbf   = Wo_bf + (size_t)8388608;       //  8,388,608 e
    bf16* kbf   = qbf + (size_t)8388608;         //  8,388,608 e
    bf16* vbuf  = kbf + (size_t)8388608;         // 16,777,216 e
    bf16* zbuf  = vbuf + (size_t)16777216;       // 16,777,216 e
    bf16* core  = zbuf + (size_t)16777216;       // 16,777,216 e
    float* ba_part = (float*)(core + (size_t)16777216);  // 1,048,576 f
    float* gbuf    = ba_part + 1048576;                  //   131,072 f
    float* betabuf = gbuf + 131072;                      //   131,072 f
    float* gcArr   = betabuf + 131072;                   //     2,048 f

    const int MBS = B_ * S_;  // 4096

    // 0. fp32 -> bf16 operand conversion
    f2bf_kernel<<<8388608 / 1024, 256, 0, stream>>>(hidden, hidden_bf);
    f2bf_kernel<<<25165824 / 1024, 256, 0, stream>>>(W_qkvz, Wq_bf);
    f2bf_kernel<<<8388608 / 1024, 256, 0, stream>>>(W_out, Wo_bf);

    // 1. qkvz = hidden @ W_qkvz^T (256^2-tile counted-vmcnt MFMA GEMM)
    gemm256_nt<<<dim3(QKVZ_DIM_ / 256, MBS / 256), 512, 0, stream>>>(
        hidden_bf, Wq_bf, qkvz, MBS, QKVZ_DIM_, HID_);
    // 2. ba = hidden @ W_ba^T (fp32, K-split x4)
    gemm_ba_ksplit<<<dim3(4, 64), 256, 0, stream>>>(hidden, W_ba, ba_part);
    // 3. gates
    gate_kernel<<<(MBS * HV_) / 256, 256, 0, stream>>>(ba_part, A_log, dt_bias,
                                                       gbuf, betabuf);
    // 4. conv + silu (8-wide) + z copy
    conv_silu_kernel<<<(int)(((int64_t)MBS * 1536) / 256), 256, 0, stream>>>(
        qkvz, conv_w, qbf, kbf, vbuf, zbuf);
    // 4b. normalize q/k
    normalize_qk_kernel<<<(MBS * HK_ * 64) / 256, 256, 0, stream>>>(qbf, kbf);
    // 5. chunked delta rule
    p1_kernel<<<2048, 256, 0, stream>>>(qbf, kbf, vbuf, gbuf, betabuf, WkA,
                                        QgA, Kg2A, UA, LA, gcArr);
    p2_kernel<<<256, 256, 0, stream>>>(WkA, QgA, Kg2A, UA, LA, gcArr, core);
    // 6. gated rmsnorm
    rmsnorm_gate_kernel<<<(MBS * HV_ * 64) / 256, 256, 0, stream>>>(core, zbuf,
                                                                    norm_w);
    // 7. out = core @ W_out^T (m97 structure)
    gemm_mfma_nt<0><<<dim3(HID_ / 128, MBS / 128), 256, 0, stream>>>(
        core, Wo_bf, (void*)out, MBS, HID_, VAL_DIM_);
}

// Round 16
// 740.909 us; speedup vs baseline: 1.9535x; 1.0497x over previous
//
#include <hip/hip_runtime.h>
#include <cstdint>
#include <cstddef>

#define B_ 2
#define S_ 2048
#define HID_ 2048
#define HK_ 16
#define HV_ 32
#define DK_ 128
#define DV_ 128
#define KEY_DIM_ 2048
#define VAL_DIM_ 4096
#define QKVZ_DIM_ 12288
#define BA_DIM_ 64
#define CONV_DIM_ 8192
#define EPS_ 1e-6f
#define NCHUNK_ 32
#define CL_ 64   // chunk length

typedef unsigned short bf16;
typedef __attribute__((ext_vector_type(8))) short bf16x8;
typedef __attribute__((ext_vector_type(8))) unsigned short u16x8;
typedef __attribute__((ext_vector_type(4))) float f32x4;

__device__ __forceinline__ float silu_f(float x) { return x / (1.f + expf(-x)); }

__device__ __forceinline__ bf16 f2bf(float x) {
    unsigned int u = __float_as_uint(x);
    u += 0x7FFF + ((u >> 16) & 1);   // round-to-nearest-even
    return (bf16)(u >> 16);
}
__device__ __forceinline__ float bf2f(bf16 x) {
    return __uint_as_float((unsigned)x << 16);
}
#define BF2F_LO(u) __uint_as_float((unsigned)(u) << 16)
#define BF2F_HI(u) __uint_as_float((unsigned)(u) & 0xFFFF0000u)

__device__ __forceinline__ float bf_lane(const uint4& x, int j) {
    const unsigned wv = (&x.x)[j >> 1];
    return (j & 1) ? BF2F_HI(wv) : BF2F_LO(wv);
}

typedef const __attribute__((address_space(1))) unsigned int cgu32;
typedef __attribute__((address_space(3))) unsigned int lsu32;
__device__ __forceinline__ void gld16(const void* g, void* l) {
    __builtin_amdgcn_global_load_lds((cgu32*)g, (lsu32*)l, 16, 0, 0);
}

#define MFMA16(a, b, c) __builtin_amdgcn_mfma_f32_16x16x32_bf16((a), (b), (c), 0, 0, 0)

// ---------------------------------------------------------------------------
// fp32 -> bf16 conversion, 4 elems/thread
// ---------------------------------------------------------------------------
__global__ __launch_bounds__(256) void f2bf_kernel(const float* __restrict__ in,
                                                   bf16* __restrict__ out) {
    const int64_t i = (int64_t)blockIdx.x * 256 + threadIdx.x;
    const float4 v = ((const float4*)in)[i];
    ushort4 o;
    o.x = f2bf(v.x); o.y = f2bf(v.y); o.z = f2bf(v.z); o.w = f2bf(v.w);
    ((ushort4*)out)[i] = o;
}

// ---------------------------------------------------------------------------
// 256xBNT-tile bf16 MFMA GEMM NT, 512 threads (8 waves, 2Mx4N), BK=32,
// 3-slot LDS ring, counted vmcnt, setprio. LDS bank swizzle: chunk index
// XORed with (row>>1)&3 on BOTH the staged global source and the ds_read
// offset -> 16 lanes reading 16 consecutive rows hit 8 distinct bank-groups
// (parity x 4 chunks) = free 2-way aliasing.
// ---------------------------------------------------------------------------
template <int BNT, int OUTBF16>
__global__ __launch_bounds__(512, 2) void gemm256_nt(
    const bf16* __restrict__ A, const bf16* __restrict__ Bm,
    void* __restrict__ Cv, int M, int N, int K) {
    __shared__ bf16 ringA[3][8192];
    __shared__ bf16 ringB[3][BNT * 32];
    const int tid = threadIdx.x;
    const int w = tid >> 6;
    const int l = tid & 63;
    const int wm = w >> 2;
    const int wn = w & 3;
    const int fl = l & 15;
    const int fk = (l >> 4) * 8;
    const int bm = blockIdx.y, bn = blockIdx.x;

    // staging: lane covers row srow=tid>>2, LDS chunk tid&3; source chunk is
    // XOR-swizzled by (srow>>1)&3 = (tid>>3)&3.
    const int srow = tid >> 2;
    const int scol = (((tid & 3) ^ ((tid >> 3) & 3)) << 3);
    const bf16* Ag0 = A + (size_t)(bm * 256 + srow) * K + scol;
    const bf16* Ag1 = A + (size_t)(bm * 256 + 128 + srow) * K + scol;
    const bf16* Bg0 = Bm + (size_t)(bn * BNT + srow) * K + scol;
    const bf16* Bg1 = Bm + (size_t)(bn * BNT + 128 + srow) * K + scol;  // BNT=256 only

    // ds_read: logical chunk fk/8 of row (…+fl) lives at chunk ^ ((fl>>1)&3)
    const int kswz = fk ^ (((fl >> 1) & 3) << 3);
    const int NFR = BNT / 64;            // B fragments per wave (4 or 2)
    int aoff[8], boff[4];
#pragma unroll
    for (int mi = 0; mi < 8; ++mi)
        aoff[mi] = (wm * 128 + mi * 16 + fl) * 32 + kswz;
#pragma unroll
    for (int ni = 0; ni < NFR; ++ni)
        boff[ni] = (wn * (BNT / 4) + ni * 16 + fl) * 32 + kswz;

    f32x4 acc[8][4];
#pragma unroll
    for (int mi = 0; mi < 8; ++mi)
#pragma unroll
        for (int ni = 0; ni < NFR; ++ni) acc[mi][ni] = (f32x4){0.f, 0.f, 0.f, 0.f};

#define STAGEX(kt, slot)                                                       \
    do {                                                                       \
        const int _k = (kt) * 32;                                              \
        gld16(Ag0 + _k, &ringA[slot][w * 512]);                                \
        gld16(Ag1 + _k, &ringA[slot][4096 + w * 512]);                         \
        gld16(Bg0 + _k, &ringB[slot][w * 512]);                                \
        if (BNT == 256) gld16(Bg1 + _k, &ringB[slot][4096 + w * 512]);         \
    } while (0)

    const int nkt = K >> 5;
    STAGEX(0, 0);
    STAGEX(1, 1);

    for (int t = 0; t < nkt; ++t) {
        if (BNT == 256)
            asm volatile("s_waitcnt vmcnt(4)" ::: "memory");
        else
            asm volatile("s_waitcnt vmcnt(3)" ::: "memory");
        __builtin_amdgcn_s_barrier();
        __builtin_amdgcn_sched_barrier(0);
        const int slot = t % 3;
        const bf16* As_ = ringA[slot];
        const bf16* Bs_ = ringB[slot];
        bf16x8 af[8], bfr[4];
#pragma unroll
        for (int mi = 0; mi < 8; ++mi)
            af[mi] = *(const bf16x8*)(As_ + aoff[mi]);
#pragma unroll
        for (int ni = 0; ni < NFR; ++ni)
            bfr[ni] = *(const bf16x8*)(Bs_ + boff[ni]);
        const int kt2 = (t + 2 < nkt) ? (t + 2) : (nkt - 1);
        STAGEX(kt2, (t + 2) % 3);
        asm volatile("s_waitcnt lgkmcnt(0)" ::: "memory");
        __builtin_amdgcn_sched_barrier(0);
        __builtin_amdgcn_s_setprio(1);
#pragma unroll
        for (int mi = 0; mi < 8; ++mi)
#pragma unroll
            for (int ni = 0; ni < NFR; ++ni)
                acc[mi][ni] = MFMA16(af[mi], bfr[ni], acc[mi][ni]);
        __builtin_amdgcn_s_setprio(0);
    }
#undef STAGEX

#pragma unroll
    for (int mi = 0; mi < 8; ++mi)
#pragma unroll
        for (int ni = 0; ni < NFR; ++ni)
#pragma unroll
            for (int r = 0; r < 4; ++r) {
                const int row = bm * 256 + wm * 128 + mi * 16 + (l >> 4) * 4 + r;
                const int col = bn * BNT + wn * (BNT / 4) + ni * 16 + fl;
                if (OUTBF16)
                    ((bf16*)Cv)[(size_t)row * N + col] = f2bf(acc[mi][ni][r]);
                else
                    ((float*)Cv)[(size_t)row * N + col] = acc[mi][ni][r];
            }
}

// ---------------------------------------------------------------------------
// ba projection, fp32, K-split x4
// ---------------------------------------------------------------------------
#define BM 64
#define BN 64
#define BKK 32

__global__ __launch_bounds__(256) void gemm_ba_ksplit(
    const float* __restrict__ A, const float* __restrict__ Bm,
    float* __restrict__ Cpart) {
    __shared__ float As[BKK][BM + 4];
    __shared__ float Bs[BKK][BN + 4];
    const int tid = threadIdx.x;
    const int tx = tid & 15;
    const int ty = tid >> 4;
    const int ks = blockIdx.x;     // 0..3
    const int bm = blockIdx.y;     // 0..63
    const float* Ab = A + (size_t)bm * BM * HID_;
    const float* Bb = Bm;
    const int lr = tid >> 2;
    const int lc = (tid & 3) << 3;

    float c[4][4] = {{0.f, 0.f, 0.f, 0.f}, {0.f, 0.f, 0.f, 0.f},
                     {0.f, 0.f, 0.f, 0.f}, {0.f, 0.f, 0.f, 0.f}};

    const int kbeg = ks * 512;
    for (int k0 = kbeg; k0 < kbeg + 512; k0 += BKK) {
        const float4 a0 = *(const float4*)(Ab + (size_t)lr * HID_ + k0 + lc);
        const float4 a1 = *(const float4*)(Ab + (size_t)lr * HID_ + k0 + lc + 4);
        const float4 b0 = *(const float4*)(Bb + (size_t)lr * HID_ + k0 + lc);
        const float4 b1 = *(const float4*)(Bb + (size_t)lr * HID_ + k0 + lc + 4);
        __syncthreads();
        As[lc + 0][lr] = a0.x; As[lc + 1][lr] = a0.y;
        As[lc + 2][lr] = a0.z; As[lc + 3][lr] = a0.w;
        As[lc + 4][lr] = a1.x; As[lc + 5][lr] = a1.y;
        As[lc + 6][lr] = a1.z; As[lc + 7][lr] = a1.w;
        Bs[lc + 0][lr] = b0.x; Bs[lc + 1][lr] = b0.y;
        Bs[lc + 2][lr] = b0.z; Bs[lc + 3][lr] = b0.w;
        Bs[lc + 4][lr] = b1.x; Bs[lc + 5][lr] = b1.y;
        Bs[lc + 6][lr] = b1.z; Bs[lc + 7][lr] = b1.w;
        __syncthreads();
#pragma unroll
        for (int kk = 0; kk < BKK; ++kk) {
            const float4 Av = *(const float4*)&As[kk][ty << 2];
            const float4 Bv = *(const float4*)&Bs[kk][tx << 2];
            const float aa[4] = {Av.x, Av.y, Av.z, Av.w};
            const float bb[4] = {Bv.x, Bv.y, Bv.z, Bv.w};
#pragma unroll
            for (int i = 0; i < 4; ++i)
#pragma unroll
                for (int j = 0; j < 4; ++j)
                    c[i][j] = fmaf(aa[i], bb[j], c[i][j]);
        }
    }
    float* Cp = Cpart + (size_t)ks * ((size_t)B_ * S_ * 64) +
                (size_t)(bm * BM + (ty << 2)) * 64 + (tx << 2);
#pragma unroll
    for (int i = 0; i < 4; ++i)
        *(float4*)(Cp + (size_t)i * 64) =
            make_float4(c[i][0], c[i][1], c[i][2], c[i][3]);
}

// ---------------------------------------------------------------------------
// Causal depthwise conv (K=4) + SiLU, 8 channels/thread + z passthrough.
// ---------------------------------------------------------------------------
__global__ __launch_bounds__(256) void conv_silu_kernel(
    const bf16* __restrict__ qkvz, const float* __restrict__ cw,
    bf16* __restrict__ qbf, bf16* __restrict__ kbf, bf16* __restrict__ vbuf,
    bf16* __restrict__ zbuf) {
    const int64_t idx = (int64_t)blockIdx.x * 256 + threadIdx.x;
    const int cg = (int)(idx % 1536);
    const int64_t bs = idx / 1536;
    const int s = (int)(bs & (S_ - 1));
    const int c0 = cg << 3;

    int col;
    bf16* outp;
    if (c0 < KEY_DIM_) {
        col = ((c0 >> 7) * 768) + (c0 & 127);
        outp = qbf + bs * KEY_DIM_ + c0;
    } else if (c0 < 2 * KEY_DIM_) {
        const int c2 = c0 - KEY_DIM_;
        col = ((c2 >> 7) * 768) + 128 + (c2 & 127);
        outp = kbf + bs * KEY_DIM_ + c2;
    } else if (c0 < 2 * KEY_DIM_ + VAL_DIM_) {
        const int c3 = c0 - 2 * KEY_DIM_;
        col = ((c3 >> 8) * 768) + 256 + (c3 & 255);
        outp = vbuf + bs * VAL_DIM_ + c3;
    } else {
        const int zc = c0 - (2 * KEY_DIM_ + VAL_DIM_);
        const int hv = zc >> 7;
        col = (hv >> 1) * 768 + 512 + (hv & 1) * 128 + (zc & 127);
        outp = zbuf + bs * VAL_DIM_ + zc;
    }
    const bf16* xp = qkvz + bs * (int64_t)QKVZ_DIM_ + col;
    if (c0 >= 2 * KEY_DIM_ + VAL_DIM_) {
        *(uint4*)outp = *(const uint4*)xp;   // z passthrough
        return;
    }
    const uint4 zero4 = {0u, 0u, 0u, 0u};
    const uint4 x0 = *(const uint4*)xp;
    const uint4 x1 = (s >= 1) ? *(const uint4*)(xp - QKVZ_DIM_) : zero4;
    const uint4 x2 = (s >= 2) ? *(const uint4*)(xp - 2 * QKVZ_DIM_) : zero4;
    const uint4 x3 = (s >= 3) ? *(const uint4*)(xp - 3 * QKVZ_DIM_) : zero4;
    u16x8 o;
#pragma unroll
    for (int j = 0; j < 8; ++j) {
        const float4 wv = *(const float4*)(cw + (size_t)(c0 + j) * 4);
        float acc = wv.w * bf_lane(x0, j);
        acc = fmaf(wv.z, bf_lane(x1, j), acc);
        acc = fmaf(wv.y, bf_lane(x2, j), acc);
        acc = fmaf(wv.x, bf_lane(x3, j), acc);
        o[j] = f2bf(silu_f(acc));
    }
    *(u16x8*)outp = o;
}

// ---------------------------------------------------------------------------
// Pre-normalize q/k (bf16 in/out, fp32 math)
// ---------------------------------------------------------------------------
__global__ __launch_bounds__(256) void normalize_qk_kernel(
    bf16* __restrict__ qbf, bf16* __restrict__ kbf) {
    const int wid = (blockIdx.x * 256 + threadIdx.x) >> 6;  // B*S*HK
    const int lane = threadIdx.x & 63;
    const int hk = wid & (HK_ - 1);
    const int64_t bs = wid >> 4;
    bf16* qp = qbf + bs * KEY_DIM_ + hk * DK_ + lane * 2;
    bf16* kp = kbf + bs * KEY_DIM_ + hk * DK_ + lane * 2;
    const ushort2 qw = *(const ushort2*)qp;
    const ushort2 kw = *(const ushort2*)kp;
    const float q0 = bf2f(qw.x), q1 = bf2f(qw.y);
    const float k0 = bf2f(kw.x), k1 = bf2f(kw.y);
    float qs = fmaf(q0, q0, q1 * q1);
    float ks = fmaf(k0, k0, k1 * k1);
#pragma unroll
    for (int m = 1; m < 64; m <<= 1) {
        qs += __shfl_xor(qs, m);
        ks += __shfl_xor(ks, m);
    }
    const float qsc = rsqrtf(qs + EPS_) * 0.08838834764831845f;  // DK^-0.5
    const float ksc = rsqrtf(ks + EPS_);
    ushort2 oq, ok;
    oq.x = f2bf(q0 * qsc); oq.y = f2bf(q1 * qsc);
    ok.x = f2bf(k0 * ksc); ok.y = f2bf(k1 * ksc);
    *(ushort2*)qp = oq;
    *(ushort2*)kp = ok;
}

// ---------------------------------------------------------------------------
// Gate precompute from 4 K-split partials
// ---------------------------------------------------------------------------
__global__ __launch_bounds__(256) void gate_kernel(
    const float* __restrict__ ba_part, const float* __restrict__ A_log,
    const float* __restrict__ dt_bias, float* __restrict__ gbuf,
    float* __restrict__ betabuf) {
    const int idx = blockIdx.x * 256 + threadIdx.x;   // B*S*HV
    const int hv = idx & (HV_ - 1);
    const int bs = idx >> 5;
    const int hk = hv >> 1, j = hv & 1;
    const size_t SP = (size_t)B_ * S_ * 64;  // 262144
    const float* p = ba_part + (size_t)bs * 64 + hk * 4;
    const float bval = p[j] + p[SP + j] + p[2 * SP + j] + p[3 * SP + j];
    const float aval =
        p[2 + j] + p[SP + 2 + j] + p[2 * SP + 2 + j] + p[3 * SP + 2 + j];
    const float x = aval + dt_bias[hv];
    const float sp = (x > 20.f) ? x : log1pf(expf(x));
    gbuf[idx] = -expf(A_log[hv]) * sp;
    betabuf[idx] = 1.f / (1.f + expf(-bval));
}

// ---------------------------------------------------------------------------
// PASS 1 — R15 structure (register substitution + wave specialization).
// ---------------------------------------------------------------------------
__global__ __launch_bounds__(256) void p1_kernel(
    const bf16* __restrict__ qbf, const bf16* __restrict__ kbf,
    const bf16* __restrict__ vbuf, const float* __restrict__ gbuf,
    const float* __restrict__ betabuf, bf16* __restrict__ WkA,
    bf16* __restrict__ QgA, bf16* __restrict__ Kg2A, bf16* __restrict__ UA,
    bf16* __restrict__ LA, float* __restrict__ gcArr) {
    const int ch = blockIdx.x;          // bh*32 + c
    const int bh = ch >> 5, c = ch & 31;
    const int b = bh >> 5, hv = bh & 31;
    const int hk = hv >> 1;
    const int tid = threadIdx.x;
    const int w = tid >> 6, l = tid & 63;
    const int fl = l & 15, fk = (l >> 4) * 8;

    __shared__ float Gls[CL_];
    __shared__ float Bls[CL_];
    __shared__ float Egt[CL_];          // exp(G_t)
    __shared__ float Egc[CL_];          // exp(G63 - G_t)
    __shared__ float A_ls[CL_][CL_ + 1];
    __shared__ bf16 Tbf[CL_ * CL_];
    __shared__ bf16 Vt[128 * 72];
    __shared__ bf16 Kt[128 * 72];

    if (tid < 64) {
        float G = gbuf[((size_t)(b * S_ + c * 64 + tid)) * HV_ + hv];
        Bls[tid] = betabuf[((size_t)(b * S_ + c * 64 + tid)) * HV_ + hv];
#pragma unroll
        for (int d = 1; d < 64; d <<= 1) {
            const float n = __shfl_up(G, d, 64);
            if (tid >= d) G += n;
        }
        Gls[tid] = G;
        const float eg = expf(G);
        Egt[tid] = eg;
        Egc[tid] = expf(__shfl(G, 63, 64) - G);
        if (tid == 63) gcArr[ch] = eg;
    }
    __syncthreads();

    const bf16* kc = kbf + ((size_t)(b * S_ + c * 64)) * KEY_DIM_ + hk * DK_;
    const bf16* qc = qbf + ((size_t)(b * S_ + c * 64)) * KEY_DIM_ + hk * DK_;
    bf16* LC = LA + (size_t)ch * 4096;

    f32x4 accK[4], accQ[4];
#pragma unroll
    for (int n = 0; n < 4; ++n) {
        accK[n] = (f32x4){0.f, 0.f, 0.f, 0.f};
        accQ[n] = (f32x4){0.f, 0.f, 0.f, 0.f};
    }
#pragma unroll
    for (int kk = 0; kk < 4; ++kk) {
        const bf16x8 aK =
            *(const bf16x8*)(kc + (size_t)(w * 16 + fl) * KEY_DIM_ + fk + 32 * kk);
        const bf16x8 aQ =
            *(const bf16x8*)(qc + (size_t)(w * 16 + fl) * KEY_DIM_ + fk + 32 * kk);
#pragma unroll
        for (int n = 0; n < 4; ++n) {
            const bf16x8 bK = *(const bf16x8*)(kc + (size_t)(n * 16 + fl) * KEY_DIM_ +
                                               fk + 32 * kk);
            accK[n] = MFMA16(aK, bK, accK[n]);
            accQ[n] = MFMA16(aQ, bK, accQ[n]);
        }
    }
#pragma unroll
    for (int n = 0; n < 4; ++n)
#pragma unroll
        for (int r = 0; r < 4; ++r) {
            const int t = w * 16 + (l >> 4) * 4 + r;
            const int s = n * 16 + fl;
            const float eg = expf(Gls[t] - Gls[s]);
            A_ls[t][s] = (s < t) ? Bls[t] * eg * accK[n][r] : 0.f;
            const float lv = (s <= t) ? eg * accQ[n][r] : 0.f;
            LC[t * 64 + s] = f2bf(lv);
        }
    __syncthreads();

    bf16* QgC = QgA + (size_t)ch * 8192;
    bf16* KgC = Kg2A + (size_t)ch * 8192;

    if (w == 0) {
        float Tcol[64];
#pragma unroll
        for (int t = 0; t < 64; ++t) {
            float acc = (t == l) ? 1.f : 0.f;
#pragma unroll
            for (int s = 0; s < t; ++s)
                acc = fmaf(-A_ls[t][s], Tcol[s], acc);
            Tcol[t] = acc;
            Tbf[t * 64 + l] = f2bf(acc);
        }
    } else if (w == 1) {
        for (int i = l; i < 8192; i += 64) {
            const int d = i & 127, s = i >> 7;
            Vt[d * 72 + s] = f2bf(
                bf2f(vbuf[((size_t)(b * S_ + c * 64 + s)) * VAL_DIM_ + hv * DV_ + d]) *
                Bls[s]);
        }
    } else if (w == 2) {
        for (int i = l; i < 8192; i += 64) {
            const int d = i & 127, s = i >> 7;
            Kt[d * 72 + s] =
                f2bf(bf2f(kc[(size_t)s * KEY_DIM_ + d]) * Bls[s] * Egt[s]);
        }
    } else {
        for (int i = l; i < 8192; i += 64) {
            const int d = i & 127, t = i >> 7;
            QgC[t * 128 + d] = f2bf(bf2f(qc[(size_t)t * KEY_DIM_ + d]) * Egt[t]);
            KgC[d * 64 + t] = f2bf(bf2f(kc[(size_t)t * KEY_DIM_ + d]) * Egc[t]);
        }
    }
    __syncthreads();

    bf16* UC = UA + (size_t)ch * 8192;
    bf16* WkC = WkA + (size_t)ch * 8192;
    f32x4 accU[8], accW[8];
#pragma unroll
    for (int n = 0; n < 8; ++n) {
        accU[n] = (f32x4){0.f, 0.f, 0.f, 0.f};
        accW[n] = (f32x4){0.f, 0.f, 0.f, 0.f};
    }
#pragma unroll
    for (int kk = 0; kk < 2; ++kk) {
        const bf16x8 aT = *(const bf16x8*)(Tbf + (w * 16 + fl) * 64 + fk + 32 * kk);
#pragma unroll
        for (int n = 0; n < 8; ++n) {
            const bf16x8 bV = *(const bf16x8*)(Vt + (n * 16 + fl) * 72 + fk + 32 * kk);
            const bf16x8 bK2 = *(const bf16x8*)(Kt + (n * 16 + fl) * 72 + fk + 32 * kk);
            accU[n] = MFMA16(aT, bV, accU[n]);
            accW[n] = MFMA16(aT, bK2, accW[n]);
        }
    }
#pragma unroll
    for (int n = 0; n < 8; ++n)
#pragma unroll
        for (int r = 0; r < 4; ++r) {
            const int t = w * 16 + (l >> 4) * 4 + r;
            const int col = n * 16 + fl;
            UC[t * 128 + col] = f2bf(accU[n][r]);
            WkC[t * 128 + col] = f2bf(accW[n][r]);
        }
}

// ---------------------------------------------------------------------------
// PASS 2 — unchanged from R12.
// ---------------------------------------------------------------------------
__global__ __launch_bounds__(256) void p2_kernel(
    const bf16* __restrict__ WkA, const bf16* __restrict__ QgA,
    const bf16* __restrict__ Kg2A, const bf16* __restrict__ UA,
    const bf16* __restrict__ LA, const float* __restrict__ gcArr,
    bf16* __restrict__ core) {
    const int xcd = blockIdx.x & 7;
    const int rr = blockIdx.x >> 3;       // 0..31
    const int bh = xcd * 8 + (rr & 7);    // 0..63
    const int dvb = rr >> 3;              // 0..3
    const int b = bh >> 5, hv = bh & 31;
    const int tid = threadIdx.x;
    const int w = tid >> 6, l = tid & 63;
    const int fl = l & 15, fk = (l >> 4) * 8;

    __shared__ bf16 Sbf[32 * 136];
    __shared__ bf16 Dbf[32 * 72];

    for (int i = tid; i < 32 * 136; i += 256) Sbf[i] = 0;
    f32x4 accS[2][2];
#pragma unroll
    for (int m = 0; m < 2; ++m)
#pragma unroll
        for (int n = 0; n < 2; ++n) accS[m][n] = (f32x4){0.f, 0.f, 0.f, 0.f};
    __syncthreads();

    for (int c = 0; c < NCHUNK_; ++c) {
        const size_t ch = (size_t)bh * 32 + c;
        const bf16* WkC = WkA + ch * 8192;
        const bf16* QgC = QgA + ch * 8192;
        const bf16* KgC = Kg2A + ch * 8192;
        const bf16* UC = UA + ch * 8192;
        const bf16* LC = LA + ch * 4096;

        f32x4 accD[2], accO[2];
#pragma unroll
        for (int n = 0; n < 2; ++n) {
            accD[n] = (f32x4){0.f, 0.f, 0.f, 0.f};
            accO[n] = (f32x4){0.f, 0.f, 0.f, 0.f};
        }
#pragma unroll
        for (int kk = 0; kk < 4; ++kk) {
            const bf16x8 bS0 = *(const bf16x8*)(Sbf + (0 * 16 + fl) * 136 + fk + 32 * kk);
            const bf16x8 bS1 = *(const bf16x8*)(Sbf + (1 * 16 + fl) * 136 + fk + 32 * kk);
            const bf16x8 aW = *(const bf16x8*)(WkC + (w * 16 + fl) * 128 + fk + 32 * kk);
            const bf16x8 aQ = *(const bf16x8*)(QgC + (w * 16 + fl) * 128 + fk + 32 * kk);
            accD[0] = MFMA16(aW, bS0, accD[0]);
            accD[1] = MFMA16(aW, bS1, accD[1]);
            accO[0] = MFMA16(aQ, bS0, accO[0]);
            accO[1] = MFMA16(aQ, bS1, accO[1]);
        }
#pragma unroll
        for (int n = 0; n < 2; ++n)
#pragma unroll
            for (int r = 0; r < 4; ++r) {
                const int t = w * 16 + (l >> 4) * 4 + r;
                const int dvl = n * 16 + fl;
                const float u = bf2f(UC[t * 128 + dvb * 32 + dvl]);
                Dbf[dvl * 72 + t] = f2bf(u - accD[n][r]);
            }
        __syncthreads();

#pragma unroll
        for (int kk = 0; kk < 2; ++kk) {
            const bf16x8 bD0 = *(const bf16x8*)(Dbf + (0 * 16 + fl) * 72 + fk + 32 * kk);
            const bf16x8 bD1 = *(const bf16x8*)(Dbf + (1 * 16 + fl) * 72 + fk + 32 * kk);
            const bf16x8 aL = *(const bf16x8*)(LC + (w * 16 + fl) * 64 + fk + 32 * kk);
            accO[0] = MFMA16(aL, bD0, accO[0]);
            accO[1] = MFMA16(aL, bD1, accO[1]);
        }
#pragma unroll
        for (int n = 0; n < 2; ++n)
#pragma unroll
            for (int r = 0; r < 4; ++r) {
                const int t = w * 16 + (l >> 4) * 4 + r;
                const int col = hv * 128 + dvb * 32 + n * 16 + fl;
                core[((size_t)(b * S_ + c * 64 + t)) * VAL_DIM_ + col] =
                    f2bf(accO[n][r]);
            }

        const float gc = gcArr[ch];
#pragma unroll
        for (int m = 0; m < 2; ++m)
#pragma unroll
            for (int n = 0; n < 2; ++n)
#pragma unroll
                for (int r = 0; r < 4; ++r) accS[m][n][r] *= gc;
#pragma unroll
        for (int kk = 0; kk < 2; ++kk) {
            const bf16x8 bD0 = *(const bf16x8*)(Dbf + (0 * 16 + fl) * 72 + fk + 32 * kk);
            const bf16x8 bD1 = *(const bf16x8*)(Dbf + (1 * 16 + fl) * 72 + fk + 32 * kk);
#pragma unroll
            for (int m = 0; m < 2; ++m) {
                const bf16x8 aK =
                    *(const bf16x8*)(KgC + ((2 * w + m) * 16 + fl) * 64 + fk + 32 * kk);
                accS[m][0] = MFMA16(aK, bD0, accS[m][0]);
                accS[m][1] = MFMA16(aK, bD1, accS[m][1]);
            }
        }
        __syncthreads();
#pragma unroll
        for (int m = 0; m < 2; ++m)
#pragma unroll
            for (int n = 0; n < 2; ++n)
#pragma unroll
                for (int r = 0; r < 4; ++r) {
                    const int dk = (2 * w + m) * 16 + (l >> 4) * 4 + r;
                    const int dvl = n * 16 + fl;
                    Sbf[dvl * 136 + dk] = f2bf(accS[m][n][r]);
                }
        __syncthreads();
    }
}

// ---------------------------------------------------------------------------
// Gated RMSNorm in-place on bf16 core; z from zbuf (contiguous).
// ---------------------------------------------------------------------------
__global__ __launch_bounds__(256) void rmsnorm_gate_kernel(
    bf16* __restrict__ core, const bf16* __restrict__ zbuf,
    const float* __restrict__ nw) {
    const int wid = (blockIdx.x * 256 + threadIdx.x) >> 6;
    const int lane = threadIdx.x & 63;
    const int hv = wid & (HV_ - 1);
    const int64_t bs = wid >> 5;
    bf16* x = core + (size_t)bs * VAL_DIM_ + hv * DV_;
    const float x0 = bf2f(x[lane]);
    const float x1 = bf2f(x[lane + 64]);
    float ss = fmaf(x0, x0, x1 * x1);
#pragma unroll
    for (int m = 1; m < 64; m <<= 1) ss += __shfl_xor(ss, m);
    const float inv = rsqrtf(ss * (1.f / 128.f) + EPS_);
    const bf16* z = zbuf + (size_t)bs * VAL_DIM_ + hv * DV_;
    x[lane] = f2bf(x0 * inv * nw[lane] * silu_f(bf2f(z[lane])));
    x[lane + 64] =
        f2bf(x1 * inv * nw[lane + 64] * silu_f(bf2f(z[lane + 64])));
}

// ---------------------------------------------------------------------------
extern "C" void kernel_launch(void* const* d_in, const int* in_sizes, int n_in,
                              void* d_out, int out_size, void* d_ws,
                              size_t ws_size, hipStream_t stream) {
    const float* hidden  = (const float*)d_in[0];
    const float* W_qkvz  = (const float*)d_in[1];
    const float* W_ba    = (const float*)d_in[2];
    const float* conv_w  = (const float*)d_in[3];
    const float* dt_bias = (const float*)d_in[4];
    const float* A_log   = (const float*)d_in[5];
    const float* norm_w  = (const float*)d_in[6];
    const float* W_out   = (const float*)d_in[7];
    float* out = (float*)d_out;

    // ---- workspace (~324 MB <= proven 337.5) ----
    bf16* R = (bf16*)d_ws;
    bf16* hidden_bf = R;                         //  8,388,608 e
    bf16* Wq_bf = R + (size_t)8388608;           // 25,165,824 e
    bf16* qkvz  = R + (size_t)33554432;          // 50,331,648 e
    // P1 aliases (valid once conv has consumed qkvz):
    bf16* WkA  = R;                              // 16,777,216 e
    bf16* QgA  = R + (size_t)16777216;           // 16,777,216 e
    bf16* Kg2A = R + (size_t)33554432;           // 16,777,216 e
    bf16* UA   = R + (size_t)50331648;           // 16,777,216 e
    bf16* LA   = R + (size_t)67108864;           //  8,388,608 e
    // non-aliased:
    bf16* Wo_bf = R + (size_t)83886080;          //  8,388,608 e
    bf16* qbf   = Wo_bf + (size_t)8388608;       //  8,388,608 e
    bf16* kbf   = qbf + (size_t)8388608;         //  8,388,608 e
    bf16* vbuf  = kbf + (size_t)8388608;         // 16,777,216 e
    bf16* zbuf  = vbuf + (size_t)16777216;       // 16,777,216 e
    bf16* core  = zbuf + (size_t)16777216;       // 16,777,216 e
    float* ba_part = (float*)(core + (size_t)16777216);  // 1,048,576 f
    float* gbuf    = ba_part + 1048576;                  //   131,072 f
    float* betabuf = gbuf + 131072;                      //   131,072 f
    float* gcArr   = betabuf + 131072;                   //     2,048 f

    const int MBS = B_ * S_;  // 4096

    // 0. fp32 -> bf16 operand conversion
    f2bf_kernel<<<8388608 / 1024, 256, 0, stream>>>(hidden, hidden_bf);
    f2bf_kernel<<<25165824 / 1024, 256, 0, stream>>>(W_qkvz, Wq_bf);
    f2bf_kernel<<<8388608 / 1024, 256, 0, stream>>>(W_out, Wo_bf);

    // 1. qkvz = hidden @ W_qkvz^T (256^2-tile counted-vmcnt MFMA GEMM)
    gemm256_nt<256, 1><<<dim3(QKVZ_DIM_ / 256, MBS / 256), 512, 0, stream>>>(
        hidden_bf, Wq_bf, (void*)qkvz, MBS, QKVZ_DIM_, HID_);
    // 2. ba = hidden @ W_ba^T (fp32, K-split x4)
    gemm_ba_ksplit<<<dim3(4, 64), 256, 0, stream>>>(hidden, W_ba, ba_part);
    // 3. gates
    gate_kernel<<<(MBS * HV_) / 256, 256, 0, stream>>>(ba_part, A_log, dt_bias,
                                                       gbuf, betabuf);
    // 4. conv + silu (8-wide) + z copy
    conv_silu_kernel<<<(int)(((int64_t)MBS * 1536) / 256), 256, 0, stream>>>(
        qkvz, conv_w, qbf, kbf, vbuf, zbuf);
    // 4b. normalize q/k
    normalize_qk_kernel<<<(MBS * HK_ * 64) / 256, 256, 0, stream>>>(qbf, kbf);
    // 5. chunked delta rule
    p1_kernel<<<2048, 256, 0, stream>>>(qbf, kbf, vbuf, gbuf, betabuf, WkA,
                                        QgA, Kg2A, UA, LA, gcArr);
    p2_kernel<<<256, 256, 0, stream>>>(WkA, QgA, Kg2A, UA, LA, gcArr, core);
    // 6. gated rmsnorm
    rmsnorm_gate_kernel<<<(MBS * HV_ * 64) / 256, 256, 0, stream>>>(core, zbuf,
                                                                    norm_w);
    // 7. out = core @ W_out^T (256x128-tile pipelined, 256 WGs, fp32 out)
    gemm256_nt<128, 0><<<dim3(HID_ / 128, MBS / 256), 512, 0, stream>>>(
        core, Wo_bf, (void*)out, MBS, HID_, VAL_DIM_);
}

// Round 17
// 711.409 us; speedup vs baseline: 2.0345x; 1.0415x over previous
//
#include <hip/hip_runtime.h>
#include <cstdint>
#include <cstddef>

#define B_ 2
#define S_ 2048
#define HID_ 2048
#define HK_ 16
#define HV_ 32
#define DK_ 128
#define DV_ 128
#define KEY_DIM_ 2048
#define VAL_DIM_ 4096
#define QKVZ_DIM_ 12288
#define BA_DIM_ 64
#define CONV_DIM_ 8192
#define EPS_ 1e-6f
#define NCHUNK_ 32
#define CL_ 64   // chunk length

typedef unsigned short bf16;
typedef __attribute__((ext_vector_type(8))) short bf16x8;
typedef __attribute__((ext_vector_type(8))) unsigned short u16x8;
typedef __attribute__((ext_vector_type(4))) float f32x4;

__device__ __forceinline__ float silu_f(float x) { return x / (1.f + expf(-x)); }

__device__ __forceinline__ bf16 f2bf(float x) {
    unsigned int u = __float_as_uint(x);
    u += 0x7FFF + ((u >> 16) & 1);   // round-to-nearest-even
    return (bf16)(u >> 16);
}
__device__ __forceinline__ float bf2f(bf16 x) {
    return __uint_as_float((unsigned)x << 16);
}
#define BF2F_LO(u) __uint_as_float((unsigned)(u) << 16)
#define BF2F_HI(u) __uint_as_float((unsigned)(u) & 0xFFFF0000u)

__device__ __forceinline__ float bf_lane(const uint4& x, int j) {
    const unsigned wv = (&x.x)[j >> 1];
    return (j & 1) ? BF2F_HI(wv) : BF2F_LO(wv);
}

typedef const __attribute__((address_space(1))) unsigned int cgu32;
typedef __attribute__((address_space(3))) unsigned int lsu32;
__device__ __forceinline__ void gld16(const void* g, void* l) {
    __builtin_amdgcn_global_load_lds((cgu32*)g, (lsu32*)l, 16, 0, 0);
}

#define MFMA16(a, b, c) __builtin_amdgcn_mfma_f32_16x16x32_bf16((a), (b), (c), 0, 0, 0)

// DPP rotate-add within 16-lane rows (for conv-fused l2norm)
template <int CTRL>
__device__ __forceinline__ float dpp_ror_add(float x) {
    const int t =
        __builtin_amdgcn_update_dpp(0, __float_as_int(x), CTRL, 0xF, 0xF, false);
    return x + __int_as_float(t);
}
__device__ __forceinline__ float row16_sum(float x) {
    x = dpp_ror_add<0x128>(x);
    x = dpp_ror_add<0x124>(x);
    x = dpp_ror_add<0x122>(x);
    x = dpp_ror_add<0x121>(x);
    return x;
}

// ---------------------------------------------------------------------------
// fp32 -> bf16 conversion, fused over hidden | W_qkvz | W_out segments.
// ---------------------------------------------------------------------------
__global__ __launch_bounds__(256) void f2bf3_kernel(
    const float* __restrict__ s0, const float* __restrict__ s1,
    const float* __restrict__ s2, bf16* __restrict__ d0,
    bf16* __restrict__ d1, bf16* __restrict__ d2) {
    const int64_t i = (int64_t)blockIdx.x * 256 + threadIdx.x;  // vec4 index
    const float* src;
    bf16* dst;
    int64_t j;
    if (i < 2097152) {                       // hidden: 8,388,608 elems
        src = s0; dst = d0; j = i;
    } else if (i < 2097152 + 6291456) {      // W_qkvz: 25,165,824 elems
        src = s1; dst = d1; j = i - 2097152;
    } else {                                 // W_out: 8,388,608 elems
        src = s2; dst = d2; j = i - (2097152 + 6291456);
    }
    const float4 v = ((const float4*)src)[j];
    ushort4 o;
    o.x = f2bf(v.x); o.y = f2bf(v.y); o.z = f2bf(v.z); o.w = f2bf(v.w);
    ((ushort4*)dst)[j] = o;
}

// ---------------------------------------------------------------------------
// 256xBNT-tile bf16 MFMA GEMM NT, 512 threads (8 waves, 2Mx4N), BK=32,
// 3-slot LDS ring, counted vmcnt, setprio. Bank swizzle (R16, verified:
// conflicts=0). NO manual lgkm fence: ds_reads are compiler-visible, so the
// compiler emits fine-grained lgkmcnt and interleaves reads/STAGE/MFMAs.
// ---------------------------------------------------------------------------
template <int BNT, int OUTBF16>
__global__ __launch_bounds__(512, 2) void gemm256_nt(
    const bf16* __restrict__ A, const bf16* __restrict__ Bm,
    void* __restrict__ Cv, int M, int N, int K) {
    __shared__ bf16 ringA[3][8192];
    __shared__ bf16 ringB[3][BNT * 32];
    const int tid = threadIdx.x;
    const int w = tid >> 6;
    const int l = tid & 63;
    const int wm = w >> 2;
    const int wn = w & 3;
    const int fl = l & 15;
    const int fk = (l >> 4) * 8;
    const int bm = blockIdx.y, bn = blockIdx.x;

    const int srow = tid >> 2;
    const int scol = (((tid & 3) ^ ((tid >> 3) & 3)) << 3);
    const bf16* Ag0 = A + (size_t)(bm * 256 + srow) * K + scol;
    const bf16* Ag1 = A + (size_t)(bm * 256 + 128 + srow) * K + scol;
    const bf16* Bg0 = Bm + (size_t)(bn * BNT + srow) * K + scol;
    const bf16* Bg1 = Bm + (size_t)(bn * BNT + 128 + srow) * K + scol;  // BNT=256

    const int kswz = fk ^ (((fl >> 1) & 3) << 3);
    const int NFR = BNT / 64;
    int aoff[8], boff[4];
#pragma unroll
    for (int mi = 0; mi < 8; ++mi)
        aoff[mi] = (wm * 128 + mi * 16 + fl) * 32 + kswz;
#pragma unroll
    for (int ni = 0; ni < NFR; ++ni)
        boff[ni] = (wn * (BNT / 4) + ni * 16 + fl) * 32 + kswz;

    f32x4 acc[8][4];
#pragma unroll
    for (int mi = 0; mi < 8; ++mi)
#pragma unroll
        for (int ni = 0; ni < NFR; ++ni) acc[mi][ni] = (f32x4){0.f, 0.f, 0.f, 0.f};

#define STAGEX(kt, slot)                                                       \
    do {                                                                       \
        const int _k = (kt) * 32;                                              \
        gld16(Ag0 + _k, &ringA[slot][w * 512]);                                \
        gld16(Ag1 + _k, &ringA[slot][4096 + w * 512]);                         \
        gld16(Bg0 + _k, &ringB[slot][w * 512]);                                \
        if (BNT == 256) gld16(Bg1 + _k, &ringB[slot][4096 + w * 512]);         \
    } while (0)

    const int nkt = K >> 5;
    STAGEX(0, 0);
    STAGEX(1, 1);

    for (int t = 0; t < nkt; ++t) {
        if (BNT == 256)
            asm volatile("s_waitcnt vmcnt(4)" ::: "memory");
        else
            asm volatile("s_waitcnt vmcnt(3)" ::: "memory");
        __builtin_amdgcn_s_barrier();
        __builtin_amdgcn_sched_barrier(0);
        const int slot = t % 3;
        const bf16* As_ = ringA[slot];
        const bf16* Bs_ = ringB[slot];
        bf16x8 af[8], bfr[4];
#pragma unroll
        for (int mi = 0; mi < 8; ++mi)
            af[mi] = *(const bf16x8*)(As_ + aoff[mi]);
#pragma unroll
        for (int ni = 0; ni < NFR; ++ni)
            bfr[ni] = *(const bf16x8*)(Bs_ + boff[ni]);
        const int kt2 = (t + 2 < nkt) ? (t + 2) : (nkt - 1);
        STAGEX(kt2, (t + 2) % 3);
        // no manual lgkm fence: compiler schedules ds_read->MFMA waits.
        __builtin_amdgcn_s_setprio(1);
#pragma unroll
        for (int mi = 0; mi < 8; ++mi)
#pragma unroll
            for (int ni = 0; ni < NFR; ++ni)
                acc[mi][ni] = MFMA16(af[mi], bfr[ni], acc[mi][ni]);
        __builtin_amdgcn_s_setprio(0);
    }
#undef STAGEX

#pragma unroll
    for (int mi = 0; mi < 8; ++mi)
#pragma unroll
        for (int ni = 0; ni < NFR; ++ni)
#pragma unroll
            for (int r = 0; r < 4; ++r) {
                const int row = bm * 256 + wm * 128 + mi * 16 + (l >> 4) * 4 + r;
                const int col = bn * BNT + wn * (BNT / 4) + ni * 16 + fl;
                if (OUTBF16)
                    ((bf16*)Cv)[(size_t)row * N + col] = f2bf(acc[mi][ni][r]);
                else
                    ((float*)Cv)[(size_t)row * N + col] = acc[mi][ni][r];
            }
}

// ---------------------------------------------------------------------------
// ba projection, fp32, K-split x4
// ---------------------------------------------------------------------------
#define BM 64
#define BN 64
#define BKK 32

__global__ __launch_bounds__(256) void gemm_ba_ksplit(
    const float* __restrict__ A, const float* __restrict__ Bm,
    float* __restrict__ Cpart) {
    __shared__ float As[BKK][BM + 4];
    __shared__ float Bs[BKK][BN + 4];
    const int tid = threadIdx.x;
    const int tx = tid & 15;
    const int ty = tid >> 4;
    const int ks = blockIdx.x;     // 0..3
    const int bm = blockIdx.y;     // 0..63
    const float* Ab = A + (size_t)bm * BM * HID_;
    const float* Bb = Bm;
    const int lr = tid >> 2;
    const int lc = (tid & 3) << 3;

    float c[4][4] = {{0.f, 0.f, 0.f, 0.f}, {0.f, 0.f, 0.f, 0.f},
                     {0.f, 0.f, 0.f, 0.f}, {0.f, 0.f, 0.f, 0.f}};

    const int kbeg = ks * 512;
    for (int k0 = kbeg; k0 < kbeg + 512; k0 += BKK) {
        const float4 a0 = *(const float4*)(Ab + (size_t)lr * HID_ + k0 + lc);
        const float4 a1 = *(const float4*)(Ab + (size_t)lr * HID_ + k0 + lc + 4);
        const float4 b0 = *(const float4*)(Bb + (size_t)lr * HID_ + k0 + lc);
        const float4 b1 = *(const float4*)(Bb + (size_t)lr * HID_ + k0 + lc + 4);
        __syncthreads();
        As[lc + 0][lr] = a0.x; As[lc + 1][lr] = a0.y;
        As[lc + 2][lr] = a0.z; As[lc + 3][lr] = a0.w;
        As[lc + 4][lr] = a1.x; As[lc + 5][lr] = a1.y;
        As[lc + 6][lr] = a1.z; As[lc + 7][lr] = a1.w;
        Bs[lc + 0][lr] = b0.x; Bs[lc + 1][lr] = b0.y;
        Bs[lc + 2][lr] = b0.z; Bs[lc + 3][lr] = b0.w;
        Bs[lc + 4][lr] = b1.x; Bs[lc + 5][lr] = b1.y;
        Bs[lc + 6][lr] = b1.z; Bs[lc + 7][lr] = b1.w;
        __syncthreads();
#pragma unroll
        for (int kk = 0; kk < BKK; ++kk) {
            const float4 Av = *(const float4*)&As[kk][ty << 2];
            const float4 Bv = *(const float4*)&Bs[kk][tx << 2];
            const float aa[4] = {Av.x, Av.y, Av.z, Av.w};
            const float bb[4] = {Bv.x, Bv.y, Bv.z, Bv.w};
#pragma unroll
            for (int i = 0; i < 4; ++i)
#pragma unroll
                for (int j = 0; j < 4; ++j)
                    c[i][j] = fmaf(aa[i], bb[j], c[i][j]);
        }
    }
    float* Cp = Cpart + (size_t)ks * ((size_t)B_ * S_ * 64) +
                (size_t)(bm * BM + (ty << 2)) * 64 + (tx << 2);
#pragma unroll
    for (int i = 0; i < 4; ++i)
        *(float4*)(Cp + (size_t)i * 64) =
            make_float4(c[i][0], c[i][1], c[i][2], c[i][3]);
}

// ---------------------------------------------------------------------------
// Causal depthwise conv (K=4) + SiLU + FUSED q/k l2norm, 8 ch/thread.
// A 16-lane group covers one 128-ch head row (waves never straddle
// sections: all boundaries are multiples of 512). z passthrough.
// ---------------------------------------------------------------------------
__global__ __launch_bounds__(256) void conv_silu_kernel(
    const bf16* __restrict__ qkvz, const float* __restrict__ cw,
    bf16* __restrict__ qbf, bf16* __restrict__ kbf, bf16* __restrict__ vbuf,
    bf16* __restrict__ zbuf) {
    const int64_t idx = (int64_t)blockIdx.x * 256 + threadIdx.x;
    const int cg = (int)(idx % 1536);
    const int64_t bs = idx / 1536;
    const int s = (int)(bs & (S_ - 1));
    const int c0 = cg << 3;

    int col;
    bf16* outp;
    if (c0 < KEY_DIM_) {
        col = ((c0 >> 7) * 768) + (c0 & 127);
        outp = qbf + bs * KEY_DIM_ + c0;
    } else if (c0 < 2 * KEY_DIM_) {
        const int c2 = c0 - KEY_DIM_;
        col = ((c2 >> 7) * 768) + 128 + (c2 & 127);
        outp = kbf + bs * KEY_DIM_ + c2;
    } else if (c0 < 2 * KEY_DIM_ + VAL_DIM_) {
        const int c3 = c0 - 2 * KEY_DIM_;
        col = ((c3 >> 8) * 768) + 256 + (c3 & 255);
        outp = vbuf + bs * VAL_DIM_ + c3;
    } else {
        const int zc = c0 - (2 * KEY_DIM_ + VAL_DIM_);
        const int hv = zc >> 7;
        col = (hv >> 1) * 768 + 512 + (hv & 1) * 128 + (zc & 127);
        outp = zbuf + bs * VAL_DIM_ + zc;
    }
    const bf16* xp = qkvz + bs * (int64_t)QKVZ_DIM_ + col;
    if (c0 >= 2 * KEY_DIM_ + VAL_DIM_) {
        *(uint4*)outp = *(const uint4*)xp;   // z passthrough
        return;
    }
    const uint4 zero4 = {0u, 0u, 0u, 0u};
    const uint4 x0 = *(const uint4*)xp;
    const uint4 x1 = (s >= 1) ? *(const uint4*)(xp - QKVZ_DIM_) : zero4;
    const uint4 x2 = (s >= 2) ? *(const uint4*)(xp - 2 * QKVZ_DIM_) : zero4;
    const uint4 x3 = (s >= 3) ? *(const uint4*)(xp - 3 * QKVZ_DIM_) : zero4;
    float y[8];
#pragma unroll
    for (int j = 0; j < 8; ++j) {
        const float4 wv = *(const float4*)(cw + (size_t)(c0 + j) * 4);
        float acc = wv.w * bf_lane(x0, j);
        acc = fmaf(wv.z, bf_lane(x1, j), acc);
        acc = fmaf(wv.y, bf_lane(x2, j), acc);
        acc = fmaf(wv.x, bf_lane(x3, j), acc);
        y[j] = silu_f(acc);
    }
    float sc = 1.f;
    if (c0 < 2 * KEY_DIM_) {   // q or k: l2norm across the 128-ch head row
        float ss = 0.f;
#pragma unroll
        for (int j = 0; j < 8; ++j) ss = fmaf(y[j], y[j], ss);
        ss = row16_sum(ss);    // 16 lanes x 8 ch = one head row
        sc = rsqrtf(ss + EPS_);
        if (c0 < KEY_DIM_) sc *= 0.08838834764831845f;  // DK^-0.5 for q
    }
    u16x8 o;
#pragma unroll
    for (int j = 0; j < 8; ++j) o[j] = f2bf(y[j] * sc);
    *(u16x8*)outp = o;
}

// ---------------------------------------------------------------------------
// Gate precompute from 4 K-split partials
// ---------------------------------------------------------------------------
__global__ __launch_bounds__(256) void gate_kernel(
    const float* __restrict__ ba_part, const float* __restrict__ A_log,
    const float* __restrict__ dt_bias, float* __restrict__ gbuf,
    float* __restrict__ betabuf) {
    const int idx = blockIdx.x * 256 + threadIdx.x;   // B*S*HV
    const int hv = idx & (HV_ - 1);
    const int bs = idx >> 5;
    const int hk = hv >> 1, j = hv & 1;
    const size_t SP = (size_t)B_ * S_ * 64;  // 262144
    const float* p = ba_part + (size_t)bs * 64 + hk * 4;
    const float bval = p[j] + p[SP + j] + p[2 * SP + j] + p[3 * SP + j];
    const float aval =
        p[2 + j] + p[SP + 2 + j] + p[2 * SP + 2 + j] + p[3 * SP + 2 + j];
    const float x = aval + dt_bias[hv];
    const float sp = (x > 20.f) ? x : log1pf(expf(x));
    gbuf[idx] = -expf(A_log[hv]) * sp;
    betabuf[idx] = 1.f / (1.f + expf(-bval));
}

// ---------------------------------------------------------------------------
// PASS 1 — R15 structure (register substitution + wave specialization).
// ---------------------------------------------------------------------------
__global__ __launch_bounds__(256) void p1_kernel(
    const bf16* __restrict__ qbf, const bf16* __restrict__ kbf,
    const bf16* __restrict__ vbuf, const float* __restrict__ gbuf,
    const float* __restrict__ betabuf, bf16* __restrict__ WkA,
    bf16* __restrict__ QgA, bf16* __restrict__ Kg2A, bf16* __restrict__ UA,
    bf16* __restrict__ LA, float* __restrict__ gcArr) {
    const int ch = blockIdx.x;          // bh*32 + c
    const int bh = ch >> 5, c = ch & 31;
    const int b = bh >> 5, hv = bh & 31;
    const int hk = hv >> 1;
    const int tid = threadIdx.x;
    const int w = tid >> 6, l = tid & 63;
    const int fl = l & 15, fk = (l >> 4) * 8;

    __shared__ float Gls[CL_];
    __shared__ float Bls[CL_];
    __shared__ float Egt[CL_];          // exp(G_t)
    __shared__ float Egc[CL_];          // exp(G63 - G_t)
    __shared__ float A_ls[CL_][CL_ + 1];
    __shared__ bf16 Tbf[CL_ * CL_];
    __shared__ bf16 Vt[128 * 72];
    __shared__ bf16 Kt[128 * 72];

    if (tid < 64) {
        float G = gbuf[((size_t)(b * S_ + c * 64 + tid)) * HV_ + hv];
        Bls[tid] = betabuf[((size_t)(b * S_ + c * 64 + tid)) * HV_ + hv];
#pragma unroll
        for (int d = 1; d < 64; d <<= 1) {
            const float n = __shfl_up(G, d, 64);
            if (tid >= d) G += n;
        }
        Gls[tid] = G;
        const float eg = expf(G);
        Egt[tid] = eg;
        Egc[tid] = expf(__shfl(G, 63, 64) - G);
        if (tid == 63) gcArr[ch] = eg;
    }
    __syncthreads();

    const bf16* kc = kbf + ((size_t)(b * S_ + c * 64)) * KEY_DIM_ + hk * DK_;
    const bf16* qc = qbf + ((size_t)(b * S_ + c * 64)) * KEY_DIM_ + hk * DK_;
    bf16* LC = LA + (size_t)ch * 4096;

    f32x4 accK[4], accQ[4];
#pragma unroll
    for (int n = 0; n < 4; ++n) {
        accK[n] = (f32x4){0.f, 0.f, 0.f, 0.f};
        accQ[n] = (f32x4){0.f, 0.f, 0.f, 0.f};
    }
#pragma unroll
    for (int kk = 0; kk < 4; ++kk) {
        const bf16x8 aK =
            *(const bf16x8*)(kc + (size_t)(w * 16 + fl) * KEY_DIM_ + fk + 32 * kk);
        const bf16x8 aQ =
            *(const bf16x8*)(qc + (size_t)(w * 16 + fl) * KEY_DIM_ + fk + 32 * kk);
#pragma unroll
        for (int n = 0; n < 4; ++n) {
            const bf16x8 bK = *(const bf16x8*)(kc + (size_t)(n * 16 + fl) * KEY_DIM_ +
                                               fk + 32 * kk);
            accK[n] = MFMA16(aK, bK, accK[n]);
            accQ[n] = MFMA16(aQ, bK, accQ[n]);
        }
    }
#pragma unroll
    for (int n = 0; n < 4; ++n)
#pragma unroll
        for (int r = 0; r < 4; ++r) {
            const int t = w * 16 + (l >> 4) * 4 + r;
            const int s = n * 16 + fl;
            const float eg = expf(Gls[t] - Gls[s]);
            A_ls[t][s] = (s < t) ? Bls[t] * eg * accK[n][r] : 0.f;
            const float lv = (s <= t) ? eg * accQ[n][r] : 0.f;
            LC[t * 64 + s] = f2bf(lv);
        }
    __syncthreads();

    bf16* QgC = QgA + (size_t)ch * 8192;
    bf16* KgC = Kg2A + (size_t)ch * 8192;

    if (w == 0) {
        float Tcol[64];
#pragma unroll
        for (int t = 0; t < 64; ++t) {
            float acc = (t == l) ? 1.f : 0.f;
#pragma unroll
            for (int s = 0; s < t; ++s)
                acc = fmaf(-A_ls[t][s], Tcol[s], acc);
            Tcol[t] = acc;
            Tbf[t * 64 + l] = f2bf(acc);
        }
    } else if (w == 1) {
        for (int i = l; i < 8192; i += 64) {
            const int d = i & 127, s = i >> 7;
            Vt[d * 72 + s] = f2bf(
                bf2f(vbuf[((size_t)(b * S_ + c * 64 + s)) * VAL_DIM_ + hv * DV_ + d]) *
                Bls[s]);
        }
    } else if (w == 2) {
        for (int i = l; i < 8192; i += 64) {
            const int d = i & 127, s = i >> 7;
            Kt[d * 72 + s] =
                f2bf(bf2f(kc[(size_t)s * KEY_DIM_ + d]) * Bls[s] * Egt[s]);
        }
    } else {
        for (int i = l; i < 8192; i += 64) {
            const int d = i & 127, t = i >> 7;
            QgC[t * 128 + d] = f2bf(bf2f(qc[(size_t)t * KEY_DIM_ + d]) * Egt[t]);
            KgC[d * 64 + t] = f2bf(bf2f(kc[(size_t)t * KEY_DIM_ + d]) * Egc[t]);
        }
    }
    __syncthreads();

    bf16* UC = UA + (size_t)ch * 8192;
    bf16* WkC = WkA + (size_t)ch * 8192;
    f32x4 accU[8], accW[8];
#pragma unroll
    for (int n = 0; n < 8; ++n) {
        accU[n] = (f32x4){0.f, 0.f, 0.f, 0.f};
        accW[n] = (f32x4){0.f, 0.f, 0.f, 0.f};
    }
#pragma unroll
    for (int kk = 0; kk < 2; ++kk) {
        const bf16x8 aT = *(const bf16x8*)(Tbf + (w * 16 + fl) * 64 + fk + 32 * kk);
#pragma unroll
        for (int n = 0; n < 8; ++n) {
            const bf16x8 bV = *(const bf16x8*)(Vt + (n * 16 + fl) * 72 + fk + 32 * kk);
            const bf16x8 bK2 = *(const bf16x8*)(Kt + (n * 16 + fl) * 72 + fk + 32 * kk);
            accU[n] = MFMA16(aT, bV, accU[n]);
            accW[n] = MFMA16(aT, bK2, accW[n]);
        }
    }
#pragma unroll
    for (int n = 0; n < 8; ++n)
#pragma unroll
        for (int r = 0; r < 4; ++r) {
            const int t = w * 16 + (l >> 4) * 4 + r;
            const int col = n * 16 + fl;
            UC[t * 128 + col] = f2bf(accU[n][r]);
            WkC[t * 128 + col] = f2bf(accW[n][r]);
        }
}

// ---------------------------------------------------------------------------
// PASS 2 — unchanged from R12.
// ---------------------------------------------------------------------------
__global__ __launch_bounds__(256) void p2_kernel(
    const bf16* __restrict__ WkA, const bf16* __restrict__ QgA,
    const bf16* __restrict__ Kg2A, const bf16* __restrict__ UA,
    const bf16* __restrict__ LA, const float* __restrict__ gcArr,
    bf16* __restrict__ core) {
    const int xcd = blockIdx.x & 7;
    const int rr = blockIdx.x >> 3;       // 0..31
    const int bh = xcd * 8 + (rr & 7);    // 0..63
    const int dvb = rr >> 3;              // 0..3
    const int b = bh >> 5, hv = bh & 31;
    const int tid = threadIdx.x;
    const int w = tid >> 6, l = tid & 63;
    const int fl = l & 15, fk = (l >> 4) * 8;

    __shared__ bf16 Sbf[32 * 136];
    __shared__ bf16 Dbf[32 * 72];

    for (int i = tid; i < 32 * 136; i += 256) Sbf[i] = 0;
    f32x4 accS[2][2];
#pragma unroll
    for (int m = 0; m < 2; ++m)
#pragma unroll
        for (int n = 0; n < 2; ++n) accS[m][n] = (f32x4){0.f, 0.f, 0.f, 0.f};
    __syncthreads();

    for (int c = 0; c < NCHUNK_; ++c) {
        const size_t ch = (size_t)bh * 32 + c;
        const bf16* WkC = WkA + ch * 8192;
        const bf16* QgC = QgA + ch * 8192;
        const bf16* KgC = Kg2A + ch * 8192;
        const bf16* UC = UA + ch * 8192;
        const bf16* LC = LA + ch * 4096;

        f32x4 accD[2], accO[2];
#pragma unroll
        for (int n = 0; n < 2; ++n) {
            accD[n] = (f32x4){0.f, 0.f, 0.f, 0.f};
            accO[n] = (f32x4){0.f, 0.f, 0.f, 0.f};
        }
#pragma unroll
        for (int kk = 0; kk < 4; ++kk) {
            const bf16x8 bS0 = *(const bf16x8*)(Sbf + (0 * 16 + fl) * 136 + fk + 32 * kk);
            const bf16x8 bS1 = *(const bf16x8*)(Sbf + (1 * 16 + fl) * 136 + fk + 32 * kk);
            const bf16x8 aW = *(const bf16x8*)(WkC + (w * 16 + fl) * 128 + fk + 32 * kk);
            const bf16x8 aQ = *(const bf16x8*)(QgC + (w * 16 + fl) * 128 + fk + 32 * kk);
            accD[0] = MFMA16(aW, bS0, accD[0]);
            accD[1] = MFMA16(aW, bS1, accD[1]);
            accO[0] = MFMA16(aQ, bS0, accO[0]);
            accO[1] = MFMA16(aQ, bS1, accO[1]);
        }
#pragma unroll
        for (int n = 0; n < 2; ++n)
#pragma unroll
            for (int r = 0; r < 4; ++r) {
                const int t = w * 16 + (l >> 4) * 4 + r;
                const int dvl = n * 16 + fl;
                const float u = bf2f(UC[t * 128 + dvb * 32 + dvl]);
                Dbf[dvl * 72 + t] = f2bf(u - accD[n][r]);
            }
        __syncthreads();

#pragma unroll
        for (int kk = 0; kk < 2; ++kk) {
            const bf16x8 bD0 = *(const bf16x8*)(Dbf + (0 * 16 + fl) * 72 + fk + 32 * kk);
            const bf16x8 bD1 = *(const bf16x8*)(Dbf + (1 * 16 + fl) * 72 + fk + 32 * kk);
            const bf16x8 aL = *(const bf16x8*)(LC + (w * 16 + fl) * 64 + fk + 32 * kk);
            accO[0] = MFMA16(aL, bD0, accO[0]);
            accO[1] = MFMA16(aL, bD1, accO[1]);
        }
#pragma unroll
        for (int n = 0; n < 2; ++n)
#pragma unroll
            for (int r = 0; r < 4; ++r) {
                const int t = w * 16 + (l >> 4) * 4 + r;
                const int col = hv * 128 + dvb * 32 + n * 16 + fl;
                core[((size_t)(b * S_ + c * 64 + t)) * VAL_DIM_ + col] =
                    f2bf(accO[n][r]);
            }

        const float gc = gcArr[ch];
#pragma unroll
        for (int m = 0; m < 2; ++m)
#pragma unroll
            for (int n = 0; n < 2; ++n)
#pragma unroll
                for (int r = 0; r < 4; ++r) accS[m][n][r] *= gc;
#pragma unroll
        for (int kk = 0; kk < 2; ++kk) {
            const bf16x8 bD0 = *(const bf16x8*)(Dbf + (0 * 16 + fl) * 72 + fk + 32 * kk);
            const bf16x8 bD1 = *(const bf16x8*)(Dbf + (1 * 16 + fl) * 72 + fk + 32 * kk);
#pragma unroll
            for (int m = 0; m < 2; ++m) {
                const bf16x8 aK =
                    *(const bf16x8*)(KgC + ((2 * w + m) * 16 + fl) * 64 + fk + 32 * kk);
                accS[m][0] = MFMA16(aK, bD0, accS[m][0]);
                accS[m][1] = MFMA16(aK, bD1, accS[m][1]);
            }
        }
        __syncthreads();
#pragma unroll
        for (int m = 0; m < 2; ++m)
#pragma unroll
            for (int n = 0; n < 2; ++n)
#pragma unroll
                for (int r = 0; r < 4; ++r) {
                    const int dk = (2 * w + m) * 16 + (l >> 4) * 4 + r;
                    const int dvl = n * 16 + fl;
                    Sbf[dvl * 136 + dk] = f2bf(accS[m][n][r]);
                }
        __syncthreads();
    }
}

// ---------------------------------------------------------------------------
// Gated RMSNorm in-place on bf16 core; z from zbuf (contiguous).
// ---------------------------------------------------------------------------
__global__ __launch_bounds__(256) void rmsnorm_gate_kernel(
    bf16* __restrict__ core, const bf16* __restrict__ zbuf,
    const float* __restrict__ nw) {
    const int wid = (blockIdx.x * 256 + threadIdx.x) >> 6;
    const int lane = threadIdx.x & 63;
    const int hv = wid & (HV_ - 1);
    const int64_t bs = wid >> 5;
    bf16* x = core + (size_t)bs * VAL_DIM_ + hv * DV_;
    const float x0 = bf2f(x[lane]);
    const float x1 = bf2f(x[lane + 64]);
    float ss = fmaf(x0, x0, x1 * x1);
#pragma unroll
    for (int m = 1; m < 64; m <<= 1) ss += __shfl_xor(ss, m);
    const float inv = rsqrtf(ss * (1.f / 128.f) + EPS_);
    const bf16* z = zbuf + (size_t)bs * VAL_DIM_ + hv * DV_;
    x[lane] = f2bf(x0 * inv * nw[lane] * silu_f(bf2f(z[lane])));
    x[lane + 64] =
        f2bf(x1 * inv * nw[lane + 64] * silu_f(bf2f(z[lane + 64])));
}

// ---------------------------------------------------------------------------
extern "C" void kernel_launch(void* const* d_in, const int* in_sizes, int n_in,
                              void* d_out, int out_size, void* d_ws,
                              size_t ws_size, hipStream_t stream) {
    const float* hidden  = (const float*)d_in[0];
    const float* W_qkvz  = (const float*)d_in[1];
    const float* W_ba    = (const float*)d_in[2];
    const float* conv_w  = (const float*)d_in[3];
    const float* dt_bias = (const float*)d_in[4];
    const float* A_log   = (const float*)d_in[5];
    const float* norm_w  = (const float*)d_in[6];
    const float* W_out   = (const float*)d_in[7];
    float* out = (float*)d_out;

    // ---- workspace (~324 MB <= proven 337.5) ----
    bf16* R = (bf16*)d_ws;
    bf16* hidden_bf = R;                         //  8,388,608 e
    bf16* Wq_bf = R + (size_t)8388608;           // 25,165,824 e
    bf16* qkvz  = R + (size_t)33554432;          // 50,331,648 e
    // P1 aliases (valid once conv has consumed qkvz):
    bf16* WkA  = R;                              // 16,777,216 e
    bf16* QgA  = R + (size_t)16777216;           // 16,777,216 e
    bf16* Kg2A = R + (size_t)33554432;           // 16,777,216 e
    bf16* UA   = R + (size_t)50331648;           // 16,777,216 e
    bf16* LA   = R + (size_t)67108864;           //  8,388,608 e
    // non-aliased:
    bf16* Wo_bf = R + (size_t)83886080;          //  8,388,608 e
    bf16* qbf   = Wo_bf + (size_t)8388608;       //  8,388,608 e
    bf16* kbf   = qbf + (size_t)8388608;         //  8,388,608 e
    bf16* vbuf  = kbf + (size_t)8388608;         // 16,777,216 e
    bf16* zbuf  = vbuf + (size_t)16777216;       // 16,777,216 e
    bf16* core  = zbuf + (size_t)16777216;       // 16,777,216 e
    float* ba_part = (float*)(core + (size_t)16777216);  // 1,048,576 f
    float* gbuf    = ba_part + 1048576;                  //   131,072 f
    float* betabuf = gbuf + 131072;                      //   131,072 f
    float* gcArr   = betabuf + 131072;                   //     2,048 f

    const int MBS = B_ * S_;  // 4096

    // 0. fp32 -> bf16 operand conversion (one fused launch)
    f2bf3_kernel<<<40960, 256, 0, stream>>>(hidden, W_qkvz, W_out, hidden_bf,
                                            Wq_bf, Wo_bf);

    // 1. qkvz = hidden @ W_qkvz^T (256^2-tile counted-vmcnt MFMA GEMM)
    gemm256_nt<256, 1><<<dim3(QKVZ_DIM_ / 256, MBS / 256), 512, 0, stream>>>(
        hidden_bf, Wq_bf, (void*)qkvz, MBS, QKVZ_DIM_, HID_);
    // 2. ba = hidden @ W_ba^T (fp32, K-split x4)
    gemm_ba_ksplit<<<dim3(4, 64), 256, 0, stream>>>(hidden, W_ba, ba_part);
    // 3. gates
    gate_kernel<<<(MBS * HV_) / 256, 256, 0, stream>>>(ba_part, A_log, dt_bias,
                                                       gbuf, betabuf);
    // 4. conv + silu + fused q/k l2norm + z copy
    conv_silu_kernel<<<(int)(((int64_t)MBS * 1536) / 256), 256, 0, stream>>>(
        qkvz, conv_w, qbf, kbf, vbuf, zbuf);
    // 5. chunked delta rule
    p1_kernel<<<2048, 256, 0, stream>>>(qbf, kbf, vbuf, gbuf, betabuf, WkA,
                                        QgA, Kg2A, UA, LA, gcArr);
    p2_kernel<<<256, 256, 0, stream>>>(WkA, QgA, Kg2A, UA, LA, gcArr, core);
    // 6. gated rmsnorm
    rmsnorm_gate_kernel<<<(MBS * HV_ * 64) / 256, 256, 0, stream>>>(core, zbuf,
                                                                    norm_w);
    // 7. out = core @ W_out^T (256x128-tile pipelined, 256 WGs, fp32 out)
    gemm256_nt<128, 0><<<dim3(HID_ / 128, MBS / 256), 512, 0, stream>>>(
        core, Wo_bf, (void*)out, MBS, HID_, VAL_DIM_);
}